// Round 11
// baseline (870.354 us; speedup 1.0000x reference)
//
#include <hip/hip_runtime.h>
#include <math.h>

#define NN 50000
#define NE 400000
#define NG 64
#define HD 128
#define LN_EPS 1e-5f

typedef unsigned short u16;
typedef unsigned int u32;
typedef __attribute__((ext_vector_type(8))) short short8;
typedef __attribute__((ext_vector_type(4))) float f32x4;

#define MFMA16(a,b,c) __builtin_amdgcn_mfma_f32_16x16x32_bf16((a),(b),(c),0,0,0)

__device__ __forceinline__ u16 f2bf(float f) {
    union { float f; u32 u; } v; v.f = f;
    u32 r = v.u + 0x7FFFu + ((v.u >> 16) & 1u);
    return (u16)(r >> 16);
}
__device__ __forceinline__ float bf2f(u32 hs) {
    union { u32 u; float f; } v; v.u = hs << 16;
    return v.f;
}
__device__ __forceinline__ float fast_rcp(float x) {
    float r; asm("v_rcp_f32 %0, %1" : "=v"(r) : "v"(x)); return r;
}
__device__ __forceinline__ float fast_exp2(float x) {
    float r; asm("v_exp_f32 %0, %1" : "=v"(r) : "v"(x)); return r;
}
__device__ __forceinline__ u32 cvtpk(float lo, float hi) {
    u32 r; asm("v_cvt_pk_bf16_f32 %0, %1, %2" : "=v"(r) : "v"(lo), "v"(hi)); return r;
}
// tanh(x) = 1 - 2/(1+2^(2*log2e*x)); exp2 saturates correctly at +-inf
__device__ __forceinline__ float fast_tanh(float x) {
    return fmaf(-2.f, fast_rcp(1.f + fast_exp2(2.885390082f * x)), 1.f);
}
__device__ __forceinline__ float fast_sigmoid(float x) {
    return fast_rcp(1.f + fast_exp2(-1.442695041f * x));
}

// swizzle term for row within 16-row group
__device__ __forceinline__ int swzr(int row) {
    return (row & 7) ^ ((row & 8) >> 2);
}

// A-fragment load from swizzled [64][128] bf16 chunk buffer.
__device__ __forceinline__ short8 loadA(const u16* buf, int mi, int kk, int l) {
    int row = mi*16 + (l & 15);
    int ci  = (kk*4 + (l >> 4)) ^ swzr(l & 15);
    return *(const short8*)(buf + row*128 + (ci << 3));
}
__device__ __forceinline__ short8 loadB(const u16* wp, int nt, int ks, int nk, int l) {
    return *(const short8*)(wp + (((nt*nk + ks)*64 + l) << 3));
}

// Store 4 accumulator values (rows R..R+3, col c) into swizzled bf16 chunk as
// packed u32 via lane-pair exchange + v_cvt_pk_bf16_f32.
__device__ __forceinline__ void storeQuad(u32* buf, int R, int c, int l,
                                          float v0, float v1, float v2, float v3)
{
    int cw = c >> 1;
    int par = l & 1;
    float send = par ? v0 : v1;
    float recv = __shfl_xor(send, 1);
    int row = R + par;
    u32 word = par ? cvtpk(recv, v1) : cvtpk(v0, recv);
    buf[row*64 + (((cw >> 2) ^ swzr(row & 15)) << 2) + (cw & 3)] = word;
    send = par ? v2 : v3;
    recv = __shfl_xor(send, 1);
    row = R + 2 + par;
    word = par ? cvtpk(recv, v3) : cvtpk(v2, recv);
    buf[row*64 + (((cw >> 2) ^ swzr(row & 15)) << 2) + (cw & 3)] = word;
}

// Unswizzle copy: LDS chunk -> global bf16 [64][128] rows n0..n0+63 (u32 words)
__device__ __forceinline__ void copyChunkOut(const u32* chunk, u32* gout, int n0, int t)
{
    for (int it = 0; it < 16; ++it) {
        int dw = it*256 + t;
        int row = dw >> 6, cw = dw & 63;
        if (n0 + row < NN)
            gout[(size_t)(n0 + row)*64 + cw] =
                chunk[row*64 + (((cw >> 2) ^ swzr(row & 15)) << 2) + (cw & 3)];
    }
}

// ---------------------------------------------------------------------------
// One-shot weight packing of all 9 GEMM weights -> bf16 MFMA B-fragment order.
// ---------------------------------------------------------------------------
__global__ __launch_bounds__(256)
void pack_all(const float* __restrict__ ee2w, const float* __restrict__ ee3w,
              const float* __restrict__ p1w,  const float* __restrict__ p2w,
              const float* __restrict__ p3w,  const float* __restrict__ ne2w,
              const float* __restrict__ ne3w, const float* __restrict__ g1w,
              const float* __restrict__ g2w,  u16* __restrict__ wpk)
{
    int idx = blockIdx.x*256 + threadIdx.x;
    if (idx >= 270336) return;
    const float* w; int K, N, local;
    if      (idx < 16384)  { w = ee2w; K = 128; N = 128; local = idx; }
    else if (idx < 32768)  { w = ee3w; K = 128; N = 128; local = idx - 16384; }
    else if (idx < 163840) { w = p1w;  K = 512; N = 256; local = idx - 32768; }
    else if (idx < 196608) { w = p2w;  K = 256; N = 128; local = idx - 163840; }
    else if (idx < 204800) { w = p3w;  K = 128; N = 64;  local = idx - 196608; }
    else if (idx < 221184) { w = ne2w; K = 128; N = 128; local = idx - 204800; }
    else if (idx < 237568) { w = ne3w; K = 128; N = 128; local = idx - 221184; }
    else if (idx < 253952) { w = g1w;  K = 128; N = 128; local = idx - 237568; }
    else                   { w = g2w;  K = 128; N = 128; local = idx - 253952; }
    int e = local & 7, l = (local >> 3) & 63, r = local >> 9;
    int nk = K >> 5;
    int nt = r / nk, kk = r % nk;
    int k = kk*32 + ((l >> 4) << 3) + e;
    int n = nt*16 + (l & 15);
    wpk[idx] = f2bf(w[k*N + n]);
}

// ---------------------------------------------------------------------------
// CSR build
// ---------------------------------------------------------------------------
__global__ __launch_bounds__(256)
void deg_count_int(const int* __restrict__ ei, int* __restrict__ degi)
{
    int e = blockIdx.x*256 + threadIdx.x;
    if (e < NE) atomicAdd(&degi[ei[NE + e]], 1);
}

__global__ __launch_bounds__(1024)
void scan_excl(const int* __restrict__ cnt, int* __restrict__ rp,
               float* __restrict__ dinv)
{
    __shared__ int wsum[16];
    __shared__ int carry;
    int t = threadIdx.x, lane = t & 63, w = t >> 6;
    int base = 0;
    for (int off = 0; off < NN; off += 4096) {
        int i0 = off + t*4;
        int v0 = (i0   < NN) ? cnt[i0]   : 0;
        int v1 = (i0+1 < NN) ? cnt[i0+1] : 0;
        int v2 = (i0+2 < NN) ? cnt[i0+2] : 0;
        int v3 = (i0+3 < NN) ? cnt[i0+3] : 0;
        int tot = v0 + v1 + v2 + v3;
        int s = tot;
#pragma unroll
        for (int d = 1; d < 64; d <<= 1) { int u = __shfl_up(s, d); if (lane >= d) s += u; }
        if (lane == 63) wsum[w] = s;
        __syncthreads();
        if (w == 0) {
            int wv = (lane < 16) ? wsum[lane] : 0;
            int ss = wv;
#pragma unroll
            for (int d = 1; d < 16; d <<= 1) { int u = __shfl_up(ss, d); if (lane >= d) ss += u; }
            if (lane < 16) wsum[lane] = ss - wv;
            if (lane == 15) carry = ss;
        }
        __syncthreads();
        int excl = base + wsum[w] + s - tot;
        if (i0   < NN) { rp[i0]   = excl;              dinv[i0]   = rsqrtf((float)v0 + 1.f); }
        if (i0+1 < NN) { rp[i0+1] = excl + v0;         dinv[i0+1] = rsqrtf((float)v1 + 1.f); }
        if (i0+2 < NN) { rp[i0+2] = excl + v0 + v1;    dinv[i0+2] = rsqrtf((float)v2 + 1.f); }
        if (i0+3 < NN) { rp[i0+3] = excl + v0 + v1 + v2; dinv[i0+3] = rsqrtf((float)v3 + 1.f); }
        base += carry;
        __syncthreads();
    }
    if (t == 0) rp[NN] = base;
}

__global__ __launch_bounds__(256)
void fill_csr(const int* __restrict__ ei, const int* __restrict__ rp,
              int* __restrict__ cursor, int* __restrict__ sadj)
{
    int e = blockIdx.x*256 + threadIdx.x;
    if (e >= NE) return;
    int d = ei[NE + e];
    int slot = atomicAdd(&cursor[d], 1);
    sadj[rp[d] + slot] = ei[e];
}

// ---------------------------------------------------------------------------
// Node encoder + g1w GEMM, MFMA. 64 nodes/block, 256 threads.
// ---------------------------------------------------------------------------
__global__ __launch_bounds__(256, 4)
void enc_mfma(const float* __restrict__ x,
              const float* __restrict__ w1, const float* __restrict__ b1,
              const u16* __restrict__ w2p, const float* __restrict__ b2,
              const u16* __restrict__ w3p, const float* __restrict__ b3,
              const float* __restrict__ gg, const float* __restrict__ bb,
              const u16* __restrict__ g1p, const float* __restrict__ dinv,
              u32* __restrict__ xw1p)
{
    __shared__ u16 chunkA[64*HD];
    __shared__ u16 chunkB[64*HD];
    __shared__ float sX[192];
    __shared__ float sDi[64];
    __shared__ float rstat[128];

    const int t = threadIdx.x;
    const int l = t & 63;
    const int wid = t >> 6;
    const int n0 = blockIdx.x * 64;

    if (t < 192) sX[t] = (n0*3 + t < NN*3) ? x[n0*3 + t] : 0.f;
    if (t < 64)  sDi[t] = (n0 + t < NN) ? dinv[n0 + t] : 0.f;
    __syncthreads();

    // L1: 3->128 relu (VALU) -> chunkA
    for (int it = 0; it < 16; ++it) {
        int dw = it*256 + t;
        int e = dw >> 6, cd = dw & 63;
        int c0 = cd*2;
        float x0 = sX[e*3], x1 = sX[e*3+1], x2 = sX[e*3+2];
        float v0 = b1[c0]   + x0*w1[c0]   + x1*w1[HD+c0]   + x2*w1[2*HD+c0];
        float v1 = b1[c0+1] + x0*w1[c0+1] + x1*w1[HD+c0+1] + x2*w1[2*HD+c0+1];
        v0 = fmaxf(v0, 0.f); v1 = fmaxf(v1, 0.f);
        int ci = cd >> 2;
        ((u32*)chunkA)[e*64 + ((ci ^ swzr(e & 15)) << 2) + (cd & 3)] = cvtpk(v0, v1);
    }
    __syncthreads();

    // L2 MFMA: relu(A@w2+b2) -> chunkB
    {
        f32x4 acc[4][2];
#pragma unroll
        for (int ni = 0; ni < 2; ++ni) {
            float b = b2[(2*wid + ni)*16 + (l & 15)];
#pragma unroll
            for (int mi = 0; mi < 4; ++mi) acc[mi][ni] = (f32x4){b,b,b,b};
        }
#pragma unroll
        for (int kk = 0; kk < 4; ++kk) {
            short8 af[4];
#pragma unroll
            for (int mi = 0; mi < 4; ++mi) af[mi] = loadA(chunkA, mi, kk, l);
#pragma unroll
            for (int ni = 0; ni < 2; ++ni) {
                short8 bw = loadB(w2p, 2*wid + ni, kk, 4, l);
#pragma unroll
                for (int mi = 0; mi < 4; ++mi) acc[mi][ni] = MFMA16(af[mi], bw, acc[mi][ni]);
            }
        }
#pragma unroll
        for (int ni = 0; ni < 2; ++ni) {
            int col = (2*wid + ni)*16 + (l & 15);
#pragma unroll
            for (int mi = 0; mi < 4; ++mi) {
                int R = mi*16 + ((l >> 4) << 2);
                storeQuad((u32*)chunkB, R, col, l,
                          fmaxf(acc[mi][ni][0], 0.f), fmaxf(acc[mi][ni][1], 0.f),
                          fmaxf(acc[mi][ni][2], 0.f), fmaxf(acc[mi][ni][3], 0.f));
            }
        }
    }
    __syncthreads();

    // L3 MFMA: B@w3+b3 (pre-LN) -> chunkA
    {
        f32x4 acc[4][2];
#pragma unroll
        for (int ni = 0; ni < 2; ++ni) {
            float b = b3[(2*wid + ni)*16 + (l & 15)];
#pragma unroll
            for (int mi = 0; mi < 4; ++mi) acc[mi][ni] = (f32x4){b,b,b,b};
        }
#pragma unroll
        for (int kk = 0; kk < 4; ++kk) {
            short8 af[4];
#pragma unroll
            for (int mi = 0; mi < 4; ++mi) af[mi] = loadA(chunkB, mi, kk, l);
#pragma unroll
            for (int ni = 0; ni < 2; ++ni) {
                short8 bw = loadB(w3p, 2*wid + ni, kk, 4, l);
#pragma unroll
                for (int mi = 0; mi < 4; ++mi) acc[mi][ni] = MFMA16(af[mi], bw, acc[mi][ni]);
            }
        }
#pragma unroll
        for (int ni = 0; ni < 2; ++ni) {
            int col = (2*wid + ni)*16 + (l & 15);
#pragma unroll
            for (int mi = 0; mi < 4; ++mi) {
                int R = mi*16 + ((l >> 4) << 2);
                storeQuad((u32*)chunkA, R, col, l,
                          acc[mi][ni][0], acc[mi][ni][1], acc[mi][ni][2], acc[mi][ni][3]);
            }
        }
    }
    __syncthreads();

    // LN stats: 4 lanes per row
    {
        int e = wid*16 + (l >> 2);
        int q = l & 3;
        const u32* rowp = (const u32*)chunkA + e*64;
        float s = 0.f, sq = 0.f;
#pragma unroll
        for (int i = 0; i < 16; ++i) {
            u32 pk = rowp[q*16 + ((i + e) & 15)];
            float a = bf2f(pk & 0xffffu), b = bf2f(pk >> 16);
            s += a + b;
            sq = fmaf(a, a, fmaf(b, b, sq));
        }
        s  += __shfl_xor(s, 1);  sq += __shfl_xor(sq, 1);
        s  += __shfl_xor(s, 2);  sq += __shfl_xor(sq, 2);
        if (q == 0) {
            float mu = s * (1.f/HD);
            rstat[e] = mu;
            rstat[64 + e] = rsqrtf(sq*(1.f/HD) - mu*mu + LN_EPS);
        }
    }
    __syncthreads();

    // normalize in place
    for (int it = 0; it < 16; ++it) {
        int pd = it*256 + t;
        int row = pd >> 6, cwd = pd & 63;
        int ci = (cwd >> 2) ^ swzr(row & 15);
        int col = ci*8 + (cwd & 3)*2;
        u32 pk = ((u32*)chunkA)[pd];
        float mu = rstat[row], ri = rstat[64 + row];
        float v0 = (bf2f(pk & 0xffffu) - mu)*ri*gg[col]     + bb[col];
        float v1 = (bf2f(pk >> 16)     - mu)*ri*gg[col + 1] + bb[col + 1];
        ((u32*)chunkA)[pd] = cvtpk(v0, v1);
    }
    __syncthreads();

    // GEMM @g1w, scale by dinv -> chunkB -> global
    {
        f32x4 acc[4][2];
#pragma unroll
        for (int mi = 0; mi < 4; ++mi)
#pragma unroll
            for (int ni = 0; ni < 2; ++ni) acc[mi][ni] = (f32x4){0.f,0.f,0.f,0.f};
#pragma unroll
        for (int kk = 0; kk < 4; ++kk) {
            short8 af[4];
#pragma unroll
            for (int mi = 0; mi < 4; ++mi) af[mi] = loadA(chunkA, mi, kk, l);
#pragma unroll
            for (int ni = 0; ni < 2; ++ni) {
                short8 bw = loadB(g1p, 2*wid + ni, kk, 4, l);
#pragma unroll
                for (int mi = 0; mi < 4; ++mi) acc[mi][ni] = MFMA16(af[mi], bw, acc[mi][ni]);
            }
        }
#pragma unroll
        for (int ni = 0; ni < 2; ++ni) {
            int col = (2*wid + ni)*16 + (l & 15);
#pragma unroll
            for (int mi = 0; mi < 4; ++mi) {
                int R = mi*16 + ((l >> 4) << 2);
                storeQuad((u32*)chunkB, R, col, l,
                          acc[mi][ni][0]*sDi[R], acc[mi][ni][1]*sDi[R+1],
                          acc[mi][ni][2]*sDi[R+2], acc[mi][ni][3]*sDi[R+3]);
            }
        }
    }
    __syncthreads();
    copyChunkOut((const u32*)chunkB, xw1p, n0, t);
}

// ---------------------------------------------------------------------------
// GCN layer 1: gather bf16 xw1p (prescaled), relu(+g1b), MFMA @g2w, *dinv -> xw2p
// ---------------------------------------------------------------------------
__global__ __launch_bounds__(256, 4)
void gcn_agg1_mfma(const u16* __restrict__ xw1p, const int* __restrict__ rp,
                   const int* __restrict__ sadj, const float* __restrict__ dinv,
                   const float* __restrict__ g1b, const u16* __restrict__ g2p,
                   u32* __restrict__ xw2p)
{
    __shared__ u16 chunkA[64*HD];
    __shared__ u16 chunkB[64*HD];
    __shared__ float sDi[64];
    __shared__ float sB[HD];

    const int t = threadIdx.x;
    const int l = t & 63;
    const int wid = t >> 6;
    const int n0 = blockIdx.x * 64;

    if (t < 64)  sDi[t] = (n0 + t < NN) ? dinv[n0 + t] : 0.f;
    if (t < HD)  sB[t] = g1b[t];
    __syncthreads();

    {
        int s = t >> 2, part = t & 3, n = n0 + s;
        float acc[32];
#pragma unroll
        for (int j = 0; j < 32; ++j) acc[j] = 0.f;
        float di = 0.f;
        if (n < NN) {
            di = sDi[s];
            const short8* selfp = (const short8*)(xw1p + (size_t)n*HD + part*32);
#pragma unroll
            for (int w = 0; w < 4; ++w) {
                short8 v = selfp[w];
#pragma unroll
                for (int j = 0; j < 8; ++j) acc[w*8+j] += bf2f((u16)v[j]);
            }
            int k1 = rp[n+1];
            for (int k = rp[n]; k < k1; ++k) {
                const short8* rp8 = (const short8*)(xw1p + (size_t)sadj[k]*HD + part*32);
#pragma unroll
                for (int w = 0; w < 4; ++w) {
                    short8 v = rp8[w];
#pragma unroll
                    for (int j = 0; j < 8; ++j) acc[w*8+j] += bf2f((u16)v[j]);
                }
            }
        }
#pragma unroll
        for (int p = 0; p < 16; ++p) {
            float v0 = fmaxf(fmaf(acc[2*p],   di, sB[part*32 + 2*p]),   0.f);
            float v1 = fmaxf(fmaf(acc[2*p+1], di, sB[part*32 + 2*p+1]), 0.f);
            int cw = part*16 + p;
            ((u32*)chunkA)[s*64 + (((cw >> 2) ^ swzr(s & 15)) << 2) + (cw & 3)] = cvtpk(v0, v1);
        }
    }
    __syncthreads();

    {
        f32x4 acc[4][2];
#pragma unroll
        for (int mi = 0; mi < 4; ++mi)
#pragma unroll
            for (int ni = 0; ni < 2; ++ni) acc[mi][ni] = (f32x4){0.f,0.f,0.f,0.f};
#pragma unroll
        for (int kk = 0; kk < 4; ++kk) {
            short8 af[4];
#pragma unroll
            for (int mi = 0; mi < 4; ++mi) af[mi] = loadA(chunkA, mi, kk, l);
#pragma unroll
            for (int ni = 0; ni < 2; ++ni) {
                short8 bw = loadB(g2p, 2*wid + ni, kk, 4, l);
#pragma unroll
                for (int mi = 0; mi < 4; ++mi) acc[mi][ni] = MFMA16(af[mi], bw, acc[mi][ni]);
            }
        }
#pragma unroll
        for (int ni = 0; ni < 2; ++ni) {
            int col = (2*wid + ni)*16 + (l & 15);
#pragma unroll
            for (int mi = 0; mi < 4; ++mi) {
                int R = mi*16 + ((l >> 4) << 2);
                storeQuad((u32*)chunkB, R, col, l,
                          acc[mi][ni][0]*sDi[R], acc[mi][ni][1]*sDi[R+1],
                          acc[mi][ni][2]*sDi[R+2], acc[mi][ni][3]*sDi[R+3]);
            }
        }
    }
    __syncthreads();
    copyChunkOut((const u32*)chunkB, xw2p, n0, t);
}

// ---------------------------------------------------------------------------
// GCN layer 2: gather bf16 xw2p, +g2b -> hbf (bf16 only)
// ---------------------------------------------------------------------------
__global__ __launch_bounds__(256)
void gcn_agg2_gather(const u16* __restrict__ xw2p, const int* __restrict__ rp,
                     const int* __restrict__ sadj, const float* __restrict__ dinv,
                     const float* __restrict__ g2b, u32* __restrict__ hbw)
{
    int t = threadIdx.x;
    int s = t >> 2, part = t & 3;
    int n = blockIdx.x * 64 + s;
    if (n >= NN) return;
    float acc[32];
#pragma unroll
    for (int j = 0; j < 32; ++j) acc[j] = 0.f;
    const short8* selfp = (const short8*)(xw2p + (size_t)n*HD + part*32);
#pragma unroll
    for (int w = 0; w < 4; ++w) {
        short8 v = selfp[w];
#pragma unroll
        for (int j = 0; j < 8; ++j) acc[w*8+j] += bf2f((u16)v[j]);
    }
    int k1 = rp[n+1];
    for (int k = rp[n]; k < k1; ++k) {
        const short8* rp8 = (const short8*)(xw2p + (size_t)sadj[k]*HD + part*32);
#pragma unroll
        for (int w = 0; w < 4; ++w) {
            short8 v = rp8[w];
#pragma unroll
            for (int j = 0; j < 8; ++j) acc[w*8+j] += bf2f((u16)v[j]);
        }
    }
    float di = dinv[n];
    u32* hb = hbw + (size_t)n*64 + part*16;
#pragma unroll
    for (int p = 0; p < 16; ++p) {
        float v0 = fmaf(acc[2*p],   di, g2b[part*32 + 2*p]);
        float v1 = fmaf(acc[2*p+1], di, g2b[part*32 + 2*p+1]);
        hb[p] = cvtpk(v0, v1);
    }
}

// ---------------------------------------------------------------------------
// Pool (batch sorted, bf16 input) + fused counts + graph MLP.
// graph_feat also precomputes gfp1[g][0:256] = gf[g] @ p1w[256:384,:] (fp32).
// ---------------------------------------------------------------------------
#define POOL_B 512
__global__ __launch_bounds__(128)
void pool_sorted(const u16* __restrict__ h, const int* __restrict__ batch,
                 float* __restrict__ sums, float* __restrict__ cnts)
{
    int b = blockIdx.x, j = threadIdx.x;
    int n0 = (int)(((long long)NN * b) / POOL_B);
    int n1 = (int)(((long long)NN * (b+1)) / POOL_B);
    int g = -1; float acc = 0.f, cl = 0.f;
    for (int n = n0; n < n1; ++n) {
        int bg = batch[n];
        if (bg != g) {
            if (g >= 0) {
                atomicAdd(&sums[g*HD + j], acc);
                if (j == 0) atomicAdd(&cnts[g], cl);
            }
            g = bg; acc = 0.f; cl = 0.f;
        }
        acc += bf2f(h[(size_t)n*HD + j]);
        cl += 1.f;
    }
    if (g >= 0) {
        atomicAdd(&sums[g*HD + j], acc);
        if (j == 0) atomicAdd(&cnts[g], cl);
    }
}

__global__ __launch_bounds__(128)
void graph_feat(const float* __restrict__ sums, const float* __restrict__ cnts,
                const float* __restrict__ w1, const float* __restrict__ b1,
                const float* __restrict__ w2, const float* __restrict__ b2,
                const float* __restrict__ gg, const float* __restrict__ bb,
                const float* __restrict__ p1w, float* __restrict__ gfp1)
{
    int gi = blockIdx.x, j = threadIdx.x;
    __shared__ float s0[HD];
    __shared__ float s1[HD];
    __shared__ float part[4];
    __shared__ float stat[2];
    float cnt = fmaxf(cnts[gi], 1.f);
    s0[j] = sums[gi*HD + j] / cnt;
    __syncthreads();
    float a = b1[j];
    for (int i = 0; i < HD; ++i) a = fmaf(s0[i], w1[i*HD + j], a);
    s1[j] = fmaxf(a, 0.f);
    __syncthreads();
    a = b2[j];
    for (int i = 0; i < HD; ++i) a = fmaf(s1[i], w2[i*HD + j], a);
    float s = a, q = a*a;
    for (int o = 32; o > 0; o >>= 1) { s += __shfl_down(s, o); q += __shfl_down(q, o); }
    int wid = j >> 6, lane = j & 63;
    if (lane == 0) { part[wid] = s; part[2 + wid] = q; }
    __syncthreads();
    if (j == 0) {
        float S = part[0] + part[1], Q = part[2] + part[3];
        float mu = S * (1.f/HD);
        stat[0] = mu;
        stat[1] = Q * (1.f/HD) - mu*mu;
    }
    __syncthreads();
    float v = (a - stat[0]) * rsqrtf(stat[1] + LN_EPS) * gg[j] + bb[j];
    __syncthreads();
    s0[j] = v;        // gf row for this graph (fp32)
    __syncthreads();
    // gfp1[gi][j] and [gi][j+128]: dot over gf-chunk of p1w (comb rows 256..383)
    float a0 = 0.f, a1 = 0.f;
    for (int k = 0; k < HD; ++k) {
        float gv = s0[k];
        a0 = fmaf(gv, p1w[(size_t)(256 + k)*256 + j],       a0);
        a1 = fmaf(gv, p1w[(size_t)(256 + k)*256 + j + 128], a1);
    }
    gfp1[gi*256 + j]       = a0;
    gfp1[gi*256 + j + 128] = a1;
}

// ---------------------------------------------------------------------------
// Stage 64 gathered bf16 rows into swizzled LDS chunk (4 threads/row)
// ---------------------------------------------------------------------------
__device__ __forceinline__ void stageRows(u16* dst, const u16* __restrict__ srcBase,
                                          const int* ridx, int t)
{
    int e = t >> 2, part = t & 3;
    const u16* src = srcBase + (size_t)ridx[e]*HD + part*32;
    u16* drow = dst + e*128;
    int re = swzr(e & 15);
#pragma unroll
    for (int w = 0; w < 4; ++w) {
        int ci = (part*4 + w) ^ re;
        *(short8*)(drow + (ci << 3)) = *(const short8*)(src + w*8);
    }
}

// ---------------------------------------------------------------------------
// Fused edge kernel (MFMA bf16). 64 edges/block, 256 threads, 3 blocks/CU.
// ep1 = 2 sequential row-half passes with acc[2][4] = 32 AGPRs; a real
// __syncthreads() between MFMA and epilogue (needed for correctness anyway)
// is the compiler fence that lets pass-0's accumulators die before pass 1
// (round-8's merge bug; round-9's sched_barrier was the wrong fence).
// ---------------------------------------------------------------------------
__global__ __launch_bounds__(256, 3)
void edge_mlp_mfma(const u16* __restrict__ hbf, const float* __restrict__ gfp1,
                   const int* __restrict__ ei, const int* __restrict__ batch,
                   const float* __restrict__ ea,
                   const float* __restrict__ ew1, const float* __restrict__ eb1,
                   const u16* __restrict__ ew2p, const float* __restrict__ eb2,
                   const u16* __restrict__ ew3p, const float* __restrict__ eb3,
                   const float* __restrict__ egm, const float* __restrict__ ebb,
                   const u16* __restrict__ p1wp, const float* __restrict__ p1b,
                   const u16* __restrict__ p2wp, const float* __restrict__ p2b,
                   const u16* __restrict__ p3wp, const float* __restrict__ p3b,
                   const float* __restrict__ p4w, const float* __restrict__ p4b,
                   float* __restrict__ out)
{
    __shared__ u16 bufChunk[64*HD];    // 16KB swizzled A-chunk
    __shared__ u16 bufWide[64*256];    // 32KB (2 chunks / fp32 scratch)
    __shared__ float sEa[192];
    __shared__ int sSrc[64], sDst[64], sGf[64];
    __shared__ float rstat[128];

    const int t = threadIdx.x;
    const int l = t & 63;
    const int wid = t >> 6;
    const int e0 = blockIdx.x * 64;

    if (t < 64) {
        int s = ei[e0 + t];
        sSrc[t] = s;
        sDst[t] = ei[NE + e0 + t];
        sGf[t]  = batch[s];
    }
    if (t < 192) sEa[t] = ea[e0*3 + t];
    __syncthreads();

    // ---- enc1: relu(ea@ew1+b1) -> bufChunk ----
    for (int it = 0; it < 16; ++it) {
        int dw = it*256 + t;
        int e = dw >> 6, cd = dw & 63;
        int c0 = cd*2;
        float x0 = sEa[e*3], x1 = sEa[e*3+1], x2 = sEa[e*3+2];
        float v0 = eb1[c0]   + x0*ew1[c0]   + x1*ew1[HD+c0]   + x2*ew1[2*HD+c0];
        float v1 = eb1[c0+1] + x0*ew1[c0+1] + x1*ew1[HD+c0+1] + x2*ew1[2*HD+c0+1];
        v0 = fmaxf(v0, 0.f); v1 = fmaxf(v1, 0.f);
        int ci = cd >> 2;
        ((u32*)bufChunk)[e*64 + ((ci ^ swzr(e & 15)) << 2) + (cd & 3)] = cvtpk(v0, v1);
    }
    __syncthreads();

    // ---- enc2: relu(A@ew2+b2) -> bufWide chunk0 ----
    {
        f32x4 acc[4][2];
#pragma unroll
        for (int ni = 0; ni < 2; ++ni) {
            float b = eb2[(2*wid + ni)*16 + (l & 15)];
#pragma unroll
            for (int mi = 0; mi < 4; ++mi) acc[mi][ni] = (f32x4){b,b,b,b};
        }
#pragma unroll
        for (int kk = 0; kk < 4; ++kk) {
            short8 af[4];
#pragma unroll
            for (int mi = 0; mi < 4; ++mi) af[mi] = loadA(bufChunk, mi, kk, l);
#pragma unroll
            for (int ni = 0; ni < 2; ++ni) {
                short8 bw = loadB(ew2p, 2*wid + ni, kk, 4, l);
#pragma unroll
                for (int mi = 0; mi < 4; ++mi) acc[mi][ni] = MFMA16(af[mi], bw, acc[mi][ni]);
            }
        }
#pragma unroll
        for (int ni = 0; ni < 2; ++ni) {
            int col = (2*wid + ni)*16 + (l & 15);
#pragma unroll
            for (int mi = 0; mi < 4; ++mi) {
                int R = mi*16 + ((l >> 4) << 2);
                storeQuad((u32*)bufWide, R, col, l,
                          fmaxf(acc[mi][ni][0], 0.f), fmaxf(acc[mi][ni][1], 0.f),
                          fmaxf(acc[mi][ni][2], 0.f), fmaxf(acc[mi][ni][3], 0.f));
            }
        }
    }
    __syncthreads();

    // ---- enc3: W0@ew3+b3 (pre-LN) -> bufChunk ----
    {
        f32x4 acc[4][2];
#pragma unroll
        for (int ni = 0; ni < 2; ++ni) {
            float b = eb3[(2*wid + ni)*16 + (l & 15)];
#pragma unroll
            for (int mi = 0; mi < 4; ++mi) acc[mi][ni] = (f32x4){b,b,b,b};
        }
#pragma unroll
        for (int kk = 0; kk < 4; ++kk) {
            short8 af[4];
#pragma unroll
            for (int mi = 0; mi < 4; ++mi) af[mi] = loadA(bufWide, mi, kk, l);
#pragma unroll
            for (int ni = 0; ni < 2; ++ni) {
                short8 bw = loadB(ew3p, 2*wid + ni, kk, 4, l);
#pragma unroll
                for (int mi = 0; mi < 4; ++mi) acc[mi][ni] = MFMA16(af[mi], bw, acc[mi][ni]);
            }
        }
#pragma unroll
        for (int ni = 0; ni < 2; ++ni) {
            int col = (2*wid + ni)*16 + (l & 15);
#pragma unroll
            for (int mi = 0; mi < 4; ++mi) {
                int R = mi*16 + ((l >> 4) << 2);
                storeQuad((u32*)bufChunk, R, col, l,
                          acc[mi][ni][0], acc[mi][ni][1], acc[mi][ni][2], acc[mi][ni][3]);
            }
        }
    }
    __syncthreads();

    // ---- stage h[src]->bufWide[0], h[dst]->bufWide[1] (enc2 data dead) ----
    stageRows(bufWide,        hbf, sSrc, t);
    stageRows(bufWide + 8192, hbf, sDst, t);

    // ---- LN stats: 4 lanes per edge ----
    {
        int e = wid*16 + (l >> 2);
        int q = l & 3;
        const u32* rowp = (const u32*)bufChunk + e*64;
        float s = 0.f, sq = 0.f;
#pragma unroll
        for (int i = 0; i < 16; ++i) {
            u32 pk = rowp[q*16 + ((i + e) & 15)];
            float a = bf2f(pk & 0xffffu), b = bf2f(pk >> 16);
            s += a + b;
            sq = fmaf(a, a, fmaf(b, b, sq));
        }
        s  += __shfl_xor(s, 1);  sq += __shfl_xor(sq, 1);
        s  += __shfl_xor(s, 2);  sq += __shfl_xor(sq, 2);
        if (q == 0) {
            float mu = s * (1.f/HD);
            rstat[e] = mu;
            rstat[64 + e] = rsqrtf(sq*(1.f/HD) - mu*mu + LN_EPS);
        }
    }
    __syncthreads();

    // ---- normalize in place: bufChunk = ef ----
    for (int it = 0; it < 16; ++it) {
        int pd = it*256 + t;
        int row = pd >> 6, cwd = pd & 63;
        int ci = (cwd >> 2) ^ swzr(row & 15);
        int col = ci*8 + (cwd & 3)*2;
        u32 pk = ((u32*)bufChunk)[pd];
        float mu = rstat[row], ri = rstat[64 + row];
        float v0 = (bf2f(pk & 0xffffu) - mu)*ri*egm[col]     + ebb[col];
        float v1 = (bf2f(pk >> 16)     - mu)*ri*egm[col + 1] + ebb[col + 1];
        ((u32*)bufChunk)[pd] = cvtpk(v0, v1);
    }
    __syncthreads();

    // ---- ep1 MFMA: 2 sequential passes over output-row halves.
    //      Pass ph: MFMA over A rows 32ph..32ph+31 (hsrc ks0-3, hdst ks4-7,
    //      ef ks12-15) -> __syncthreads (all waves' reads of those rows AND
    //      the pass's write-targets are drained) -> epilogue writes rows
    //      32ph..32ph+31 (disjoint from pass-1's A reads, rows 32-63).
#pragma unroll 1
    for (int ph = 0; ph < 2; ++ph) {
        f32x4 acc[2][4];
#pragma unroll
        for (int ni = 0; ni < 4; ++ni) {
            float b = p1b[(4*wid + ni)*16 + (l & 15)];
#pragma unroll
            for (int m = 0; m < 2; ++m) acc[m][ni] = (f32x4){b,b,b,b};
        }
#pragma unroll
        for (int kk = 0; kk < 4; ++kk) {
            short8 af[2];
#pragma unroll
            for (int m = 0; m < 2; ++m) af[m] = loadA(bufWide, 2*ph + m, kk, l);
#pragma unroll
            for (int ni = 0; ni < 4; ++ni) {
                short8 bw = loadB(p1wp, 4*wid + ni, kk, 16, l);
#pragma unroll
                for (int m = 0; m < 2; ++m) acc[m][ni] = MFMA16(af[m], bw, acc[m][ni]);
            }
        }
#pragma unroll
        for (int kk = 0; kk < 4; ++kk) {
            short8 af[2];
#pragma unroll
            for (int m = 0; m < 2; ++m) af[m] = loadA(bufWide + 8192, 2*ph + m, kk, l);
#pragma unroll
            for (int ni = 0; ni < 4; ++ni) {
                short8 bw = loadB(p1wp, 4*wid + ni, 4 + kk, 16, l);
#pragma unroll
                for (int m = 0; m < 2; ++m) acc[m][ni] = MFMA16(af[m], bw, acc[m][ni]);
            }
        }
#pragma unroll
        for (int kk = 0; kk < 4; ++kk) {
            short8 af[2];
#pragma unroll
            for (int m = 0; m < 2; ++m) af[m] = loadA(bufChunk, 2*ph + m, kk, l);
#pragma unroll
            for (int ni = 0; ni < 4; ++ni) {
                short8 bw = loadB(p1wp, 4*wid + ni, 12 + kk, 16, l);
#pragma unroll
                for (int m = 0; m < 2; ++m) acc[m][ni] = MFMA16(af[m], bw, acc[m][ni]);
            }
        }
        __syncthreads();   // all waves done reading this pass's rows; also the
                           // register fence that ends pass-0 acc liveness
        // epilogue: add per-graph gfp1 row, tanh, pack to rows 32ph..32ph+31
#pragma unroll
        for (int m = 0; m < 2; ++m) {
            int R = (2*ph + m)*16 + ((l >> 4) << 2);
            int g0 = sGf[R], g1 = sGf[R+1], g2 = sGf[R+2], g3 = sGf[R+3];
#pragma unroll
            for (int ni = 0; ni < 4; ++ni) {
                int col = (4*wid + ni)*16 + (l & 15);
                u32* dst = (u32*)bufWide + ((col >> 7) << 12);
                int cc = col & 127;
                storeQuad(dst, R, cc, l,
                          fast_tanh(acc[m][ni][0] + gfp1[g0*256 + col]),
                          fast_tanh(acc[m][ni][1] + gfp1[g1*256 + col]),
                          fast_tanh(acc[m][ni][2] + gfp1[g2*256 + col]),
                          fast_tanh(acc[m][ni][3] + gfp1[g3*256 + col]));
            }
        }
    }
    __syncthreads();

    // ---- ep2: [64,256]@p2w[256,128], tanh -> bufChunk ----
    {
        f32x4 acc[4][2];
#pragma unroll
        for (int ni = 0; ni < 2; ++ni) {
            float b = p2b[(2*wid + ni)*16 + (l & 15)];
#pragma unroll
            for (int mi = 0; mi < 4; ++mi) acc[mi][ni] = (f32x4){b,b,b,b};
        }
        for (int kc = 0; kc < 2; ++kc) {
            const u16* abuf = bufWide + (kc << 13);
#pragma unroll
            for (int kk = 0; kk < 4; ++kk) {
                short8 af[4];
#pragma unroll
                for (int mi = 0; mi < 4; ++mi) af[mi] = loadA(abuf, mi, kk, l);
                int ks = kc*4 + kk;
#pragma unroll
                for (int ni = 0; ni < 2; ++ni) {
                    short8 bw = loadB(p2wp, 2*wid + ni, ks, 8, l);
#pragma unroll
                    for (int mi = 0; mi < 4; ++mi) acc[mi][ni] = MFMA16(af[mi], bw, acc[mi][ni]);
                }
            }
        }
#pragma unroll
        for (int ni = 0; ni < 2; ++ni) {
            int col = (2*wid + ni)*16 + (l & 15);
#pragma unroll
            for (int mi = 0; mi < 4; ++mi) {
                int R = mi*16 + ((l >> 4) << 2);
                storeQuad((u32*)bufChunk, R, col, l,
                          fast_tanh(acc[mi][ni][0]), fast_tanh(acc[mi][ni][1]),
                          fast_tanh(acc[mi][ni][2]), fast_tanh(acc[mi][ni][3]));
            }
        }
    }
    __syncthreads();

    // ---- ep3: [64,128]@p3w[128,64], relu -> bufWide fp32 stride-65 ----
    {
        f32x4 acc[4];
        {
            float b = p3b[wid*16 + (l & 15)];
#pragma unroll
            for (int mi = 0; mi < 4; ++mi) acc[mi] = (f32x4){b,b,b,b};
        }
#pragma unroll
        for (int kk = 0; kk < 4; ++kk) {
            short8 af[4];
#pragma unroll
            for (int mi = 0; mi < 4; ++mi) af[mi] = loadA(bufChunk, mi, kk, l);
            short8 bw = loadB(p3wp, wid, kk, 4, l);
#pragma unroll
            for (int mi = 0; mi < 4; ++mi) acc[mi] = MFMA16(af[mi], bw, acc[mi]);
        }
        float* fb = (float*)bufWide;
        int col = wid*16 + (l & 15);
#pragma unroll
        for (int mi = 0; mi < 4; ++mi)
#pragma unroll
            for (int rr = 0; rr < 4; ++rr) {
                int row = mi*16 + ((l >> 4) << 2) + rr;
                fb[row*65 + col] = fmaxf(acc[mi][rr], 0.f);
            }
    }
    __syncthreads();

    // ---- ep4: 4 lanes/edge dot-64 + sigmoid ----
    {
        const float* fb = (const float*)bufWide;
        int e = wid*16 + (l >> 2), q = l & 3;
        float v = 0.f;
#pragma unroll
        for (int k = 0; k < 16; ++k) {
            int i = q*16 + k;
            v = fmaf(fb[e*65 + i], p4w[i], v);
        }
        v += __shfl_xor(v, 1);
        v += __shfl_xor(v, 2);
        if (q == 0) out[e0 + e] = fast_sigmoid(v + p4b[0]);
    }
}

// ---------------------------------------------------------------------------
extern "C" void kernel_launch(void* const* d_in, const int* in_sizes, int n_in,
                              void* d_out, int out_size, void* d_ws, size_t ws_size,
                              hipStream_t stream)
{
    const float* x     = (const float*)d_in[0];
    const int*   ei    = (const int*)  d_in[1];
    const float* ea    = (const float*)d_in[2];
    const int*   batch = (const int*)  d_in[3];
    const float* ne1w = (const float*)d_in[4];  const float* ne1b = (const float*)d_in[5];
    const float* ne2w = (const float*)d_in[6];  const float* ne2b = (const float*)d_in[7];
    const float* ne3w = (const float*)d_in[8];  const float* ne3b = (const float*)d_in[9];
    const float* neg  = (const float*)d_in[10]; const float* nebb = (const float*)d_in[11];
    const float* ee1w = (const float*)d_in[12]; const float* ee1b = (const float*)d_in[13];
    const float* ee2w = (const float*)d_in[14]; const float* ee2b = (const float*)d_in[15];
    const float* ee3w = (const float*)d_in[16]; const float* ee3b = (const float*)d_in[17];
    const float* eeg  = (const float*)d_in[18]; const float* eebb = (const float*)d_in[19];
    const float* g1w  = (const float*)d_in[20]; const float* g1b  = (const float*)d_in[21];
    const float* g2w  = (const float*)d_in[22]; const float* g2b  = (const float*)d_in[23];
    const float* gp1w = (const float*)d_in[24]; const float* gp1b = (const float*)d_in[25];
    const float* gp2w = (const float*)d_in[26]; const float* gp2b = (const float*)d_in[27];
    const float* gpg  = (const float*)d_in[28]; const float* gpbb = (const float*)d_in[29];
    const float* p1w  = (const float*)d_in[30]; const float* p1b  = (const float*)d_in[31];
    const float* p2w  = (const float*)d_in[32]; const float* p2b  = (const float*)d_in[33];
    const float* p3w  = (const float*)d_in[34]; const float* p3b  = (const float*)d_in[35];
    const float* p4w  = (const float*)d_in[36]; const float* p4b  = (const float*)d_in[37];

    float* dinv = (float*)d_ws;                // NN
    float* sums = dinv + NN;                   // NG*HD
    float* cnts = sums + NG*HD;                // NG
    float* gfp1 = cnts + NG;                   // NG*256
    int* degi   = (int*)(gfp1 + NG*256);       // NN
    int* cursor = degi + NN;                   // NN+2
    int* rowptr = cursor + NN + 2;             // NN+2
    int* sadj   = rowptr + NN + 2;             // NE
    u16* xw1p   = (u16*)(sadj + NE);           // NN*HD
    u16* xw2p   = xw1p + (size_t)NN*HD;        // NN*HD
    u16* hbf    = xw2p + (size_t)NN*HD;        // NN*HD
    u16* wpk    = hbf + (size_t)NN*HD;         // 270336
    u16* ee2p = wpk;
    u16* ee3p = wpk + 16384;
    u16* p1p  = wpk + 32768;
    u16* p2p  = wpk + 163840;
    u16* p3p  = wpk + 196608;
    u16* ne2p = wpk + 204800;
    u16* ne3p = wpk + 221184;
    u16* g1p  = wpk + 237568;
    u16* g2p  = wpk + 253952;

    float* out = (float*)d_out;

    hipMemsetAsync(degi, 0, (size_t)(2*NN + 2)*sizeof(int), stream);
    hipMemsetAsync(sums, 0, (size_t)(NG*HD + NG)*sizeof(float), stream);

    pack_all<<<(270336 + 255)/256, 256, 0, stream>>>(ee2w, ee3w, p1w, p2w, p3w,
                                                     ne2w, ne3w, g1w, g2w, wpk);

    // CSR build (+dinv fused into scan)
    deg_count_int<<<(NE + 255)/256, 256, 0, stream>>>(ei, degi);
    scan_excl<<<1, 1024, 0, stream>>>(degi, rowptr, dinv);
    fill_csr<<<(NE + 255)/256, 256, 0, stream>>>(ei, rowptr, cursor, sadj);

    // node encoder + g1 GEMM (bf16 out, prescaled by dinv)
    enc_mfma<<<(NN + 63)/64, 256, 0, stream>>>(x, ne1w, ne1b, ne2p, ne2b, ne3p, ne3b,
                                               neg, nebb, g1p, dinv, (u32*)xw1p);
    // GCN1 gather + relu + g2 GEMM
    gcn_agg1_mfma<<<(NN + 63)/64, 256, 0, stream>>>(xw1p, rowptr, sadj, dinv,
                                                    g1b, g2p, (u32*)xw2p);
    // GCN2 gather -> hbf bf16
    gcn_agg2_gather<<<(NN + 63)/64, 256, 0, stream>>>(xw2p, rowptr, sadj, dinv,
                                                      g2b, (u32*)hbf);

    // pool (+counts fused) + graph MLP (+gfp1 precompute)
    pool_sorted<<<POOL_B, 128, 0, stream>>>(hbf, batch, sums, cnts);
    graph_feat<<<NG, 128, 0, stream>>>(sums, cnts, gp1w, gp1b, gp2w, gp2b,
                                       gpg, gpbb, p1w, gfp1);

    // fused edge encoder + edge-score MLP
    edge_mlp_mfma<<<NE/64, 256, 0, stream>>>(hbf, gfp1, ei, batch, ea,
                                             ee1w, ee1b, ee2p, ee2b, ee3p, ee3b,
                                             eeg, eebb,
                                             p1p, p1b, p2p, p2b, p3p, p3b,
                                             p4w, p4b, out);
}

// Round 12
// 639.276 us; speedup vs baseline: 1.3615x; 1.3615x over previous
//
#include <hip/hip_runtime.h>
#include <math.h>

#define NN 50000
#define NE 400000
#define NG 64
#define HD 128
#define LN_EPS 1e-5f

typedef unsigned short u16;
typedef unsigned int u32;
typedef __attribute__((ext_vector_type(8))) short short8;
typedef __attribute__((ext_vector_type(4))) float f32x4;

#define MFMA16(a,b,c) __builtin_amdgcn_mfma_f32_16x16x32_bf16((a),(b),(c),0,0,0)

__device__ __forceinline__ u16 f2bf(float f) {
    union { float f; u32 u; } v; v.f = f;
    u32 r = v.u + 0x7FFFu + ((v.u >> 16) & 1u);
    return (u16)(r >> 16);
}
__device__ __forceinline__ float bf2f(u32 hs) {
    union { u32 u; float f; } v; v.u = hs << 16;
    return v.f;
}
__device__ __forceinline__ float fast_rcp(float x) {
    float r; asm("v_rcp_f32 %0, %1" : "=v"(r) : "v"(x)); return r;
}
__device__ __forceinline__ float fast_exp2(float x) {
    float r; asm("v_exp_f32 %0, %1" : "=v"(r) : "v"(x)); return r;
}
__device__ __forceinline__ u32 cvtpk(float lo, float hi) {
    u32 r; asm("v_cvt_pk_bf16_f32 %0, %1, %2" : "=v"(r) : "v"(lo), "v"(hi)); return r;
}
// tanh(x) = 1 - 2/(1+2^(2*log2e*x)); exp2 saturates correctly at +-inf
__device__ __forceinline__ float fast_tanh(float x) {
    return fmaf(-2.f, fast_rcp(1.f + fast_exp2(2.885390082f * x)), 1.f);
}
__device__ __forceinline__ float fast_sigmoid(float x) {
    return fast_rcp(1.f + fast_exp2(-1.442695041f * x));
}

// swizzle term for row within 16-row group
__device__ __forceinline__ int swzr(int row) {
    return (row & 7) ^ ((row & 8) >> 2);
}

// A-fragment load from swizzled [64][128] bf16 chunk buffer.
__device__ __forceinline__ short8 loadA(const u16* buf, int mi, int kk, int l) {
    int row = mi*16 + (l & 15);
    int ci  = (kk*4 + (l >> 4)) ^ swzr(l & 15);
    return *(const short8*)(buf + row*128 + (ci << 3));
}
__device__ __forceinline__ short8 loadB(const u16* wp, int nt, int ks, int nk, int l) {
    return *(const short8*)(wp + (((nt*nk + ks)*64 + l) << 3));
}

// Store 4 accumulator values (rows R..R+3, col c) into swizzled bf16 chunk as
// packed u32 via lane-pair exchange + v_cvt_pk_bf16_f32.
__device__ __forceinline__ void storeQuad(u32* buf, int R, int c, int l,
                                          float v0, float v1, float v2, float v3)
{
    int cw = c >> 1;
    int par = l & 1;
    float send = par ? v0 : v1;
    float recv = __shfl_xor(send, 1);
    int row = R + par;
    u32 word = par ? cvtpk(recv, v1) : cvtpk(v0, recv);
    buf[row*64 + (((cw >> 2) ^ swzr(row & 15)) << 2) + (cw & 3)] = word;
    send = par ? v2 : v3;
    recv = __shfl_xor(send, 1);
    row = R + 2 + par;
    word = par ? cvtpk(recv, v3) : cvtpk(v2, recv);
    buf[row*64 + (((cw >> 2) ^ swzr(row & 15)) << 2) + (cw & 3)] = word;
}

// Unswizzle copy: LDS chunk -> global bf16 [64][128] rows n0..n0+63 (u32 words)
__device__ __forceinline__ void copyChunkOut(const u32* chunk, u32* gout, int n0, int t)
{
    for (int it = 0; it < 16; ++it) {
        int dw = it*256 + t;
        int row = dw >> 6, cw = dw & 63;
        if (n0 + row < NN)
            gout[(size_t)(n0 + row)*64 + cw] =
                chunk[row*64 + (((cw >> 2) ^ swzr(row & 15)) << 2) + (cw & 3)];
    }
}

// ---------------------------------------------------------------------------
// One-shot weight packing of all 9 GEMM weights -> bf16 MFMA B-fragment order.
// ---------------------------------------------------------------------------
__global__ __launch_bounds__(256)
void pack_all(const float* __restrict__ ee2w, const float* __restrict__ ee3w,
              const float* __restrict__ p1w,  const float* __restrict__ p2w,
              const float* __restrict__ p3w,  const float* __restrict__ ne2w,
              const float* __restrict__ ne3w, const float* __restrict__ g1w,
              const float* __restrict__ g2w,  u16* __restrict__ wpk)
{
    int idx = blockIdx.x*256 + threadIdx.x;
    if (idx >= 270336) return;
    const float* w; int K, N, local;
    if      (idx < 16384)  { w = ee2w; K = 128; N = 128; local = idx; }
    else if (idx < 32768)  { w = ee3w; K = 128; N = 128; local = idx - 16384; }
    else if (idx < 163840) { w = p1w;  K = 512; N = 256; local = idx - 32768; }
    else if (idx < 196608) { w = p2w;  K = 256; N = 128; local = idx - 163840; }
    else if (idx < 204800) { w = p3w;  K = 128; N = 64;  local = idx - 196608; }
    else if (idx < 221184) { w = ne2w; K = 128; N = 128; local = idx - 204800; }
    else if (idx < 237568) { w = ne3w; K = 128; N = 128; local = idx - 221184; }
    else if (idx < 253952) { w = g1w;  K = 128; N = 128; local = idx - 237568; }
    else                   { w = g2w;  K = 128; N = 128; local = idx - 253952; }
    int e = local & 7, l = (local >> 3) & 63, r = local >> 9;
    int nk = K >> 5;
    int nt = r / nk, kk = r % nk;
    int k = kk*32 + ((l >> 4) << 3) + e;
    int n = nt*16 + (l & 15);
    wpk[idx] = f2bf(w[k*N + n]);
}

// ---------------------------------------------------------------------------
// CSR build
// ---------------------------------------------------------------------------
__global__ __launch_bounds__(256)
void deg_count_int(const int* __restrict__ ei, int* __restrict__ degi)
{
    int e = blockIdx.x*256 + threadIdx.x;
    if (e < NE) atomicAdd(&degi[ei[NE + e]], 1);
}

__global__ __launch_bounds__(1024)
void scan_excl(const int* __restrict__ cnt, int* __restrict__ rp,
               float* __restrict__ dinv)
{
    __shared__ int wsum[16];
    __shared__ int carry;
    int t = threadIdx.x, lane = t & 63, w = t >> 6;
    int base = 0;
    for (int off = 0; off < NN; off += 4096) {
        int i0 = off + t*4;
        int v0 = (i0   < NN) ? cnt[i0]   : 0;
        int v1 = (i0+1 < NN) ? cnt[i0+1] : 0;
        int v2 = (i0+2 < NN) ? cnt[i0+2] : 0;
        int v3 = (i0+3 < NN) ? cnt[i0+3] : 0;
        int tot = v0 + v1 + v2 + v3;
        int s = tot;
#pragma unroll
        for (int d = 1; d < 64; d <<= 1) { int u = __shfl_up(s, d); if (lane >= d) s += u; }
        if (lane == 63) wsum[w] = s;
        __syncthreads();
        if (w == 0) {
            int wv = (lane < 16) ? wsum[lane] : 0;
            int ss = wv;
#pragma unroll
            for (int d = 1; d < 16; d <<= 1) { int u = __shfl_up(ss, d); if (lane >= d) ss += u; }
            if (lane < 16) wsum[lane] = ss - wv;
            if (lane == 15) carry = ss;
        }
        __syncthreads();
        int excl = base + wsum[w] + s - tot;
        if (i0   < NN) { rp[i0]   = excl;              dinv[i0]   = rsqrtf((float)v0 + 1.f); }
        if (i0+1 < NN) { rp[i0+1] = excl + v0;         dinv[i0+1] = rsqrtf((float)v1 + 1.f); }
        if (i0+2 < NN) { rp[i0+2] = excl + v0 + v1;    dinv[i0+2] = rsqrtf((float)v2 + 1.f); }
        if (i0+3 < NN) { rp[i0+3] = excl + v0 + v1 + v2; dinv[i0+3] = rsqrtf((float)v3 + 1.f); }
        base += carry;
        __syncthreads();
    }
    if (t == 0) rp[NN] = base;
}

__global__ __launch_bounds__(256)
void fill_csr(const int* __restrict__ ei, const int* __restrict__ rp,
              int* __restrict__ cursor, int* __restrict__ sadj)
{
    int e = blockIdx.x*256 + threadIdx.x;
    if (e >= NE) return;
    int d = ei[NE + e];
    int slot = atomicAdd(&cursor[d], 1);
    sadj[rp[d] + slot] = ei[e];
}

// ---------------------------------------------------------------------------
// Node encoder + g1w GEMM, MFMA. 64 nodes/block, 256 threads.
// ---------------------------------------------------------------------------
__global__ __launch_bounds__(256, 4)
void enc_mfma(const float* __restrict__ x,
              const float* __restrict__ w1, const float* __restrict__ b1,
              const u16* __restrict__ w2p, const float* __restrict__ b2,
              const u16* __restrict__ w3p, const float* __restrict__ b3,
              const float* __restrict__ gg, const float* __restrict__ bb,
              const u16* __restrict__ g1p, const float* __restrict__ dinv,
              u32* __restrict__ xw1p)
{
    __shared__ u16 chunkA[64*HD];
    __shared__ u16 chunkB[64*HD];
    __shared__ float sX[192];
    __shared__ float sDi[64];
    __shared__ float rstat[128];

    const int t = threadIdx.x;
    const int l = t & 63;
    const int wid = t >> 6;
    const int n0 = blockIdx.x * 64;

    if (t < 192) sX[t] = (n0*3 + t < NN*3) ? x[n0*3 + t] : 0.f;
    if (t < 64)  sDi[t] = (n0 + t < NN) ? dinv[n0 + t] : 0.f;
    __syncthreads();

    // L1: 3->128 relu (VALU) -> chunkA
    for (int it = 0; it < 16; ++it) {
        int dw = it*256 + t;
        int e = dw >> 6, cd = dw & 63;
        int c0 = cd*2;
        float x0 = sX[e*3], x1 = sX[e*3+1], x2 = sX[e*3+2];
        float v0 = b1[c0]   + x0*w1[c0]   + x1*w1[HD+c0]   + x2*w1[2*HD+c0];
        float v1 = b1[c0+1] + x0*w1[c0+1] + x1*w1[HD+c0+1] + x2*w1[2*HD+c0+1];
        v0 = fmaxf(v0, 0.f); v1 = fmaxf(v1, 0.f);
        int ci = cd >> 2;
        ((u32*)chunkA)[e*64 + ((ci ^ swzr(e & 15)) << 2) + (cd & 3)] = cvtpk(v0, v1);
    }
    __syncthreads();

    // L2 MFMA: relu(A@w2+b2) -> chunkB
    {
        f32x4 acc[4][2];
#pragma unroll
        for (int ni = 0; ni < 2; ++ni) {
            float b = b2[(2*wid + ni)*16 + (l & 15)];
#pragma unroll
            for (int mi = 0; mi < 4; ++mi) acc[mi][ni] = (f32x4){b,b,b,b};
        }
#pragma unroll
        for (int kk = 0; kk < 4; ++kk) {
            short8 af[4];
#pragma unroll
            for (int mi = 0; mi < 4; ++mi) af[mi] = loadA(chunkA, mi, kk, l);
#pragma unroll
            for (int ni = 0; ni < 2; ++ni) {
                short8 bw = loadB(w2p, 2*wid + ni, kk, 4, l);
#pragma unroll
                for (int mi = 0; mi < 4; ++mi) acc[mi][ni] = MFMA16(af[mi], bw, acc[mi][ni]);
            }
        }
#pragma unroll
        for (int ni = 0; ni < 2; ++ni) {
            int col = (2*wid + ni)*16 + (l & 15);
#pragma unroll
            for (int mi = 0; mi < 4; ++mi) {
                int R = mi*16 + ((l >> 4) << 2);
                storeQuad((u32*)chunkB, R, col, l,
                          fmaxf(acc[mi][ni][0], 0.f), fmaxf(acc[mi][ni][1], 0.f),
                          fmaxf(acc[mi][ni][2], 0.f), fmaxf(acc[mi][ni][3], 0.f));
            }
        }
    }
    __syncthreads();

    // L3 MFMA: B@w3+b3 (pre-LN) -> chunkA
    {
        f32x4 acc[4][2];
#pragma unroll
        for (int ni = 0; ni < 2; ++ni) {
            float b = b3[(2*wid + ni)*16 + (l & 15)];
#pragma unroll
            for (int mi = 0; mi < 4; ++mi) acc[mi][ni] = (f32x4){b,b,b,b};
        }
#pragma unroll
        for (int kk = 0; kk < 4; ++kk) {
            short8 af[4];
#pragma unroll
            for (int mi = 0; mi < 4; ++mi) af[mi] = loadA(chunkB, mi, kk, l);
#pragma unroll
            for (int ni = 0; ni < 2; ++ni) {
                short8 bw = loadB(w3p, 2*wid + ni, kk, 4, l);
#pragma unroll
                for (int mi = 0; mi < 4; ++mi) acc[mi][ni] = MFMA16(af[mi], bw, acc[mi][ni]);
            }
        }
#pragma unroll
        for (int ni = 0; ni < 2; ++ni) {
            int col = (2*wid + ni)*16 + (l & 15);
#pragma unroll
            for (int mi = 0; mi < 4; ++mi) {
                int R = mi*16 + ((l >> 4) << 2);
                storeQuad((u32*)chunkA, R, col, l,
                          acc[mi][ni][0], acc[mi][ni][1], acc[mi][ni][2], acc[mi][ni][3]);
            }
        }
    }
    __syncthreads();

    // LN stats: 4 lanes per row
    {
        int e = wid*16 + (l >> 2);
        int q = l & 3;
        const u32* rowp = (const u32*)chunkA + e*64;
        float s = 0.f, sq = 0.f;
#pragma unroll
        for (int i = 0; i < 16; ++i) {
            u32 pk = rowp[q*16 + ((i + e) & 15)];
            float a = bf2f(pk & 0xffffu), b = bf2f(pk >> 16);
            s += a + b;
            sq = fmaf(a, a, fmaf(b, b, sq));
        }
        s  += __shfl_xor(s, 1);  sq += __shfl_xor(sq, 1);
        s  += __shfl_xor(s, 2);  sq += __shfl_xor(sq, 2);
        if (q == 0) {
            float mu = s * (1.f/HD);
            rstat[e] = mu;
            rstat[64 + e] = rsqrtf(sq*(1.f/HD) - mu*mu + LN_EPS);
        }
    }
    __syncthreads();

    // normalize in place
    for (int it = 0; it < 16; ++it) {
        int pd = it*256 + t;
        int row = pd >> 6, cwd = pd & 63;
        int ci = (cwd >> 2) ^ swzr(row & 15);
        int col = ci*8 + (cwd & 3)*2;
        u32 pk = ((u32*)chunkA)[pd];
        float mu = rstat[row], ri = rstat[64 + row];
        float v0 = (bf2f(pk & 0xffffu) - mu)*ri*gg[col]     + bb[col];
        float v1 = (bf2f(pk >> 16)     - mu)*ri*gg[col + 1] + bb[col + 1];
        ((u32*)chunkA)[pd] = cvtpk(v0, v1);
    }
    __syncthreads();

    // GEMM @g1w, scale by dinv -> chunkB -> global
    {
        f32x4 acc[4][2];
#pragma unroll
        for (int mi = 0; mi < 4; ++mi)
#pragma unroll
            for (int ni = 0; ni < 2; ++ni) acc[mi][ni] = (f32x4){0.f,0.f,0.f,0.f};
#pragma unroll
        for (int kk = 0; kk < 4; ++kk) {
            short8 af[4];
#pragma unroll
            for (int mi = 0; mi < 4; ++mi) af[mi] = loadA(chunkA, mi, kk, l);
#pragma unroll
            for (int ni = 0; ni < 2; ++ni) {
                short8 bw = loadB(g1p, 2*wid + ni, kk, 4, l);
#pragma unroll
                for (int mi = 0; mi < 4; ++mi) acc[mi][ni] = MFMA16(af[mi], bw, acc[mi][ni]);
            }
        }
#pragma unroll
        for (int ni = 0; ni < 2; ++ni) {
            int col = (2*wid + ni)*16 + (l & 15);
#pragma unroll
            for (int mi = 0; mi < 4; ++mi) {
                int R = mi*16 + ((l >> 4) << 2);
                storeQuad((u32*)chunkB, R, col, l,
                          acc[mi][ni][0]*sDi[R], acc[mi][ni][1]*sDi[R+1],
                          acc[mi][ni][2]*sDi[R+2], acc[mi][ni][3]*sDi[R+3]);
            }
        }
    }
    __syncthreads();
    copyChunkOut((const u32*)chunkB, xw1p, n0, t);
}

// ---------------------------------------------------------------------------
// GCN layer 1: gather bf16 xw1p (prescaled), relu(+g1b), MFMA @g2w, *dinv -> xw2p
// ---------------------------------------------------------------------------
__global__ __launch_bounds__(256, 4)
void gcn_agg1_mfma(const u16* __restrict__ xw1p, const int* __restrict__ rp,
                   const int* __restrict__ sadj, const float* __restrict__ dinv,
                   const float* __restrict__ g1b, const u16* __restrict__ g2p,
                   u32* __restrict__ xw2p)
{
    __shared__ u16 chunkA[64*HD];
    __shared__ u16 chunkB[64*HD];
    __shared__ float sDi[64];
    __shared__ float sB[HD];

    const int t = threadIdx.x;
    const int l = t & 63;
    const int wid = t >> 6;
    const int n0 = blockIdx.x * 64;

    if (t < 64)  sDi[t] = (n0 + t < NN) ? dinv[n0 + t] : 0.f;
    if (t < HD)  sB[t] = g1b[t];
    __syncthreads();

    {
        int s = t >> 2, part = t & 3, n = n0 + s;
        float acc[32];
#pragma unroll
        for (int j = 0; j < 32; ++j) acc[j] = 0.f;
        float di = 0.f;
        if (n < NN) {
            di = sDi[s];
            const short8* selfp = (const short8*)(xw1p + (size_t)n*HD + part*32);
#pragma unroll
            for (int w = 0; w < 4; ++w) {
                short8 v = selfp[w];
#pragma unroll
                for (int j = 0; j < 8; ++j) acc[w*8+j] += bf2f((u16)v[j]);
            }
            int k1 = rp[n+1];
            for (int k = rp[n]; k < k1; ++k) {
                const short8* rp8 = (const short8*)(xw1p + (size_t)sadj[k]*HD + part*32);
#pragma unroll
                for (int w = 0; w < 4; ++w) {
                    short8 v = rp8[w];
#pragma unroll
                    for (int j = 0; j < 8; ++j) acc[w*8+j] += bf2f((u16)v[j]);
                }
            }
        }
#pragma unroll
        for (int p = 0; p < 16; ++p) {
            float v0 = fmaxf(fmaf(acc[2*p],   di, sB[part*32 + 2*p]),   0.f);
            float v1 = fmaxf(fmaf(acc[2*p+1], di, sB[part*32 + 2*p+1]), 0.f);
            int cw = part*16 + p;
            ((u32*)chunkA)[s*64 + (((cw >> 2) ^ swzr(s & 15)) << 2) + (cw & 3)] = cvtpk(v0, v1);
        }
    }
    __syncthreads();

    {
        f32x4 acc[4][2];
#pragma unroll
        for (int mi = 0; mi < 4; ++mi)
#pragma unroll
            for (int ni = 0; ni < 2; ++ni) acc[mi][ni] = (f32x4){0.f,0.f,0.f,0.f};
#pragma unroll
        for (int kk = 0; kk < 4; ++kk) {
            short8 af[4];
#pragma unroll
            for (int mi = 0; mi < 4; ++mi) af[mi] = loadA(chunkA, mi, kk, l);
#pragma unroll
            for (int ni = 0; ni < 2; ++ni) {
                short8 bw = loadB(g2p, 2*wid + ni, kk, 4, l);
#pragma unroll
                for (int mi = 0; mi < 4; ++mi) acc[mi][ni] = MFMA16(af[mi], bw, acc[mi][ni]);
            }
        }
#pragma unroll
        for (int ni = 0; ni < 2; ++ni) {
            int col = (2*wid + ni)*16 + (l & 15);
#pragma unroll
            for (int mi = 0; mi < 4; ++mi) {
                int R = mi*16 + ((l >> 4) << 2);
                storeQuad((u32*)chunkB, R, col, l,
                          acc[mi][ni][0]*sDi[R], acc[mi][ni][1]*sDi[R+1],
                          acc[mi][ni][2]*sDi[R+2], acc[mi][ni][3]*sDi[R+3]);
            }
        }
    }
    __syncthreads();
    copyChunkOut((const u32*)chunkB, xw2p, n0, t);
}

// ---------------------------------------------------------------------------
// GCN layer 2: gather bf16 xw2p, +g2b -> hbf (bf16 only)
// ---------------------------------------------------------------------------
__global__ __launch_bounds__(256)
void gcn_agg2_gather(const u16* __restrict__ xw2p, const int* __restrict__ rp,
                     const int* __restrict__ sadj, const float* __restrict__ dinv,
                     const float* __restrict__ g2b, u32* __restrict__ hbw)
{
    int t = threadIdx.x;
    int s = t >> 2, part = t & 3;
    int n = blockIdx.x * 64 + s;
    if (n >= NN) return;
    float acc[32];
#pragma unroll
    for (int j = 0; j < 32; ++j) acc[j] = 0.f;
    const short8* selfp = (const short8*)(xw2p + (size_t)n*HD + part*32);
#pragma unroll
    for (int w = 0; w < 4; ++w) {
        short8 v = selfp[w];
#pragma unroll
        for (int j = 0; j < 8; ++j) acc[w*8+j] += bf2f((u16)v[j]);
    }
    int k1 = rp[n+1];
    for (int k = rp[n]; k < k1; ++k) {
        const short8* rp8 = (const short8*)(xw2p + (size_t)sadj[k]*HD + part*32);
#pragma unroll
        for (int w = 0; w < 4; ++w) {
            short8 v = rp8[w];
#pragma unroll
            for (int j = 0; j < 8; ++j) acc[w*8+j] += bf2f((u16)v[j]);
        }
    }
    float di = dinv[n];
    u32* hb = hbw + (size_t)n*64 + part*16;
#pragma unroll
    for (int p = 0; p < 16; ++p) {
        float v0 = fmaf(acc[2*p],   di, g2b[part*32 + 2*p]);
        float v1 = fmaf(acc[2*p+1], di, g2b[part*32 + 2*p+1]);
        hb[p] = cvtpk(v0, v1);
    }
}

// ---------------------------------------------------------------------------
// Pool (batch sorted, bf16 input) + fused counts + graph MLP.
// graph_feat also precomputes gfp1t[col][g] = (gf[g] @ p1w[256:384,:])[col]
// (TRANSPOSED layout: epilogue lane reads 4 g's from one 256B row).
// ---------------------------------------------------------------------------
#define POOL_B 512
__global__ __launch_bounds__(128)
void pool_sorted(const u16* __restrict__ h, const int* __restrict__ batch,
                 float* __restrict__ sums, float* __restrict__ cnts)
{
    int b = blockIdx.x, j = threadIdx.x;
    int n0 = (int)(((long long)NN * b) / POOL_B);
    int n1 = (int)(((long long)NN * (b+1)) / POOL_B);
    int g = -1; float acc = 0.f, cl = 0.f;
    for (int n = n0; n < n1; ++n) {
        int bg = batch[n];
        if (bg != g) {
            if (g >= 0) {
                atomicAdd(&sums[g*HD + j], acc);
                if (j == 0) atomicAdd(&cnts[g], cl);
            }
            g = bg; acc = 0.f; cl = 0.f;
        }
        acc += bf2f(h[(size_t)n*HD + j]);
        cl += 1.f;
    }
    if (g >= 0) {
        atomicAdd(&sums[g*HD + j], acc);
        if (j == 0) atomicAdd(&cnts[g], cl);
    }
}

__global__ __launch_bounds__(128)
void graph_feat(const float* __restrict__ sums, const float* __restrict__ cnts,
                const float* __restrict__ w1, const float* __restrict__ b1,
                const float* __restrict__ w2, const float* __restrict__ b2,
                const float* __restrict__ gg, const float* __restrict__ bb,
                const float* __restrict__ p1w, float* __restrict__ gfp1t)
{
    int gi = blockIdx.x, j = threadIdx.x;
    __shared__ float s0[HD];
    __shared__ float s1[HD];
    __shared__ float part[4];
    __shared__ float stat[2];
    float cnt = fmaxf(cnts[gi], 1.f);
    s0[j] = sums[gi*HD + j] / cnt;
    __syncthreads();
    float a = b1[j];
    for (int i = 0; i < HD; ++i) a = fmaf(s0[i], w1[i*HD + j], a);
    s1[j] = fmaxf(a, 0.f);
    __syncthreads();
    a = b2[j];
    for (int i = 0; i < HD; ++i) a = fmaf(s1[i], w2[i*HD + j], a);
    float s = a, q = a*a;
    for (int o = 32; o > 0; o >>= 1) { s += __shfl_down(s, o); q += __shfl_down(q, o); }
    int wid = j >> 6, lane = j & 63;
    if (lane == 0) { part[wid] = s; part[2 + wid] = q; }
    __syncthreads();
    if (j == 0) {
        float S = part[0] + part[1], Q = part[2] + part[3];
        float mu = S * (1.f/HD);
        stat[0] = mu;
        stat[1] = Q * (1.f/HD) - mu*mu;
    }
    __syncthreads();
    float v = (a - stat[0]) * rsqrtf(stat[1] + LN_EPS) * gg[j] + bb[j];
    __syncthreads();
    s0[j] = v;        // gf row for this graph (fp32)
    __syncthreads();
    // transposed: gfp1t[col*NG + gi]
    float a0 = 0.f, a1 = 0.f;
    for (int k = 0; k < HD; ++k) {
        float gv = s0[k];
        a0 = fmaf(gv, p1w[(size_t)(256 + k)*256 + j],       a0);
        a1 = fmaf(gv, p1w[(size_t)(256 + k)*256 + j + 128], a1);
    }
    gfp1t[(size_t)j*NG + gi]         = a0;
    gfp1t[(size_t)(j + 128)*NG + gi] = a1;
}

// ---------------------------------------------------------------------------
// Stage 64 gathered bf16 rows into swizzled LDS chunk (4 threads/row)
// ---------------------------------------------------------------------------
__device__ __forceinline__ void stageRows(u16* dst, const u16* __restrict__ srcBase,
                                          const int* ridx, int t)
{
    int e = t >> 2, part = t & 3;
    const u16* src = srcBase + (size_t)ridx[e]*HD + part*32;
    u16* drow = dst + e*128;
    int re = swzr(e & 15);
#pragma unroll
    for (int w = 0; w < 4; ++w) {
        int ci = (part*4 + w) ^ re;
        *(short8*)(drow + (ci << 3)) = *(const short8*)(src + w*8);
    }
}

// ---------------------------------------------------------------------------
// Fused edge kernel (MFMA bf16). 64 edges/block, 256 threads, 3 blocks/CU.
// Round-8 structure (empirical best): gfp1-factored ep1, full-unroll 2-phase
// (compiler merges; moderate spill accepted — 3blk beats clean 2blk).
// gfp1 is TRANSPOSED [col][G] for epilogue load locality.
// ---------------------------------------------------------------------------
__global__ __launch_bounds__(256, 3)
void edge_mlp_mfma(const u16* __restrict__ hbf, const float* __restrict__ gfp1t,
                   const int* __restrict__ ei, const int* __restrict__ batch,
                   const float* __restrict__ ea,
                   const float* __restrict__ ew1, const float* __restrict__ eb1,
                   const u16* __restrict__ ew2p, const float* __restrict__ eb2,
                   const u16* __restrict__ ew3p, const float* __restrict__ eb3,
                   const float* __restrict__ egm, const float* __restrict__ ebb,
                   const u16* __restrict__ p1wp, const float* __restrict__ p1b,
                   const u16* __restrict__ p2wp, const float* __restrict__ p2b,
                   const u16* __restrict__ p3wp, const float* __restrict__ p3b,
                   const float* __restrict__ p4w, const float* __restrict__ p4b,
                   float* __restrict__ out)
{
    __shared__ u16 bufChunk[64*HD];    // 16KB swizzled A-chunk
    __shared__ u16 bufWide[64*256];    // 32KB (2 chunks / fp32 scratch)
    __shared__ float sEa[192];
    __shared__ int sSrc[64], sDst[64], sGf[64];
    __shared__ float rstat[128];

    const int t = threadIdx.x;
    const int l = t & 63;
    const int wid = t >> 6;
    const int e0 = blockIdx.x * 64;

    if (t < 64) {
        int s = ei[e0 + t];
        sSrc[t] = s;
        sDst[t] = ei[NE + e0 + t];
        sGf[t]  = batch[s];
    }
    if (t < 192) sEa[t] = ea[e0*3 + t];
    __syncthreads();

    // ---- enc1: relu(ea@ew1+b1) -> bufChunk ----
    for (int it = 0; it < 16; ++it) {
        int dw = it*256 + t;
        int e = dw >> 6, cd = dw & 63;
        int c0 = cd*2;
        float x0 = sEa[e*3], x1 = sEa[e*3+1], x2 = sEa[e*3+2];
        float v0 = eb1[c0]   + x0*ew1[c0]   + x1*ew1[HD+c0]   + x2*ew1[2*HD+c0];
        float v1 = eb1[c0+1] + x0*ew1[c0+1] + x1*ew1[HD+c0+1] + x2*ew1[2*HD+c0+1];
        v0 = fmaxf(v0, 0.f); v1 = fmaxf(v1, 0.f);
        int ci = cd >> 2;
        ((u32*)bufChunk)[e*64 + ((ci ^ swzr(e & 15)) << 2) + (cd & 3)] = cvtpk(v0, v1);
    }
    __syncthreads();

    // ---- enc2: relu(A@ew2+b2) -> bufWide chunk0 ----
    {
        f32x4 acc[4][2];
#pragma unroll
        for (int ni = 0; ni < 2; ++ni) {
            float b = eb2[(2*wid + ni)*16 + (l & 15)];
#pragma unroll
            for (int mi = 0; mi < 4; ++mi) acc[mi][ni] = (f32x4){b,b,b,b};
        }
#pragma unroll
        for (int kk = 0; kk < 4; ++kk) {
            short8 af[4];
#pragma unroll
            for (int mi = 0; mi < 4; ++mi) af[mi] = loadA(bufChunk, mi, kk, l);
#pragma unroll
            for (int ni = 0; ni < 2; ++ni) {
                short8 bw = loadB(ew2p, 2*wid + ni, kk, 4, l);
#pragma unroll
                for (int mi = 0; mi < 4; ++mi) acc[mi][ni] = MFMA16(af[mi], bw, acc[mi][ni]);
            }
        }
#pragma unroll
        for (int ni = 0; ni < 2; ++ni) {
            int col = (2*wid + ni)*16 + (l & 15);
#pragma unroll
            for (int mi = 0; mi < 4; ++mi) {
                int R = mi*16 + ((l >> 4) << 2);
                storeQuad((u32*)bufWide, R, col, l,
                          fmaxf(acc[mi][ni][0], 0.f), fmaxf(acc[mi][ni][1], 0.f),
                          fmaxf(acc[mi][ni][2], 0.f), fmaxf(acc[mi][ni][3], 0.f));
            }
        }
    }
    __syncthreads();

    // ---- enc3: W0@ew3+b3 (pre-LN) -> bufChunk ----
    {
        f32x4 acc[4][2];
#pragma unroll
        for (int ni = 0; ni < 2; ++ni) {
            float b = eb3[(2*wid + ni)*16 + (l & 15)];
#pragma unroll
            for (int mi = 0; mi < 4; ++mi) acc[mi][ni] = (f32x4){b,b,b,b};
        }
#pragma unroll
        for (int kk = 0; kk < 4; ++kk) {
            short8 af[4];
#pragma unroll
            for (int mi = 0; mi < 4; ++mi) af[mi] = loadA(bufWide, mi, kk, l);
#pragma unroll
            for (int ni = 0; ni < 2; ++ni) {
                short8 bw = loadB(ew3p, 2*wid + ni, kk, 4, l);
#pragma unroll
                for (int mi = 0; mi < 4; ++mi) acc[mi][ni] = MFMA16(af[mi], bw, acc[mi][ni]);
            }
        }
#pragma unroll
        for (int ni = 0; ni < 2; ++ni) {
            int col = (2*wid + ni)*16 + (l & 15);
#pragma unroll
            for (int mi = 0; mi < 4; ++mi) {
                int R = mi*16 + ((l >> 4) << 2);
                storeQuad((u32*)bufChunk, R, col, l,
                          acc[mi][ni][0], acc[mi][ni][1], acc[mi][ni][2], acc[mi][ni][3]);
            }
        }
    }
    __syncthreads();

    // ---- stage h[src]->bufWide[0], h[dst]->bufWide[1] (enc2 data dead) ----
    stageRows(bufWide,        hbf, sSrc, t);
    stageRows(bufWide + 8192, hbf, sDst, t);

    // ---- LN stats: 4 lanes per edge ----
    {
        int e = wid*16 + (l >> 2);
        int q = l & 3;
        const u32* rowp = (const u32*)bufChunk + e*64;
        float s = 0.f, sq = 0.f;
#pragma unroll
        for (int i = 0; i < 16; ++i) {
            u32 pk = rowp[q*16 + ((i + e) & 15)];
            float a = bf2f(pk & 0xffffu), b = bf2f(pk >> 16);
            s += a + b;
            sq = fmaf(a, a, fmaf(b, b, sq));
        }
        s  += __shfl_xor(s, 1);  sq += __shfl_xor(sq, 1);
        s  += __shfl_xor(s, 2);  sq += __shfl_xor(sq, 2);
        if (q == 0) {
            float mu = s * (1.f/HD);
            rstat[e] = mu;
            rstat[64 + e] = rsqrtf(sq*(1.f/HD) - mu*mu + LN_EPS);
        }
    }
    __syncthreads();

    // ---- normalize in place: bufChunk = ef ----
    for (int it = 0; it < 16; ++it) {
        int pd = it*256 + t;
        int row = pd >> 6, cwd = pd & 63;
        int ci = (cwd >> 2) ^ swzr(row & 15);
        int col = ci*8 + (cwd & 3)*2;
        u32 pk = ((u32*)bufChunk)[pd];
        float mu = rstat[row], ri = rstat[64 + row];
        float v0 = (bf2f(pk & 0xffffu) - mu)*ri*egm[col]     + ebb[col];
        float v1 = (bf2f(pk >> 16)     - mu)*ri*egm[col + 1] + ebb[col + 1];
        ((u32*)bufChunk)[pd] = cvtpk(v0, v1);
    }
    __syncthreads();

    // ---- ep1 MFMA: 2 phases over row halves (full unroll; compiler may
    //      merge), acc[2][4]; gf contribution from transposed gfp1t ----
#pragma unroll
    for (int ph = 0; ph < 2; ++ph) {
        f32x4 acc[2][4];
#pragma unroll
        for (int ni = 0; ni < 4; ++ni) {
            float b = p1b[(4*wid + ni)*16 + (l & 15)];
#pragma unroll
            for (int m = 0; m < 2; ++m) acc[m][ni] = (f32x4){b,b,b,b};
        }
#pragma unroll
        for (int kk = 0; kk < 4; ++kk) {
            short8 af[2];
#pragma unroll
            for (int m = 0; m < 2; ++m) af[m] = loadA(bufWide, 2*ph + m, kk, l);
#pragma unroll
            for (int ni = 0; ni < 4; ++ni) {
                short8 bw = loadB(p1wp, 4*wid + ni, kk, 16, l);
#pragma unroll
                for (int m = 0; m < 2; ++m) acc[m][ni] = MFMA16(af[m], bw, acc[m][ni]);
            }
        }
#pragma unroll
        for (int kk = 0; kk < 4; ++kk) {
            short8 af[2];
#pragma unroll
            for (int m = 0; m < 2; ++m) af[m] = loadA(bufWide + 8192, 2*ph + m, kk, l);
#pragma unroll
            for (int ni = 0; ni < 4; ++ni) {
                short8 bw = loadB(p1wp, 4*wid + ni, 4 + kk, 16, l);
#pragma unroll
                for (int m = 0; m < 2; ++m) acc[m][ni] = MFMA16(af[m], bw, acc[m][ni]);
            }
        }
#pragma unroll
        for (int kk = 0; kk < 4; ++kk) {
            short8 af[2];
#pragma unroll
            for (int m = 0; m < 2; ++m) af[m] = loadA(bufChunk, 2*ph + m, kk, l);
#pragma unroll
            for (int ni = 0; ni < 4; ++ni) {
                short8 bw = loadB(p1wp, 4*wid + ni, 12 + kk, 16, l);
#pragma unroll
                for (int m = 0; m < 2; ++m) acc[m][ni] = MFMA16(af[m], bw, acc[m][ni]);
            }
        }
        // epilogue: add per-graph gfp1t column-row, tanh, pack
#pragma unroll
        for (int m = 0; m < 2; ++m) {
            int R = (2*ph + m)*16 + ((l >> 4) << 2);
            int g0 = sGf[R], g1 = sGf[R+1], g2 = sGf[R+2], g3 = sGf[R+3];
#pragma unroll
            for (int ni = 0; ni < 4; ++ni) {
                int col = (4*wid + ni)*16 + (l & 15);
                const float* gp = gfp1t + (size_t)col*NG;
                u32* dst = (u32*)bufWide + ((col >> 7) << 12);
                int cc = col & 127;
                storeQuad(dst, R, cc, l,
                          fast_tanh(acc[m][ni][0] + gp[g0]),
                          fast_tanh(acc[m][ni][1] + gp[g1]),
                          fast_tanh(acc[m][ni][2] + gp[g2]),
                          fast_tanh(acc[m][ni][3] + gp[g3]));
            }
        }
    }
    __syncthreads();

    // ---- ep2: [64,256]@p2w[256,128], tanh -> bufChunk ----
    {
        f32x4 acc[4][2];
#pragma unroll
        for (int ni = 0; ni < 2; ++ni) {
            float b = p2b[(2*wid + ni)*16 + (l & 15)];
#pragma unroll
            for (int mi = 0; mi < 4; ++mi) acc[mi][ni] = (f32x4){b,b,b,b};
        }
        for (int kc = 0; kc < 2; ++kc) {
            const u16* abuf = bufWide + (kc << 13);
#pragma unroll
            for (int kk = 0; kk < 4; ++kk) {
                short8 af[4];
#pragma unroll
                for (int mi = 0; mi < 4; ++mi) af[mi] = loadA(abuf, mi, kk, l);
                int ks = kc*4 + kk;
#pragma unroll
                for (int ni = 0; ni < 2; ++ni) {
                    short8 bw = loadB(p2wp, 2*wid + ni, ks, 8, l);
#pragma unroll
                    for (int mi = 0; mi < 4; ++mi) acc[mi][ni] = MFMA16(af[mi], bw, acc[mi][ni]);
                }
            }
        }
#pragma unroll
        for (int ni = 0; ni < 2; ++ni) {
            int col = (2*wid + ni)*16 + (l & 15);
#pragma unroll
            for (int mi = 0; mi < 4; ++mi) {
                int R = mi*16 + ((l >> 4) << 2);
                storeQuad((u32*)bufChunk, R, col, l,
                          fast_tanh(acc[mi][ni][0]), fast_tanh(acc[mi][ni][1]),
                          fast_tanh(acc[mi][ni][2]), fast_tanh(acc[mi][ni][3]));
            }
        }
    }
    __syncthreads();

    // ---- ep3: [64,128]@p3w[128,64], relu -> bufWide fp32 stride-65 ----
    {
        f32x4 acc[4];
        {
            float b = p3b[wid*16 + (l & 15)];
#pragma unroll
            for (int mi = 0; mi < 4; ++mi) acc[mi] = (f32x4){b,b,b,b};
        }
#pragma unroll
        for (int kk = 0; kk < 4; ++kk) {
            short8 af[4];
#pragma unroll
            for (int mi = 0; mi < 4; ++mi) af[mi] = loadA(bufChunk, mi, kk, l);
            short8 bw = loadB(p3wp, wid, kk, 4, l);
#pragma unroll
            for (int mi = 0; mi < 4; ++mi) acc[mi] = MFMA16(af[mi], bw, acc[mi]);
        }
        float* fb = (float*)bufWide;
        int col = wid*16 + (l & 15);
#pragma unroll
        for (int mi = 0; mi < 4; ++mi)
#pragma unroll
            for (int rr = 0; rr < 4; ++rr) {
                int row = mi*16 + ((l >> 4) << 2) + rr;
                fb[row*65 + col] = fmaxf(acc[mi][rr], 0.f);
            }
    }
    __syncthreads();

    // ---- ep4: 4 lanes/edge dot-64 + sigmoid ----
    {
        const float* fb = (const float*)bufWide;
        int e = wid*16 + (l >> 2), q = l & 3;
        float v = 0.f;
#pragma unroll
        for (int k = 0; k < 16; ++k) {
            int i = q*16 + k;
            v = fmaf(fb[e*65 + i], p4w[i], v);
        }
        v += __shfl_xor(v, 1);
        v += __shfl_xor(v, 2);
        if (q == 0) out[e0 + e] = fast_sigmoid(v + p4b[0]);
    }
}

// ---------------------------------------------------------------------------
extern "C" void kernel_launch(void* const* d_in, const int* in_sizes, int n_in,
                              void* d_out, int out_size, void* d_ws, size_t ws_size,
                              hipStream_t stream)
{
    const float* x     = (const float*)d_in[0];
    const int*   ei    = (const int*)  d_in[1];
    const float* ea    = (const float*)d_in[2];
    const int*   batch = (const int*)  d_in[3];
    const float* ne1w = (const float*)d_in[4];  const float* ne1b = (const float*)d_in[5];
    const float* ne2w = (const float*)d_in[6];  const float* ne2b = (const float*)d_in[7];
    const float* ne3w = (const float*)d_in[8];  const float* ne3b = (const float*)d_in[9];
    const float* neg  = (const float*)d_in[10]; const float* nebb = (const float*)d_in[11];
    const float* ee1w = (const float*)d_in[12]; const float* ee1b = (const float*)d_in[13];
    const float* ee2w = (const float*)d_in[14]; const float* ee2b = (const float*)d_in[15];
    const float* ee3w = (const float*)d_in[16]; const float* ee3b = (const float*)d_in[17];
    const float* eeg  = (const float*)d_in[18]; const float* eebb = (const float*)d_in[19];
    const float* g1w  = (const float*)d_in[20]; const float* g1b  = (const float*)d_in[21];
    const float* g2w  = (const float*)d_in[22]; const float* g2b  = (const float*)d_in[23];
    const float* gp1w = (const float*)d_in[24]; const float* gp1b = (const float*)d_in[25];
    const float* gp2w = (const float*)d_in[26]; const float* gp2b = (const float*)d_in[27];
    const float* gpg  = (const float*)d_in[28]; const float* gpbb = (const float*)d_in[29];
    const float* p1w  = (const float*)d_in[30]; const float* p1b  = (const float*)d_in[31];
    const float* p2w  = (const float*)d_in[32]; const float* p2b  = (const float*)d_in[33];
    const float* p3w  = (const float*)d_in[34]; const float* p3b  = (const float*)d_in[35];
    const float* p4w  = (const float*)d_in[36]; const float* p4b  = (const float*)d_in[37];

    float* dinv = (float*)d_ws;                // NN
    float* sums = dinv + NN;                   // NG*HD
    float* cnts = sums + NG*HD;                // NG
    float* gfp1 = cnts + NG;                   // 256*NG (transposed)
    int* degi   = (int*)(gfp1 + 256*NG);       // NN
    int* cursor = degi + NN;                   // NN+2
    int* rowptr = cursor + NN + 2;             // NN+2
    int* sadj   = rowptr + NN + 2;             // NE
    u16* xw1p   = (u16*)(sadj + NE);           // NN*HD
    u16* xw2p   = xw1p + (size_t)NN*HD;        // NN*HD
    u16* hbf    = xw2p + (size_t)NN*HD;        // NN*HD
    u16* wpk    = hbf + (size_t)NN*HD;         // 270336
    u16* ee2p = wpk;
    u16* ee3p = wpk + 16384;
    u16* p1p  = wpk + 32768;
    u16* p2p  = wpk + 163840;
    u16* p3p  = wpk + 196608;
    u16* ne2p = wpk + 204800;
    u16* ne3p = wpk + 221184;
    u16* g1p  = wpk + 237568;
    u16* g2p  = wpk + 253952;

    float* out = (float*)d_out;

    hipMemsetAsync(degi, 0, (size_t)(2*NN + 2)*sizeof(int), stream);
    hipMemsetAsync(sums, 0, (size_t)(NG*HD + NG)*sizeof(float), stream);

    pack_all<<<(270336 + 255)/256, 256, 0, stream>>>(ee2w, ee3w, p1w, p2w, p3w,
                                                     ne2w, ne3w, g1w, g2w, wpk);

    // CSR build (+dinv fused into scan)
    deg_count_int<<<(NE + 255)/256, 256, 0, stream>>>(ei, degi);
    scan_excl<<<1, 1024, 0, stream>>>(degi, rowptr, dinv);
    fill_csr<<<(NE + 255)/256, 256, 0, stream>>>(ei, rowptr, cursor, sadj);

    // node encoder + g1 GEMM (bf16 out, prescaled by dinv)
    enc_mfma<<<(NN + 63)/64, 256, 0, stream>>>(x, ne1w, ne1b, ne2p, ne2b, ne3p, ne3b,
                                               neg, nebb, g1p, dinv, (u32*)xw1p);
    // GCN1 gather + relu + g2 GEMM
    gcn_agg1_mfma<<<(NN + 63)/64, 256, 0, stream>>>(xw1p, rowptr, sadj, dinv,
                                                    g1b, g2p, (u32*)xw2p);
    // GCN2 gather -> hbf bf16
    gcn_agg2_gather<<<(NN + 63)/64, 256, 0, stream>>>(xw2p, rowptr, sadj, dinv,
                                                      g2b, (u32*)hbf);

    // pool (+counts fused) + graph MLP (+gfp1t precompute, transposed)
    pool_sorted<<<POOL_B, 128, 0, stream>>>(hbf, batch, sums, cnts);
    graph_feat<<<NG, 128, 0, stream>>>(sums, cnts, gp1w, gp1b, gp2w, gp2b,
                                       gpg, gpbb, p1w, gfp1);

    // fused edge encoder + edge-score MLP
    edge_mlp_mfma<<<NE/64, 256, 0, stream>>>(hbf, gfp1, ei, batch, ea,
                                             ee1w, ee1b, ee2p, ee2b, ee3p, ee3b,
                                             eeg, eebb,
                                             p1p, p1b, p2p, p2b, p3p, p3b,
                                             p4w, p4b, out);
}

// Round 13
// 524.573 us; speedup vs baseline: 1.6592x; 1.2187x over previous
//
#include <hip/hip_runtime.h>
#include <math.h>

#define NN 50000
#define NE 400000
#define NG 64
#define HD 128
#define LN_EPS 1e-5f

typedef unsigned short u16;
typedef unsigned int u32;
typedef __attribute__((ext_vector_type(8))) short short8;
typedef __attribute__((ext_vector_type(4))) float f32x4;

#define MFMA16(a,b,c) __builtin_amdgcn_mfma_f32_16x16x32_bf16((a),(b),(c),0,0,0)

__device__ __forceinline__ u16 f2bf(float f) {
    union { float f; u32 u; } v; v.f = f;
    u32 r = v.u + 0x7FFFu + ((v.u >> 16) & 1u);
    return (u16)(r >> 16);
}
__device__ __forceinline__ float bf2f(u32 hs) {
    union { u32 u; float f; } v; v.u = hs << 16;
    return v.f;
}
__device__ __forceinline__ float fast_rcp(float x) {
    float r; asm("v_rcp_f32 %0, %1" : "=v"(r) : "v"(x)); return r;
}
__device__ __forceinline__ float fast_exp2(float x) {
    float r; asm("v_exp_f32 %0, %1" : "=v"(r) : "v"(x)); return r;
}
__device__ __forceinline__ u32 cvtpk(float lo, float hi) {
    u32 r; asm("v_cvt_pk_bf16_f32 %0, %1, %2" : "=v"(r) : "v"(lo), "v"(hi)); return r;
}
// tanh(x) = 1 - 2/(1+2^(2*log2e*x)); exp2 saturates correctly at +-inf
__device__ __forceinline__ float fast_tanh(float x) {
    return fmaf(-2.f, fast_rcp(1.f + fast_exp2(2.885390082f * x)), 1.f);
}
__device__ __forceinline__ float fast_sigmoid(float x) {
    return fast_rcp(1.f + fast_exp2(-1.442695041f * x));
}

// swizzle term for row within 16-row group
__device__ __forceinline__ int swzr(int row) {
    return (row & 7) ^ ((row & 8) >> 2);
}

// A-fragment load from swizzled [64][128] bf16 chunk buffer.
__device__ __forceinline__ short8 loadA(const u16* buf, int mi, int kk, int l) {
    int row = mi*16 + (l & 15);
    int ci  = (kk*4 + (l >> 4)) ^ swzr(l & 15);
    return *(const short8*)(buf + row*128 + (ci << 3));
}
__device__ __forceinline__ short8 loadB(const u16* wp, int nt, int ks, int nk, int l) {
    return *(const short8*)(wp + (((nt*nk + ks)*64 + l) << 3));
}

// Store 4 accumulator values (rows R..R+3, col c) into swizzled bf16 chunk as
// packed u32 via lane-pair exchange + v_cvt_pk_bf16_f32.
__device__ __forceinline__ void storeQuad(u32* buf, int R, int c, int l,
                                          float v0, float v1, float v2, float v3)
{
    int cw = c >> 1;
    int par = l & 1;
    float send = par ? v0 : v1;
    float recv = __shfl_xor(send, 1);
    int row = R + par;
    u32 word = par ? cvtpk(recv, v1) : cvtpk(v0, recv);
    buf[row*64 + (((cw >> 2) ^ swzr(row & 15)) << 2) + (cw & 3)] = word;
    send = par ? v2 : v3;
    recv = __shfl_xor(send, 1);
    row = R + 2 + par;
    word = par ? cvtpk(recv, v3) : cvtpk(v2, recv);
    buf[row*64 + (((cw >> 2) ^ swzr(row & 15)) << 2) + (cw & 3)] = word;
}

// Unswizzle copy: LDS chunk -> global bf16 [64][128] rows n0..n0+63 (u32 words)
__device__ __forceinline__ void copyChunkOut(const u32* chunk, u32* gout, int n0, int t)
{
    for (int it = 0; it < 16; ++it) {
        int dw = it*256 + t;
        int row = dw >> 6, cw = dw & 63;
        if (n0 + row < NN)
            gout[(size_t)(n0 + row)*64 + cw] =
                chunk[row*64 + (((cw >> 2) ^ swzr(row & 15)) << 2) + (cw & 3)];
    }
}

// ---------------------------------------------------------------------------
// One-shot weight packing of all 9 GEMM weights -> bf16 MFMA B-fragment order.
// ---------------------------------------------------------------------------
__global__ __launch_bounds__(256)
void pack_all(const float* __restrict__ ee2w, const float* __restrict__ ee3w,
              const float* __restrict__ p1w,  const float* __restrict__ p2w,
              const float* __restrict__ p3w,  const float* __restrict__ ne2w,
              const float* __restrict__ ne3w, const float* __restrict__ g1w,
              const float* __restrict__ g2w,  u16* __restrict__ wpk)
{
    int idx = blockIdx.x*256 + threadIdx.x;
    if (idx >= 270336) return;
    const float* w; int K, N, local;
    if      (idx < 16384)  { w = ee2w; K = 128; N = 128; local = idx; }
    else if (idx < 32768)  { w = ee3w; K = 128; N = 128; local = idx - 16384; }
    else if (idx < 163840) { w = p1w;  K = 512; N = 256; local = idx - 32768; }
    else if (idx < 196608) { w = p2w;  K = 256; N = 128; local = idx - 163840; }
    else if (idx < 204800) { w = p3w;  K = 128; N = 64;  local = idx - 196608; }
    else if (idx < 221184) { w = ne2w; K = 128; N = 128; local = idx - 204800; }
    else if (idx < 237568) { w = ne3w; K = 128; N = 128; local = idx - 221184; }
    else if (idx < 253952) { w = g1w;  K = 128; N = 128; local = idx - 237568; }
    else                   { w = g2w;  K = 128; N = 128; local = idx - 253952; }
    int e = local & 7, l = (local >> 3) & 63, r = local >> 9;
    int nk = K >> 5;
    int nt = r / nk, kk = r % nk;
    int k = kk*32 + ((l >> 4) << 3) + e;
    int n = nt*16 + (l & 15);
    wpk[idx] = f2bf(w[k*N + n]);
}

// ---------------------------------------------------------------------------
// CSR build
// ---------------------------------------------------------------------------
__global__ __launch_bounds__(256)
void deg_count_int(const int* __restrict__ ei, int* __restrict__ degi)
{
    int e = blockIdx.x*256 + threadIdx.x;
    if (e < NE) atomicAdd(&degi[ei[NE + e]], 1);
}

__global__ __launch_bounds__(1024)
void scan_excl(const int* __restrict__ cnt, int* __restrict__ rp,
               float* __restrict__ dinv)
{
    __shared__ int wsum[16];
    __shared__ int carry;
    int t = threadIdx.x, lane = t & 63, w = t >> 6;
    int base = 0;
    for (int off = 0; off < NN; off += 4096) {
        int i0 = off + t*4;
        int v0 = (i0   < NN) ? cnt[i0]   : 0;
        int v1 = (i0+1 < NN) ? cnt[i0+1] : 0;
        int v2 = (i0+2 < NN) ? cnt[i0+2] : 0;
        int v3 = (i0+3 < NN) ? cnt[i0+3] : 0;
        int tot = v0 + v1 + v2 + v3;
        int s = tot;
#pragma unroll
        for (int d = 1; d < 64; d <<= 1) { int u = __shfl_up(s, d); if (lane >= d) s += u; }
        if (lane == 63) wsum[w] = s;
        __syncthreads();
        if (w == 0) {
            int wv = (lane < 16) ? wsum[lane] : 0;
            int ss = wv;
#pragma unroll
            for (int d = 1; d < 16; d <<= 1) { int u = __shfl_up(ss, d); if (lane >= d) ss += u; }
            if (lane < 16) wsum[lane] = ss - wv;
            if (lane == 15) carry = ss;
        }
        __syncthreads();
        int excl = base + wsum[w] + s - tot;
        if (i0   < NN) { rp[i0]   = excl;              dinv[i0]   = rsqrtf((float)v0 + 1.f); }
        if (i0+1 < NN) { rp[i0+1] = excl + v0;         dinv[i0+1] = rsqrtf((float)v1 + 1.f); }
        if (i0+2 < NN) { rp[i0+2] = excl + v0 + v1;    dinv[i0+2] = rsqrtf((float)v2 + 1.f); }
        if (i0+3 < NN) { rp[i0+3] = excl + v0 + v1 + v2; dinv[i0+3] = rsqrtf((float)v3 + 1.f); }
        base += carry;
        __syncthreads();
    }
    if (t == 0) rp[NN] = base;
}

__global__ __launch_bounds__(256)
void fill_csr(const int* __restrict__ ei, const int* __restrict__ rp,
              int* __restrict__ cursor, int* __restrict__ sadj)
{
    int e = blockIdx.x*256 + threadIdx.x;
    if (e >= NE) return;
    int d = ei[NE + e];
    int slot = atomicAdd(&cursor[d], 1);
    sadj[rp[d] + slot] = ei[e];
}

// ---------------------------------------------------------------------------
// Node encoder + g1w GEMM, MFMA. 64 nodes/block, 256 threads.
// ---------------------------------------------------------------------------
__global__ __launch_bounds__(256, 4)
void enc_mfma(const float* __restrict__ x,
              const float* __restrict__ w1, const float* __restrict__ b1,
              const u16* __restrict__ w2p, const float* __restrict__ b2,
              const u16* __restrict__ w3p, const float* __restrict__ b3,
              const float* __restrict__ gg, const float* __restrict__ bb,
              const u16* __restrict__ g1p, const float* __restrict__ dinv,
              u32* __restrict__ xw1p)
{
    __shared__ u16 chunkA[64*HD];
    __shared__ u16 chunkB[64*HD];
    __shared__ float sX[192];
    __shared__ float sDi[64];
    __shared__ float rstat[128];

    const int t = threadIdx.x;
    const int l = t & 63;
    const int wid = t >> 6;
    const int n0 = blockIdx.x * 64;

    if (t < 192) sX[t] = (n0*3 + t < NN*3) ? x[n0*3 + t] : 0.f;
    if (t < 64)  sDi[t] = (n0 + t < NN) ? dinv[n0 + t] : 0.f;
    __syncthreads();

    // L1: 3->128 relu (VALU) -> chunkA
    for (int it = 0; it < 16; ++it) {
        int dw = it*256 + t;
        int e = dw >> 6, cd = dw & 63;
        int c0 = cd*2;
        float x0 = sX[e*3], x1 = sX[e*3+1], x2 = sX[e*3+2];
        float v0 = b1[c0]   + x0*w1[c0]   + x1*w1[HD+c0]   + x2*w1[2*HD+c0];
        float v1 = b1[c0+1] + x0*w1[c0+1] + x1*w1[HD+c0+1] + x2*w1[2*HD+c0+1];
        v0 = fmaxf(v0, 0.f); v1 = fmaxf(v1, 0.f);
        int ci = cd >> 2;
        ((u32*)chunkA)[e*64 + ((ci ^ swzr(e & 15)) << 2) + (cd & 3)] = cvtpk(v0, v1);
    }
    __syncthreads();

    // L2 MFMA: relu(A@w2+b2) -> chunkB
    {
        f32x4 acc[4][2];
#pragma unroll
        for (int ni = 0; ni < 2; ++ni) {
            float b = b2[(2*wid + ni)*16 + (l & 15)];
#pragma unroll
            for (int mi = 0; mi < 4; ++mi) acc[mi][ni] = (f32x4){b,b,b,b};
        }
#pragma unroll
        for (int kk = 0; kk < 4; ++kk) {
            short8 af[4];
#pragma unroll
            for (int mi = 0; mi < 4; ++mi) af[mi] = loadA(chunkA, mi, kk, l);
#pragma unroll
            for (int ni = 0; ni < 2; ++ni) {
                short8 bw = loadB(w2p, 2*wid + ni, kk, 4, l);
#pragma unroll
                for (int mi = 0; mi < 4; ++mi) acc[mi][ni] = MFMA16(af[mi], bw, acc[mi][ni]);
            }
        }
#pragma unroll
        for (int ni = 0; ni < 2; ++ni) {
            int col = (2*wid + ni)*16 + (l & 15);
#pragma unroll
            for (int mi = 0; mi < 4; ++mi) {
                int R = mi*16 + ((l >> 4) << 2);
                storeQuad((u32*)chunkB, R, col, l,
                          fmaxf(acc[mi][ni][0], 0.f), fmaxf(acc[mi][ni][1], 0.f),
                          fmaxf(acc[mi][ni][2], 0.f), fmaxf(acc[mi][ni][3], 0.f));
            }
        }
    }
    __syncthreads();

    // L3 MFMA: B@w3+b3 (pre-LN) -> chunkA
    {
        f32x4 acc[4][2];
#pragma unroll
        for (int ni = 0; ni < 2; ++ni) {
            float b = b3[(2*wid + ni)*16 + (l & 15)];
#pragma unroll
            for (int mi = 0; mi < 4; ++mi) acc[mi][ni] = (f32x4){b,b,b,b};
        }
#pragma unroll
        for (int kk = 0; kk < 4; ++kk) {
            short8 af[4];
#pragma unroll
            for (int mi = 0; mi < 4; ++mi) af[mi] = loadA(chunkB, mi, kk, l);
#pragma unroll
            for (int ni = 0; ni < 2; ++ni) {
                short8 bw = loadB(w3p, 2*wid + ni, kk, 4, l);
#pragma unroll
                for (int mi = 0; mi < 4; ++mi) acc[mi][ni] = MFMA16(af[mi], bw, acc[mi][ni]);
            }
        }
#pragma unroll
        for (int ni = 0; ni < 2; ++ni) {
            int col = (2*wid + ni)*16 + (l & 15);
#pragma unroll
            for (int mi = 0; mi < 4; ++mi) {
                int R = mi*16 + ((l >> 4) << 2);
                storeQuad((u32*)chunkA, R, col, l,
                          acc[mi][ni][0], acc[mi][ni][1], acc[mi][ni][2], acc[mi][ni][3]);
            }
        }
    }
    __syncthreads();

    // LN stats: 4 lanes per row, rotated read
    {
        int e = wid*16 + (l >> 2);
        int q = l & 3;
        const u32* rowp = (const u32*)chunkA + e*64;
        float s = 0.f, sq = 0.f;
#pragma unroll
        for (int i = 0; i < 16; ++i) {
            u32 pk = rowp[q*16 + ((i + e) & 15)];
            float a = bf2f(pk & 0xffffu), b = bf2f(pk >> 16);
            s += a + b;
            sq = fmaf(a, a, fmaf(b, b, sq));
        }
        s  += __shfl_xor(s, 1);  sq += __shfl_xor(sq, 1);
        s  += __shfl_xor(s, 2);  sq += __shfl_xor(sq, 2);
        if (q == 0) {
            float mu = s * (1.f/HD);
            rstat[e] = mu;
            rstat[64 + e] = rsqrtf(sq*(1.f/HD) - mu*mu + LN_EPS);
        }
    }
    __syncthreads();

    // normalize in place
    for (int it = 0; it < 16; ++it) {
        int pd = it*256 + t;
        int row = pd >> 6, cwd = pd & 63;
        int ci = (cwd >> 2) ^ swzr(row & 15);
        int col = ci*8 + (cwd & 3)*2;
        u32 pk = ((u32*)chunkA)[pd];
        float mu = rstat[row], ri = rstat[64 + row];
        float v0 = (bf2f(pk & 0xffffu) - mu)*ri*gg[col]     + bb[col];
        float v1 = (bf2f(pk >> 16)     - mu)*ri*gg[col + 1] + bb[col + 1];
        ((u32*)chunkA)[pd] = cvtpk(v0, v1);
    }
    __syncthreads();

    // GEMM @g1w, scale by dinv -> chunkB -> global
    {
        f32x4 acc[4][2];
#pragma unroll
        for (int mi = 0; mi < 4; ++mi)
#pragma unroll
            for (int ni = 0; ni < 2; ++ni) acc[mi][ni] = (f32x4){0.f,0.f,0.f,0.f};
#pragma unroll
        for (int kk = 0; kk < 4; ++kk) {
            short8 af[4];
#pragma unroll
            for (int mi = 0; mi < 4; ++mi) af[mi] = loadA(chunkA, mi, kk, l);
#pragma unroll
            for (int ni = 0; ni < 2; ++ni) {
                short8 bw = loadB(g1p, 2*wid + ni, kk, 4, l);
#pragma unroll
                for (int mi = 0; mi < 4; ++mi) acc[mi][ni] = MFMA16(af[mi], bw, acc[mi][ni]);
            }
        }
#pragma unroll
        for (int ni = 0; ni < 2; ++ni) {
            int col = (2*wid + ni)*16 + (l & 15);
#pragma unroll
            for (int mi = 0; mi < 4; ++mi) {
                int R = mi*16 + ((l >> 4) << 2);
                storeQuad((u32*)chunkB, R, col, l,
                          acc[mi][ni][0]*sDi[R], acc[mi][ni][1]*sDi[R+1],
                          acc[mi][ni][2]*sDi[R+2], acc[mi][ni][3]*sDi[R+3]);
            }
        }
    }
    __syncthreads();
    copyChunkOut((const u32*)chunkB, xw1p, n0, t);
}

// ---------------------------------------------------------------------------
// GCN layer 1: gather bf16 xw1p (prescaled), relu(+g1b), MFMA @g2w, *dinv -> xw2p
// ---------------------------------------------------------------------------
__global__ __launch_bounds__(256, 4)
void gcn_agg1_mfma(const u16* __restrict__ xw1p, const int* __restrict__ rp,
                   const int* __restrict__ sadj, const float* __restrict__ dinv,
                   const float* __restrict__ g1b, const u16* __restrict__ g2p,
                   u32* __restrict__ xw2p)
{
    __shared__ u16 chunkA[64*HD];
    __shared__ u16 chunkB[64*HD];
    __shared__ float sDi[64];
    __shared__ float sB[HD];

    const int t = threadIdx.x;
    const int l = t & 63;
    const int wid = t >> 6;
    const int n0 = blockIdx.x * 64;

    if (t < 64)  sDi[t] = (n0 + t < NN) ? dinv[n0 + t] : 0.f;
    if (t < HD)  sB[t] = g1b[t];
    __syncthreads();

    {
        int s = t >> 2, part = t & 3, n = n0 + s;
        float acc[32];
#pragma unroll
        for (int j = 0; j < 32; ++j) acc[j] = 0.f;
        float di = 0.f;
        if (n < NN) {
            di = sDi[s];
            const short8* selfp = (const short8*)(xw1p + (size_t)n*HD + part*32);
#pragma unroll
            for (int w = 0; w < 4; ++w) {
                short8 v = selfp[w];
#pragma unroll
                for (int j = 0; j < 8; ++j) acc[w*8+j] += bf2f((u16)v[j]);
            }
            int k1 = rp[n+1];
            for (int k = rp[n]; k < k1; ++k) {
                const short8* rp8 = (const short8*)(xw1p + (size_t)sadj[k]*HD + part*32);
#pragma unroll
                for (int w = 0; w < 4; ++w) {
                    short8 v = rp8[w];
#pragma unroll
                    for (int j = 0; j < 8; ++j) acc[w*8+j] += bf2f((u16)v[j]);
                }
            }
        }
#pragma unroll
        for (int p = 0; p < 16; ++p) {
            float v0 = fmaxf(fmaf(acc[2*p],   di, sB[part*32 + 2*p]),   0.f);
            float v1 = fmaxf(fmaf(acc[2*p+1], di, sB[part*32 + 2*p+1]), 0.f);
            int cw = part*16 + p;
            ((u32*)chunkA)[s*64 + (((cw >> 2) ^ swzr(s & 15)) << 2) + (cw & 3)] = cvtpk(v0, v1);
        }
    }
    __syncthreads();

    {
        f32x4 acc[4][2];
#pragma unroll
        for (int mi = 0; mi < 4; ++mi)
#pragma unroll
            for (int ni = 0; ni < 2; ++ni) acc[mi][ni] = (f32x4){0.f,0.f,0.f,0.f};
#pragma unroll
        for (int kk = 0; kk < 4; ++kk) {
            short8 af[4];
#pragma unroll
            for (int mi = 0; mi < 4; ++mi) af[mi] = loadA(chunkA, mi, kk, l);
#pragma unroll
            for (int ni = 0; ni < 2; ++ni) {
                short8 bw = loadB(g2p, 2*wid + ni, kk, 4, l);
#pragma unroll
                for (int mi = 0; mi < 4; ++mi) acc[mi][ni] = MFMA16(af[mi], bw, acc[mi][ni]);
            }
        }
#pragma unroll
        for (int ni = 0; ni < 2; ++ni) {
            int col = (2*wid + ni)*16 + (l & 15);
#pragma unroll
            for (int mi = 0; mi < 4; ++mi) {
                int R = mi*16 + ((l >> 4) << 2);
                storeQuad((u32*)chunkB, R, col, l,
                          acc[mi][ni][0]*sDi[R], acc[mi][ni][1]*sDi[R+1],
                          acc[mi][ni][2]*sDi[R+2], acc[mi][ni][3]*sDi[R+3]);
            }
        }
    }
    __syncthreads();
    copyChunkOut((const u32*)chunkB, xw2p, n0, t);
}

// ---------------------------------------------------------------------------
// GCN layer 2: gather bf16 xw2p, +g2b -> hbf (bf16 only)
// ---------------------------------------------------------------------------
__global__ __launch_bounds__(256)
void gcn_agg2_gather(const u16* __restrict__ xw2p, const int* __restrict__ rp,
                     const int* __restrict__ sadj, const float* __restrict__ dinv,
                     const float* __restrict__ g2b, u32* __restrict__ hbw)
{
    int t = threadIdx.x;
    int s = t >> 2, part = t & 3;
    int n = blockIdx.x * 64 + s;
    if (n >= NN) return;
    float acc[32];
#pragma unroll
    for (int j = 0; j < 32; ++j) acc[j] = 0.f;
    const short8* selfp = (const short8*)(xw2p + (size_t)n*HD + part*32);
#pragma unroll
    for (int w = 0; w < 4; ++w) {
        short8 v = selfp[w];
#pragma unroll
        for (int j = 0; j < 8; ++j) acc[w*8+j] += bf2f((u16)v[j]);
    }
    int k1 = rp[n+1];
    for (int k = rp[n]; k < k1; ++k) {
        const short8* rp8 = (const short8*)(xw2p + (size_t)sadj[k]*HD + part*32);
#pragma unroll
        for (int w = 0; w < 4; ++w) {
            short8 v = rp8[w];
#pragma unroll
            for (int j = 0; j < 8; ++j) acc[w*8+j] += bf2f((u16)v[j]);
        }
    }
    float di = dinv[n];
    u32* hb = hbw + (size_t)n*64 + part*16;
#pragma unroll
    for (int p = 0; p < 16; ++p) {
        float v0 = fmaf(acc[2*p],   di, g2b[part*32 + 2*p]);
        float v1 = fmaf(acc[2*p+1], di, g2b[part*32 + 2*p+1]);
        hb[p] = cvtpk(v0, v1);
    }
}

// ---------------------------------------------------------------------------
// Pool (batch sorted, bf16 input) + fused counts + graph MLP
// ---------------------------------------------------------------------------
#define POOL_B 512
__global__ __launch_bounds__(128)
void pool_sorted(const u16* __restrict__ h, const int* __restrict__ batch,
                 float* __restrict__ sums, float* __restrict__ cnts)
{
    int b = blockIdx.x, j = threadIdx.x;
    int n0 = (int)(((long long)NN * b) / POOL_B);
    int n1 = (int)(((long long)NN * (b+1)) / POOL_B);
    int g = -1; float acc = 0.f, cl = 0.f;
    for (int n = n0; n < n1; ++n) {
        int bg = batch[n];
        if (bg != g) {
            if (g >= 0) {
                atomicAdd(&sums[g*HD + j], acc);
                if (j == 0) atomicAdd(&cnts[g], cl);
            }
            g = bg; acc = 0.f; cl = 0.f;
        }
        acc += bf2f(h[(size_t)n*HD + j]);
        cl += 1.f;
    }
    if (g >= 0) {
        atomicAdd(&sums[g*HD + j], acc);
        if (j == 0) atomicAdd(&cnts[g], cl);
    }
}

__global__ __launch_bounds__(128)
void graph_feat(const float* __restrict__ sums, const float* __restrict__ cnts,
                const float* __restrict__ w1, const float* __restrict__ b1,
                const float* __restrict__ w2, const float* __restrict__ b2,
                const float* __restrict__ gg, const float* __restrict__ bb,
                u16* __restrict__ gf16)
{
    int gi = blockIdx.x, j = threadIdx.x;
    __shared__ float s0[HD];
    __shared__ float s1[HD];
    __shared__ float part[4];
    __shared__ float stat[2];
    float cnt = fmaxf(cnts[gi], 1.f);
    s0[j] = sums[gi*HD + j] / cnt;
    __syncthreads();
    float a = b1[j];
    for (int i = 0; i < HD; ++i) a = fmaf(s0[i], w1[i*HD + j], a);
    s1[j] = fmaxf(a, 0.f);
    __syncthreads();
    a = b2[j];
    for (int i = 0; i < HD; ++i) a = fmaf(s1[i], w2[i*HD + j], a);
    float s = a, q = a*a;
    for (int o = 32; o > 0; o >>= 1) { s += __shfl_down(s, o); q += __shfl_down(q, o); }
    int wid = j >> 6, lane = j & 63;
    if (lane == 0) { part[wid] = s; part[2 + wid] = q; }
    __syncthreads();
    if (j == 0) {
        float S = part[0] + part[1], Q = part[2] + part[3];
        float mu = S * (1.f/HD);
        stat[0] = mu;
        stat[1] = Q * (1.f/HD) - mu*mu;
    }
    __syncthreads();
    float v = (a - stat[0]) * rsqrtf(stat[1] + LN_EPS) * gg[j] + bb[j];
    gf16[gi*HD + j] = f2bf(v);
}

// ---------------------------------------------------------------------------
// Stage 64 gathered bf16 rows into swizzled LDS chunk (4 threads/row)
// ---------------------------------------------------------------------------
__device__ __forceinline__ void stageRows(u16* dst, const u16* __restrict__ srcBase,
                                          const int* ridx, int t)
{
    int e = t >> 2, part = t & 3;
    const u16* src = srcBase + (size_t)ridx[e]*HD + part*32;
    u16* drow = dst + e*128;
    int re = swzr(e & 15);
#pragma unroll
    for (int w = 0; w < 4; ++w) {
        int ci = (part*4 + w) ^ re;
        *(short8*)(drow + (ci << 3)) = *(const short8*)(src + w*8);
    }
}

// ---------------------------------------------------------------------------
// Fused edge kernel (MFMA bf16). 64 edges/block, 256 threads, 2 blocks/CU.
// Empirically the stable optimum: (256,2) never spills (VGPR ~108, WRITE
// ~1.5MB); (256,3) ALWAYS spills this kernel (r6-r12) and spilled configs
// are bistable (occasional 31ms scratch-thrash dispatches). h[src]/h[dst]
// prefetched into registers; gf staged late via LDS (full 16-ks ep1 MFMA).
// ---------------------------------------------------------------------------
__global__ __launch_bounds__(256, 2)
void edge_mlp_mfma(const u16* __restrict__ hbf, const u16* __restrict__ gfbf,
                   const int* __restrict__ ei, const int* __restrict__ batch,
                   const float* __restrict__ ea,
                   const float* __restrict__ ew1, const float* __restrict__ eb1,
                   const u16* __restrict__ ew2p, const float* __restrict__ eb2,
                   const u16* __restrict__ ew3p, const float* __restrict__ eb3,
                   const float* __restrict__ egm, const float* __restrict__ ebb,
                   const u16* __restrict__ p1wp, const float* __restrict__ p1b,
                   const u16* __restrict__ p2wp, const float* __restrict__ p2b,
                   const u16* __restrict__ p3wp, const float* __restrict__ p3b,
                   const float* __restrict__ p4w, const float* __restrict__ p4b,
                   float* __restrict__ out)
{
    __shared__ u16 bufChunk[64*HD];    // 16KB swizzled A-chunk
    __shared__ u16 bufWide[64*256];    // 32KB (2 chunks / fp32 scratch)
    __shared__ float sEa[192];
    __shared__ int sGf[64];
    __shared__ float rstat[128];

    const int t = threadIdx.x;
    const int l = t & 63;
    const int wid = t >> 6;
    const int e0 = blockIdx.x * 64;

    // ---- prefetch h[src]/h[dst] into registers (hidden under encoder) ----
    const int eRow = t >> 2, part = t & 3;
    int srcN = ei[e0 + eRow];
    int dstN = ei[NE + e0 + eRow];
    if (part == 0) sGf[eRow] = batch[srcN];
    short8 rs[4], rd[4];
    {
        const short8* ps = (const short8*)(hbf + (size_t)srcN*HD + part*32);
        const short8* pd = (const short8*)(hbf + (size_t)dstN*HD + part*32);
#pragma unroll
        for (int w = 0; w < 4; ++w) { rs[w] = ps[w]; rd[w] = pd[w]; }
    }

    if (t < 192) sEa[t] = ea[e0*3 + t];
    __syncthreads();

    // ---- enc1: relu(ea@ew1+b1) -> bufChunk ----
    for (int it = 0; it < 16; ++it) {
        int dw = it*256 + t;
        int e = dw >> 6, cd = dw & 63;
        int c0 = cd*2;
        float x0 = sEa[e*3], x1 = sEa[e*3+1], x2 = sEa[e*3+2];
        float v0 = eb1[c0]   + x0*ew1[c0]   + x1*ew1[HD+c0]   + x2*ew1[2*HD+c0];
        float v1 = eb1[c0+1] + x0*ew1[c0+1] + x1*ew1[HD+c0+1] + x2*ew1[2*HD+c0+1];
        v0 = fmaxf(v0, 0.f); v1 = fmaxf(v1, 0.f);
        int ci = cd >> 2;
        ((u32*)bufChunk)[e*64 + ((ci ^ swzr(e & 15)) << 2) + (cd & 3)] = cvtpk(v0, v1);
    }
    __syncthreads();

    // ---- enc2: relu(A@ew2+b2) -> bufWide chunk0 ----
    {
        f32x4 acc[4][2];
#pragma unroll
        for (int ni = 0; ni < 2; ++ni) {
            float b = eb2[(2*wid + ni)*16 + (l & 15)];
#pragma unroll
            for (int mi = 0; mi < 4; ++mi) acc[mi][ni] = (f32x4){b,b,b,b};
        }
#pragma unroll
        for (int kk = 0; kk < 4; ++kk) {
            short8 af[4];
#pragma unroll
            for (int mi = 0; mi < 4; ++mi) af[mi] = loadA(bufChunk, mi, kk, l);
#pragma unroll
            for (int ni = 0; ni < 2; ++ni) {
                short8 bw = loadB(ew2p, 2*wid + ni, kk, 4, l);
#pragma unroll
                for (int mi = 0; mi < 4; ++mi) acc[mi][ni] = MFMA16(af[mi], bw, acc[mi][ni]);
            }
        }
#pragma unroll
        for (int ni = 0; ni < 2; ++ni) {
            int col = (2*wid + ni)*16 + (l & 15);
#pragma unroll
            for (int mi = 0; mi < 4; ++mi) {
                int R = mi*16 + ((l >> 4) << 2);
                storeQuad((u32*)bufWide, R, col, l,
                          fmaxf(acc[mi][ni][0], 0.f), fmaxf(acc[mi][ni][1], 0.f),
                          fmaxf(acc[mi][ni][2], 0.f), fmaxf(acc[mi][ni][3], 0.f));
            }
        }
    }
    __syncthreads();

    // ---- enc3: W0@ew3+b3 (pre-LN) -> bufChunk ----
    {
        f32x4 acc[4][2];
#pragma unroll
        for (int ni = 0; ni < 2; ++ni) {
            float b = eb3[(2*wid + ni)*16 + (l & 15)];
#pragma unroll
            for (int mi = 0; mi < 4; ++mi) acc[mi][ni] = (f32x4){b,b,b,b};
        }
#pragma unroll
        for (int kk = 0; kk < 4; ++kk) {
            short8 af[4];
#pragma unroll
            for (int mi = 0; mi < 4; ++mi) af[mi] = loadA(bufWide, mi, kk, l);
#pragma unroll
            for (int ni = 0; ni < 2; ++ni) {
                short8 bw = loadB(ew3p, 2*wid + ni, kk, 4, l);
#pragma unroll
                for (int mi = 0; mi < 4; ++mi) acc[mi][ni] = MFMA16(af[mi], bw, acc[mi][ni]);
            }
        }
#pragma unroll
        for (int ni = 0; ni < 2; ++ni) {
            int col = (2*wid + ni)*16 + (l & 15);
#pragma unroll
            for (int mi = 0; mi < 4; ++mi) {
                int R = mi*16 + ((l >> 4) << 2);
                storeQuad((u32*)bufChunk, R, col, l,
                          acc[mi][ni][0], acc[mi][ni][1], acc[mi][ni][2], acc[mi][ni][3]);
            }
        }
    }
    __syncthreads();

    // ---- write prefetched h[src]/h[dst] to bufWide (enc2 data dead) ----
    {
        u16* drow0 = bufWide + eRow*128;
        u16* drow1 = bufWide + 8192 + eRow*128;
        int re = swzr(eRow & 15);
#pragma unroll
        for (int w = 0; w < 4; ++w) {
            int ci = (part*4 + w) ^ re;
            *(short8*)(drow0 + (ci << 3)) = rs[w];
            *(short8*)(drow1 + (ci << 3)) = rd[w];
        }
    }

    // ---- LN stats: 4 lanes per edge, rotated read ----
    {
        int e = wid*16 + (l >> 2);
        int q = l & 3;
        const u32* rowp = (const u32*)bufChunk + e*64;
        float s = 0.f, sq = 0.f;
#pragma unroll
        for (int i = 0; i < 16; ++i) {
            u32 pk = rowp[q*16 + ((i + e) & 15)];
            float a = bf2f(pk & 0xffffu), b = bf2f(pk >> 16);
            s += a + b;
            sq = fmaf(a, a, fmaf(b, b, sq));
        }
        s  += __shfl_xor(s, 1);  sq += __shfl_xor(sq, 1);
        s  += __shfl_xor(s, 2);  sq += __shfl_xor(sq, 2);
        if (q == 0) {
            float mu = s * (1.f/HD);
            rstat[e] = mu;
            rstat[64 + e] = rsqrtf(sq*(1.f/HD) - mu*mu + LN_EPS);
        }
    }
    __syncthreads();

    // ---- normalize in place: bufChunk = ef ----
    for (int it = 0; it < 16; ++it) {
        int pd = it*256 + t;
        int row = pd >> 6, cwd = pd & 63;
        int ci = (cwd >> 2) ^ swzr(row & 15);
        int col = ci*8 + (cwd & 3)*2;
        u32 pk = ((u32*)bufChunk)[pd];
        float mu = rstat[row], ri = rstat[64 + row];
        float v0 = (bf2f(pk & 0xffffu) - mu)*ri*egm[col]     + ebb[col];
        float v1 = (bf2f(pk >> 16)     - mu)*ri*egm[col + 1] + ebb[col + 1];
        ((u32*)bufChunk)[pd] = cvtpk(v0, v1);
    }
    __syncthreads();

    // ---- ep1 MFMA: ef (ks 12..15), hsrc (ks 0..3), hdst (ks 4..7) ----
    f32x4 acc1[4][4];
#pragma unroll
    for (int ni = 0; ni < 4; ++ni) {
        float b = p1b[(4*wid + ni)*16 + (l & 15)];
#pragma unroll
        for (int mi = 0; mi < 4; ++mi) acc1[mi][ni] = (f32x4){b,b,b,b};
    }
#pragma unroll
    for (int kk = 0; kk < 4; ++kk) {
        short8 af[4];
#pragma unroll
        for (int mi = 0; mi < 4; ++mi) af[mi] = loadA(bufChunk, mi, kk, l);
#pragma unroll
        for (int ni = 0; ni < 4; ++ni) {
            short8 bw = loadB(p1wp, 4*wid + ni, 12 + kk, 16, l);
#pragma unroll
            for (int mi = 0; mi < 4; ++mi) acc1[mi][ni] = MFMA16(af[mi], bw, acc1[mi][ni]);
        }
    }
#pragma unroll
    for (int kk = 0; kk < 4; ++kk) {
        short8 af[4];
#pragma unroll
        for (int mi = 0; mi < 4; ++mi) af[mi] = loadA(bufWide, mi, kk, l);
#pragma unroll
        for (int ni = 0; ni < 4; ++ni) {
            short8 bw = loadB(p1wp, 4*wid + ni, kk, 16, l);
#pragma unroll
            for (int mi = 0; mi < 4; ++mi) acc1[mi][ni] = MFMA16(af[mi], bw, acc1[mi][ni]);
        }
    }
#pragma unroll
    for (int kk = 0; kk < 4; ++kk) {
        short8 af[4];
#pragma unroll
        for (int mi = 0; mi < 4; ++mi) af[mi] = loadA(bufWide + 8192, mi, kk, l);
#pragma unroll
        for (int ni = 0; ni < 4; ++ni) {
            short8 bw = loadB(p1wp, 4*wid + ni, 4 + kk, 16, l);
#pragma unroll
            for (int mi = 0; mi < 4; ++mi) acc1[mi][ni] = MFMA16(af[mi], bw, acc1[mi][ni]);
        }
    }
    __syncthreads();

    // ---- stage gf -> bufChunk (ef dead), MFMA (ks 8..11), tanh -> bufWide ----
    stageRows(bufChunk, gfbf, sGf, t);
    __syncthreads();
#pragma unroll
    for (int kk = 0; kk < 4; ++kk) {
        short8 af[4];
#pragma unroll
        for (int mi = 0; mi < 4; ++mi) af[mi] = loadA(bufChunk, mi, kk, l);
#pragma unroll
        for (int ni = 0; ni < 4; ++ni) {
            short8 bw = loadB(p1wp, 4*wid + ni, 8 + kk, 16, l);
#pragma unroll
            for (int mi = 0; mi < 4; ++mi) acc1[mi][ni] = MFMA16(af[mi], bw, acc1[mi][ni]);
        }
    }
#pragma unroll
    for (int ni = 0; ni < 4; ++ni) {
        int col = (4*wid + ni)*16 + (l & 15);
        u32* dst = (u32*)bufWide + ((col >> 7) << 12);
        int cc = col & 127;
#pragma unroll
        for (int mi = 0; mi < 4; ++mi) {
            int R = mi*16 + ((l >> 4) << 2);
            storeQuad(dst, R, cc, l,
                      fast_tanh(acc1[mi][ni][0]), fast_tanh(acc1[mi][ni][1]),
                      fast_tanh(acc1[mi][ni][2]), fast_tanh(acc1[mi][ni][3]));
        }
    }
    __syncthreads();

    // ---- ep2: [64,256]@p2w[256,128], tanh -> bufChunk ----
    {
        f32x4 acc[4][2];
#pragma unroll
        for (int ni = 0; ni < 2; ++ni) {
            float b = p2b[(2*wid + ni)*16 + (l & 15)];
#pragma unroll
            for (int mi = 0; mi < 4; ++mi) acc[mi][ni] = (f32x4){b,b,b,b};
        }
        for (int kc = 0; kc < 2; ++kc) {
            const u16* abuf = bufWide + (kc << 13);
#pragma unroll
            for (int kk = 0; kk < 4; ++kk) {
                short8 af[4];
#pragma unroll
                for (int mi = 0; mi < 4; ++mi) af[mi] = loadA(abuf, mi, kk, l);
                int ks = kc*4 + kk;
#pragma unroll
                for (int ni = 0; ni < 2; ++ni) {
                    short8 bw = loadB(p2wp, 2*wid + ni, ks, 8, l);
#pragma unroll
                    for (int mi = 0; mi < 4; ++mi) acc[mi][ni] = MFMA16(af[mi], bw, acc[mi][ni]);
                }
            }
        }
#pragma unroll
        for (int ni = 0; ni < 2; ++ni) {
            int col = (2*wid + ni)*16 + (l & 15);
#pragma unroll
            for (int mi = 0; mi < 4; ++mi) {
                int R = mi*16 + ((l >> 4) << 2);
                storeQuad((u32*)bufChunk, R, col, l,
                          fast_tanh(acc[mi][ni][0]), fast_tanh(acc[mi][ni][1]),
                          fast_tanh(acc[mi][ni][2]), fast_tanh(acc[mi][ni][3]));
            }
        }
    }
    __syncthreads();

    // ---- ep3: [64,128]@p3w[128,64], relu -> bufWide fp32 stride-65 ----
    {
        f32x4 acc[4];
        {
            float b = p3b[wid*16 + (l & 15)];
#pragma unroll
            for (int mi = 0; mi < 4; ++mi) acc[mi] = (f32x4){b,b,b,b};
        }
#pragma unroll
        for (int kk = 0; kk < 4; ++kk) {
            short8 af[4];
#pragma unroll
            for (int mi = 0; mi < 4; ++mi) af[mi] = loadA(bufChunk, mi, kk, l);
            short8 bw = loadB(p3wp, wid, kk, 4, l);
#pragma unroll
            for (int mi = 0; mi < 4; ++mi) acc[mi] = MFMA16(af[mi], bw, acc[mi]);
        }
        float* fb = (float*)bufWide;
        int col = wid*16 + (l & 15);
#pragma unroll
        for (int mi = 0; mi < 4; ++mi)
#pragma unroll
            for (int rr = 0; rr < 4; ++rr) {
                int row = mi*16 + ((l >> 4) << 2) + rr;
                fb[row*65 + col] = fmaxf(acc[mi][rr], 0.f);
            }
    }
    __syncthreads();

    // ---- ep4: 4 lanes/edge dot-64 + sigmoid ----
    {
        const float* fb = (const float*)bufWide;
        int e = wid*16 + (l >> 2), q = l & 3;
        float v = 0.f;
#pragma unroll
        for (int k = 0; k < 16; ++k) {
            int i = q*16 + k;
            v = fmaf(fb[e*65 + i], p4w[i], v);
        }
        v += __shfl_xor(v, 1);
        v += __shfl_xor(v, 2);
        if (q == 0) out[e0 + e] = fast_sigmoid(v + p4b[0]);
    }
}

// ---------------------------------------------------------------------------
extern "C" void kernel_launch(void* const* d_in, const int* in_sizes, int n_in,
                              void* d_out, int out_size, void* d_ws, size_t ws_size,
                              hipStream_t stream)
{
    const float* x     = (const float*)d_in[0];
    const int*   ei    = (const int*)  d_in[1];
    const float* ea    = (const float*)d_in[2];
    const int*   batch = (const int*)  d_in[3];
    const float* ne1w = (const float*)d_in[4];  const float* ne1b = (const float*)d_in[5];
    const float* ne2w = (const float*)d_in[6];  const float* ne2b = (const float*)d_in[7];
    const float* ne3w = (const float*)d_in[8];  const float* ne3b = (const float*)d_in[9];
    const float* neg  = (const float*)d_in[10]; const float* nebb = (const float*)d_in[11];
    const float* ee1w = (const float*)d_in[12]; const float* ee1b = (const float*)d_in[13];
    const float* ee2w = (const float*)d_in[14]; const float* ee2b = (const float*)d_in[15];
    const float* ee3w = (const float*)d_in[16]; const float* ee3b = (const float*)d_in[17];
    const float* eeg  = (const float*)d_in[18]; const float* eebb = (const float*)d_in[19];
    const float* g1w  = (const float*)d_in[20]; const float* g1b  = (const float*)d_in[21];
    const float* g2w  = (const float*)d_in[22]; const float* g2b  = (const float*)d_in[23];
    const float* gp1w = (const float*)d_in[24]; const float* gp1b = (const float*)d_in[25];
    const float* gp2w = (const float*)d_in[26]; const float* gp2b = (const float*)d_in[27];
    const float* gpg  = (const float*)d_in[28]; const float* gpbb = (const float*)d_in[29];
    const float* p1w  = (const float*)d_in[30]; const float* p1b  = (const float*)d_in[31];
    const float* p2w  = (const float*)d_in[32]; const float* p2b  = (const float*)d_in[33];
    const float* p3w  = (const float*)d_in[34]; const float* p3b  = (const float*)d_in[35];
    const float* p4w  = (const float*)d_in[36]; const float* p4b  = (const float*)d_in[37];

    float* dinv = (float*)d_ws;                // NN
    float* sums = dinv + NN;                   // NG*HD
    float* cnts = sums + NG*HD;                // NG
    int* degi   = (int*)(cnts + NG);           // NN
    int* cursor = degi + NN;                   // NN+2
    int* rowptr = cursor + NN + 2;             // NN+2
    int* sadj   = rowptr + NN + 2;             // NE
    u16* xw1p   = (u16*)(sadj + NE);           // NN*HD
    u16* xw2p   = xw1p + (size_t)NN*HD;        // NN*HD
    u16* hbf    = xw2p + (size_t)NN*HD;        // NN*HD
    u16* gf16   = hbf + (size_t)NN*HD;         // NG*HD
    u16* wpk    = gf16 + NG*HD;                // 270336
    u16* ee2p = wpk;
    u16* ee3p = wpk + 16384;
    u16* p1p  = wpk + 32768;
    u16* p2p  = wpk + 163840;
    u16* p3p  = wpk + 196608;
    u16* ne2p = wpk + 204800;
    u16* ne3p = wpk + 221184;
    u16* g1p  = wpk + 237568;
    u16* g2p  = wpk + 253952;

    float* out = (float*)d_out;

    hipMemsetAsync(degi, 0, (size_t)(2*NN + 2)*sizeof(int), stream);
    hipMemsetAsync(sums, 0, (size_t)(NG*HD + NG)*sizeof(float), stream);

    pack_all<<<(270336 + 255)/256, 256, 0, stream>>>(ee2w, ee3w, p1w, p2w, p3w,
                                                     ne2w, ne3w, g1w, g2w, wpk);

    // CSR build (+dinv fused into scan)
    deg_count_int<<<(NE + 255)/256, 256, 0, stream>>>(ei, degi);
    scan_excl<<<1, 1024, 0, stream>>>(degi, rowptr, dinv);
    fill_csr<<<(NE + 255)/256, 256, 0, stream>>>(ei, rowptr, cursor, sadj);

    // node encoder + g1 GEMM (bf16 out, prescaled by dinv)
    enc_mfma<<<(NN + 63)/64, 256, 0, stream>>>(x, ne1w, ne1b, ne2p, ne2b, ne3p, ne3b,
                                               neg, nebb, g1p, dinv, (u32*)xw1p);
    // GCN1 gather + relu + g2 GEMM
    gcn_agg1_mfma<<<(NN + 63)/64, 256, 0, stream>>>(xw1p, rowptr, sadj, dinv,
                                                    g1b, g2p, (u32*)xw2p);
    // GCN2 gather -> hbf bf16
    gcn_agg2_gather<<<(NN + 63)/64, 256, 0, stream>>>(xw2p, rowptr, sadj, dinv,
                                                      g2b, (u32*)hbf);

    // pool (+counts fused) + graph MLP
    pool_sorted<<<POOL_B, 128, 0, stream>>>(hbf, batch, sums, cnts);
    graph_feat<<<NG, 128, 0, stream>>>(sums, cnts, gp1w, gp1b, gp2w, gp2b,
                                       gpg, gpbb, gf16);

    // fused edge encoder + edge-score MLP
    edge_mlp_mfma<<<NE/64, 256, 0, stream>>>(hbf, gf16, ei, batch, ea,
                                             ee1w, ee1b, ee2p, ee2b, ee3p, ee3b,
                                             eeg, eebb,
                                             p1p, p1b, p2p, p2b, p3p, p3b,
                                             p4w, p4b, out);
}

// Round 14
// 451.467 us; speedup vs baseline: 1.9278x; 1.1619x over previous
//
#include <hip/hip_runtime.h>
#include <math.h>

#define NN 50000
#define NE 400000
#define NG 64
#define HD 128
#define LN_EPS 1e-5f

typedef unsigned short u16;
typedef unsigned int u32;
typedef __attribute__((ext_vector_type(8))) short short8;
typedef __attribute__((ext_vector_type(4))) float f32x4;

#define MFMA16(a,b,c) __builtin_amdgcn_mfma_f32_16x16x32_bf16((a),(b),(c),0,0,0)

__device__ __forceinline__ u16 f2bf(float f) {
    union { float f; u32 u; } v; v.f = f;
    u32 r = v.u + 0x7FFFu + ((v.u >> 16) & 1u);
    return (u16)(r >> 16);
}
__device__ __forceinline__ float bf2f(u32 hs) {
    union { u32 u; float f; } v; v.u = hs << 16;
    return v.f;
}
__device__ __forceinline__ float fast_rcp(float x) {
    float r; asm("v_rcp_f32 %0, %1" : "=v"(r) : "v"(x)); return r;
}
__device__ __forceinline__ float fast_exp2(float x) {
    float r; asm("v_exp_f32 %0, %1" : "=v"(r) : "v"(x)); return r;
}
__device__ __forceinline__ u32 cvtpk(float lo, float hi) {
    u32 r; asm("v_cvt_pk_bf16_f32 %0, %1, %2" : "=v"(r) : "v"(lo), "v"(hi)); return r;
}
// tanh(x) = 1 - 2/(1+2^(2*log2e*x)); exp2 saturates correctly at +-inf
__device__ __forceinline__ float fast_tanh(float x) {
    return fmaf(-2.f, fast_rcp(1.f + fast_exp2(2.885390082f * x)), 1.f);
}
__device__ __forceinline__ float fast_sigmoid(float x) {
    return fast_rcp(1.f + fast_exp2(-1.442695041f * x));
}

// swizzle term for row within 16-row group
__device__ __forceinline__ int swzr(int row) {
    return (row & 7) ^ ((row & 8) >> 2);
}

// A-fragment load from swizzled [64][128] bf16 chunk buffer.
__device__ __forceinline__ short8 loadA(const u16* buf, int mi, int kk, int l) {
    int row = mi*16 + (l & 15);
    int ci  = (kk*4 + (l >> 4)) ^ swzr(l & 15);
    return *(const short8*)(buf + row*128 + (ci << 3));
}
__device__ __forceinline__ short8 loadB(const u16* wp, int nt, int ks, int nk, int l) {
    return *(const short8*)(wp + (((nt*nk + ks)*64 + l) << 3));
}

// Store 4 accumulator values (rows R..R+3, col c) into swizzled bf16 chunk as
// packed u32 via lane-pair exchange + v_cvt_pk_bf16_f32.
__device__ __forceinline__ void storeQuad(u32* buf, int R, int c, int l,
                                          float v0, float v1, float v2, float v3)
{
    int cw = c >> 1;
    int par = l & 1;
    float send = par ? v0 : v1;
    float recv = __shfl_xor(send, 1);
    int row = R + par;
    u32 word = par ? cvtpk(recv, v1) : cvtpk(v0, recv);
    buf[row*64 + (((cw >> 2) ^ swzr(row & 15)) << 2) + (cw & 3)] = word;
    send = par ? v2 : v3;
    recv = __shfl_xor(send, 1);
    row = R + 2 + par;
    word = par ? cvtpk(recv, v3) : cvtpk(v2, recv);
    buf[row*64 + (((cw >> 2) ^ swzr(row & 15)) << 2) + (cw & 3)] = word;
}

// Unswizzle copy: LDS chunk -> global bf16 [64][128] rows n0..n0+63 (u32 words)
__device__ __forceinline__ void copyChunkOut(const u32* chunk, u32* gout, int n0, int t)
{
    for (int it = 0; it < 16; ++it) {
        int dw = it*256 + t;
        int row = dw >> 6, cw = dw & 63;
        if (n0 + row < NN)
            gout[(size_t)(n0 + row)*64 + cw] =
                chunk[row*64 + (((cw >> 2) ^ swzr(row & 15)) << 2) + (cw & 3)];
    }
}

// ---------------------------------------------------------------------------
// One-shot weight packing of all 9 GEMM weights -> bf16 MFMA B-fragment order.
// ---------------------------------------------------------------------------
__global__ __launch_bounds__(256)
void pack_all(const float* __restrict__ ee2w, const float* __restrict__ ee3w,
              const float* __restrict__ p1w,  const float* __restrict__ p2w,
              const float* __restrict__ p3w,  const float* __restrict__ ne2w,
              const float* __restrict__ ne3w, const float* __restrict__ g1w,
              const float* __restrict__ g2w,  u16* __restrict__ wpk)
{
    int idx = blockIdx.x*256 + threadIdx.x;
    if (idx >= 270336) return;
    const float* w; int K, N, local;
    if      (idx < 16384)  { w = ee2w; K = 128; N = 128; local = idx; }
    else if (idx < 32768)  { w = ee3w; K = 128; N = 128; local = idx - 16384; }
    else if (idx < 163840) { w = p1w;  K = 512; N = 256; local = idx - 32768; }
    else if (idx < 196608) { w = p2w;  K = 256; N = 128; local = idx - 163840; }
    else if (idx < 204800) { w = p3w;  K = 128; N = 64;  local = idx - 196608; }
    else if (idx < 221184) { w = ne2w; K = 128; N = 128; local = idx - 204800; }
    else if (idx < 237568) { w = ne3w; K = 128; N = 128; local = idx - 221184; }
    else if (idx < 253952) { w = g1w;  K = 128; N = 128; local = idx - 237568; }
    else                   { w = g2w;  K = 128; N = 128; local = idx - 253952; }
    int e = local & 7, l = (local >> 3) & 63, r = local >> 9;
    int nk = K >> 5;
    int nt = r / nk, kk = r % nk;
    int k = kk*32 + ((l >> 4) << 3) + e;
    int n = nt*16 + (l & 15);
    wpk[idx] = f2bf(w[k*N + n]);
}

// ---------------------------------------------------------------------------
// CSR build
// ---------------------------------------------------------------------------
__global__ __launch_bounds__(256)
void deg_count_int(const int* __restrict__ ei, int* __restrict__ degi)
{
    int e = blockIdx.x*256 + threadIdx.x;
    if (e < NE) atomicAdd(&degi[ei[NE + e]], 1);
}

__global__ __launch_bounds__(1024)
void scan_excl(const int* __restrict__ cnt, int* __restrict__ rp,
               float* __restrict__ dinv)
{
    __shared__ int wsum[16];
    __shared__ int carry;
    int t = threadIdx.x, lane = t & 63, w = t >> 6;
    int base = 0;
    for (int off = 0; off < NN; off += 4096) {
        int i0 = off + t*4;
        int v0 = (i0   < NN) ? cnt[i0]   : 0;
        int v1 = (i0+1 < NN) ? cnt[i0+1] : 0;
        int v2 = (i0+2 < NN) ? cnt[i0+2] : 0;
        int v3 = (i0+3 < NN) ? cnt[i0+3] : 0;
        int tot = v0 + v1 + v2 + v3;
        int s = tot;
#pragma unroll
        for (int d = 1; d < 64; d <<= 1) { int u = __shfl_up(s, d); if (lane >= d) s += u; }
        if (lane == 63) wsum[w] = s;
        __syncthreads();
        if (w == 0) {
            int wv = (lane < 16) ? wsum[lane] : 0;
            int ss = wv;
#pragma unroll
            for (int d = 1; d < 16; d <<= 1) { int u = __shfl_up(ss, d); if (lane >= d) ss += u; }
            if (lane < 16) wsum[lane] = ss - wv;
            if (lane == 15) carry = ss;
        }
        __syncthreads();
        int excl = base + wsum[w] + s - tot;
        if (i0   < NN) { rp[i0]   = excl;              dinv[i0]   = rsqrtf((float)v0 + 1.f); }
        if (i0+1 < NN) { rp[i0+1] = excl + v0;         dinv[i0+1] = rsqrtf((float)v1 + 1.f); }
        if (i0+2 < NN) { rp[i0+2] = excl + v0 + v1;    dinv[i0+2] = rsqrtf((float)v2 + 1.f); }
        if (i0+3 < NN) { rp[i0+3] = excl + v0 + v1 + v2; dinv[i0+3] = rsqrtf((float)v3 + 1.f); }
        base += carry;
        __syncthreads();
    }
    if (t == 0) rp[NN] = base;
}

__global__ __launch_bounds__(256)
void fill_csr(const int* __restrict__ ei, const int* __restrict__ rp,
              int* __restrict__ cursor, int* __restrict__ sadj)
{
    int e = blockIdx.x*256 + threadIdx.x;
    if (e >= NE) return;
    int d = ei[NE + e];
    int slot = atomicAdd(&cursor[d], 1);
    sadj[rp[d] + slot] = ei[e];
}

// ---------------------------------------------------------------------------
// Node encoder + g1w GEMM, MFMA. 64 nodes/block, 256 threads.
// ---------------------------------------------------------------------------
__global__ __launch_bounds__(256, 4)
void enc_mfma(const float* __restrict__ x,
              const float* __restrict__ w1, const float* __restrict__ b1,
              const u16* __restrict__ w2p, const float* __restrict__ b2,
              const u16* __restrict__ w3p, const float* __restrict__ b3,
              const float* __restrict__ gg, const float* __restrict__ bb,
              const u16* __restrict__ g1p, const float* __restrict__ dinv,
              u32* __restrict__ xw1p)
{
    __shared__ u16 chunkA[64*HD];
    __shared__ u16 chunkB[64*HD];
    __shared__ float sX[192];
    __shared__ float sDi[64];
    __shared__ float rstat[128];

    const int t = threadIdx.x;
    const int l = t & 63;
    const int wid = t >> 6;
    const int n0 = blockIdx.x * 64;

    if (t < 192) sX[t] = (n0*3 + t < NN*3) ? x[n0*3 + t] : 0.f;
    if (t < 64)  sDi[t] = (n0 + t < NN) ? dinv[n0 + t] : 0.f;
    __syncthreads();

    // L1: 3->128 relu (VALU) -> chunkA
    for (int it = 0; it < 16; ++it) {
        int dw = it*256 + t;
        int e = dw >> 6, cd = dw & 63;
        int c0 = cd*2;
        float x0 = sX[e*3], x1 = sX[e*3+1], x2 = sX[e*3+2];
        float v0 = b1[c0]   + x0*w1[c0]   + x1*w1[HD+c0]   + x2*w1[2*HD+c0];
        float v1 = b1[c0+1] + x0*w1[c0+1] + x1*w1[HD+c0+1] + x2*w1[2*HD+c0+1];
        v0 = fmaxf(v0, 0.f); v1 = fmaxf(v1, 0.f);
        int ci = cd >> 2;
        ((u32*)chunkA)[e*64 + ((ci ^ swzr(e & 15)) << 2) + (cd & 3)] = cvtpk(v0, v1);
    }
    __syncthreads();

    // L2 MFMA: relu(A@w2+b2) -> chunkB
    {
        f32x4 acc[4][2];
#pragma unroll
        for (int ni = 0; ni < 2; ++ni) {
            float b = b2[(2*wid + ni)*16 + (l & 15)];
#pragma unroll
            for (int mi = 0; mi < 4; ++mi) acc[mi][ni] = (f32x4){b,b,b,b};
        }
#pragma unroll
        for (int kk = 0; kk < 4; ++kk) {
            short8 af[4];
#pragma unroll
            for (int mi = 0; mi < 4; ++mi) af[mi] = loadA(chunkA, mi, kk, l);
#pragma unroll
            for (int ni = 0; ni < 2; ++ni) {
                short8 bw = loadB(w2p, 2*wid + ni, kk, 4, l);
#pragma unroll
                for (int mi = 0; mi < 4; ++mi) acc[mi][ni] = MFMA16(af[mi], bw, acc[mi][ni]);
            }
        }
#pragma unroll
        for (int ni = 0; ni < 2; ++ni) {
            int col = (2*wid + ni)*16 + (l & 15);
#pragma unroll
            for (int mi = 0; mi < 4; ++mi) {
                int R = mi*16 + ((l >> 4) << 2);
                storeQuad((u32*)chunkB, R, col, l,
                          fmaxf(acc[mi][ni][0], 0.f), fmaxf(acc[mi][ni][1], 0.f),
                          fmaxf(acc[mi][ni][2], 0.f), fmaxf(acc[mi][ni][3], 0.f));
            }
        }
    }
    __syncthreads();

    // L3 MFMA: B@w3+b3 (pre-LN) -> chunkA
    {
        f32x4 acc[4][2];
#pragma unroll
        for (int ni = 0; ni < 2; ++ni) {
            float b = b3[(2*wid + ni)*16 + (l & 15)];
#pragma unroll
            for (int mi = 0; mi < 4; ++mi) acc[mi][ni] = (f32x4){b,b,b,b};
        }
#pragma unroll
        for (int kk = 0; kk < 4; ++kk) {
            short8 af[4];
#pragma unroll
            for (int mi = 0; mi < 4; ++mi) af[mi] = loadA(chunkB, mi, kk, l);
#pragma unroll
            for (int ni = 0; ni < 2; ++ni) {
                short8 bw = loadB(w3p, 2*wid + ni, kk, 4, l);
#pragma unroll
                for (int mi = 0; mi < 4; ++mi) acc[mi][ni] = MFMA16(af[mi], bw, acc[mi][ni]);
            }
        }
#pragma unroll
        for (int ni = 0; ni < 2; ++ni) {
            int col = (2*wid + ni)*16 + (l & 15);
#pragma unroll
            for (int mi = 0; mi < 4; ++mi) {
                int R = mi*16 + ((l >> 4) << 2);
                storeQuad((u32*)chunkA, R, col, l,
                          acc[mi][ni][0], acc[mi][ni][1], acc[mi][ni][2], acc[mi][ni][3]);
            }
        }
    }
    __syncthreads();

    // LN stats: 4 lanes per row, rotated read
    {
        int e = wid*16 + (l >> 2);
        int q = l & 3;
        const u32* rowp = (const u32*)chunkA + e*64;
        float s = 0.f, sq = 0.f;
#pragma unroll
        for (int i = 0; i < 16; ++i) {
            u32 pk = rowp[q*16 + ((i + e) & 15)];
            float a = bf2f(pk & 0xffffu), b = bf2f(pk >> 16);
            s += a + b;
            sq = fmaf(a, a, fmaf(b, b, sq));
        }
        s  += __shfl_xor(s, 1);  sq += __shfl_xor(sq, 1);
        s  += __shfl_xor(s, 2);  sq += __shfl_xor(sq, 2);
        if (q == 0) {
            float mu = s * (1.f/HD);
            rstat[e] = mu;
            rstat[64 + e] = rsqrtf(sq*(1.f/HD) - mu*mu + LN_EPS);
        }
    }
    __syncthreads();

    // normalize in place
    for (int it = 0; it < 16; ++it) {
        int pd = it*256 + t;
        int row = pd >> 6, cwd = pd & 63;
        int ci = (cwd >> 2) ^ swzr(row & 15);
        int col = ci*8 + (cwd & 3)*2;
        u32 pk = ((u32*)chunkA)[pd];
        float mu = rstat[row], ri = rstat[64 + row];
        float v0 = (bf2f(pk & 0xffffu) - mu)*ri*gg[col]     + bb[col];
        float v1 = (bf2f(pk >> 16)     - mu)*ri*gg[col + 1] + bb[col + 1];
        ((u32*)chunkA)[pd] = cvtpk(v0, v1);
    }
    __syncthreads();

    // GEMM @g1w, scale by dinv -> chunkB -> global
    {
        f32x4 acc[4][2];
#pragma unroll
        for (int mi = 0; mi < 4; ++mi)
#pragma unroll
            for (int ni = 0; ni < 2; ++ni) acc[mi][ni] = (f32x4){0.f,0.f,0.f,0.f};
#pragma unroll
        for (int kk = 0; kk < 4; ++kk) {
            short8 af[4];
#pragma unroll
            for (int mi = 0; mi < 4; ++mi) af[mi] = loadA(chunkA, mi, kk, l);
#pragma unroll
            for (int ni = 0; ni < 2; ++ni) {
                short8 bw = loadB(g1p, 2*wid + ni, kk, 4, l);
#pragma unroll
                for (int mi = 0; mi < 4; ++mi) acc[mi][ni] = MFMA16(af[mi], bw, acc[mi][ni]);
            }
        }
#pragma unroll
        for (int ni = 0; ni < 2; ++ni) {
            int col = (2*wid + ni)*16 + (l & 15);
#pragma unroll
            for (int mi = 0; mi < 4; ++mi) {
                int R = mi*16 + ((l >> 4) << 2);
                storeQuad((u32*)chunkB, R, col, l,
                          acc[mi][ni][0]*sDi[R], acc[mi][ni][1]*sDi[R+1],
                          acc[mi][ni][2]*sDi[R+2], acc[mi][ni][3]*sDi[R+3]);
            }
        }
    }
    __syncthreads();
    copyChunkOut((const u32*)chunkB, xw1p, n0, t);
}

// ---------------------------------------------------------------------------
// GCN layer 1: gather bf16 xw1p (prescaled), relu(+g1b), MFMA @g2w, *dinv -> xw2p
// ---------------------------------------------------------------------------
__global__ __launch_bounds__(256, 4)
void gcn_agg1_mfma(const u16* __restrict__ xw1p, const int* __restrict__ rp,
                   const int* __restrict__ sadj, const float* __restrict__ dinv,
                   const float* __restrict__ g1b, const u16* __restrict__ g2p,
                   u32* __restrict__ xw2p)
{
    __shared__ u16 chunkA[64*HD];
    __shared__ u16 chunkB[64*HD];
    __shared__ float sDi[64];
    __shared__ float sB[HD];

    const int t = threadIdx.x;
    const int l = t & 63;
    const int wid = t >> 6;
    const int n0 = blockIdx.x * 64;

    if (t < 64)  sDi[t] = (n0 + t < NN) ? dinv[n0 + t] : 0.f;
    if (t < HD)  sB[t] = g1b[t];
    __syncthreads();

    {
        int s = t >> 2, part = t & 3, n = n0 + s;
        float acc[32];
#pragma unroll
        for (int j = 0; j < 32; ++j) acc[j] = 0.f;
        float di = 0.f;
        if (n < NN) {
            di = sDi[s];
            const short8* selfp = (const short8*)(xw1p + (size_t)n*HD + part*32);
#pragma unroll
            for (int w = 0; w < 4; ++w) {
                short8 v = selfp[w];
#pragma unroll
                for (int j = 0; j < 8; ++j) acc[w*8+j] += bf2f((u16)v[j]);
            }
            int k1 = rp[n+1];
            for (int k = rp[n]; k < k1; ++k) {
                const short8* rp8 = (const short8*)(xw1p + (size_t)sadj[k]*HD + part*32);
#pragma unroll
                for (int w = 0; w < 4; ++w) {
                    short8 v = rp8[w];
#pragma unroll
                    for (int j = 0; j < 8; ++j) acc[w*8+j] += bf2f((u16)v[j]);
                }
            }
        }
#pragma unroll
        for (int p = 0; p < 16; ++p) {
            float v0 = fmaxf(fmaf(acc[2*p],   di, sB[part*32 + 2*p]),   0.f);
            float v1 = fmaxf(fmaf(acc[2*p+1], di, sB[part*32 + 2*p+1]), 0.f);
            int cw = part*16 + p;
            ((u32*)chunkA)[s*64 + (((cw >> 2) ^ swzr(s & 15)) << 2) + (cw & 3)] = cvtpk(v0, v1);
        }
    }
    __syncthreads();

    {
        f32x4 acc[4][2];
#pragma unroll
        for (int mi = 0; mi < 4; ++mi)
#pragma unroll
            for (int ni = 0; ni < 2; ++ni) acc[mi][ni] = (f32x4){0.f,0.f,0.f,0.f};
#pragma unroll
        for (int kk = 0; kk < 4; ++kk) {
            short8 af[4];
#pragma unroll
            for (int mi = 0; mi < 4; ++mi) af[mi] = loadA(chunkA, mi, kk, l);
#pragma unroll
            for (int ni = 0; ni < 2; ++ni) {
                short8 bw = loadB(g2p, 2*wid + ni, kk, 4, l);
#pragma unroll
                for (int mi = 0; mi < 4; ++mi) acc[mi][ni] = MFMA16(af[mi], bw, acc[mi][ni]);
            }
        }
#pragma unroll
        for (int ni = 0; ni < 2; ++ni) {
            int col = (2*wid + ni)*16 + (l & 15);
#pragma unroll
            for (int mi = 0; mi < 4; ++mi) {
                int R = mi*16 + ((l >> 4) << 2);
                storeQuad((u32*)chunkB, R, col, l,
                          acc[mi][ni][0]*sDi[R], acc[mi][ni][1]*sDi[R+1],
                          acc[mi][ni][2]*sDi[R+2], acc[mi][ni][3]*sDi[R+3]);
            }
        }
    }
    __syncthreads();
    copyChunkOut((const u32*)chunkB, xw2p, n0, t);
}

// ---------------------------------------------------------------------------
// GCN layer 2: gather bf16 xw2p, +g2b -> hbf (bf16 only)
// ---------------------------------------------------------------------------
__global__ __launch_bounds__(256)
void gcn_agg2_gather(const u16* __restrict__ xw2p, const int* __restrict__ rp,
                     const int* __restrict__ sadj, const float* __restrict__ dinv,
                     const float* __restrict__ g2b, u32* __restrict__ hbw)
{
    int t = threadIdx.x;
    int s = t >> 2, part = t & 3;
    int n = blockIdx.x * 64 + s;
    if (n >= NN) return;
    float acc[32];
#pragma unroll
    for (int j = 0; j < 32; ++j) acc[j] = 0.f;
    const short8* selfp = (const short8*)(xw2p + (size_t)n*HD + part*32);
#pragma unroll
    for (int w = 0; w < 4; ++w) {
        short8 v = selfp[w];
#pragma unroll
        for (int j = 0; j < 8; ++j) acc[w*8+j] += bf2f((u16)v[j]);
    }
    int k1 = rp[n+1];
    for (int k = rp[n]; k < k1; ++k) {
        const short8* rp8 = (const short8*)(xw2p + (size_t)sadj[k]*HD + part*32);
#pragma unroll
        for (int w = 0; w < 4; ++w) {
            short8 v = rp8[w];
#pragma unroll
            for (int j = 0; j < 8; ++j) acc[w*8+j] += bf2f((u16)v[j]);
        }
    }
    float di = dinv[n];
    u32* hb = hbw + (size_t)n*64 + part*16;
#pragma unroll
    for (int p = 0; p < 16; ++p) {
        float v0 = fmaf(acc[2*p],   di, g2b[part*32 + 2*p]);
        float v1 = fmaf(acc[2*p+1], di, g2b[part*32 + 2*p+1]);
        hb[p] = cvtpk(v0, v1);
    }
}

// ---------------------------------------------------------------------------
// Pool (batch sorted, bf16 input) + fused counts + graph MLP
// ---------------------------------------------------------------------------
#define POOL_B 512
__global__ __launch_bounds__(128)
void pool_sorted(const u16* __restrict__ h, const int* __restrict__ batch,
                 float* __restrict__ sums, float* __restrict__ cnts)
{
    int b = blockIdx.x, j = threadIdx.x;
    int n0 = (int)(((long long)NN * b) / POOL_B);
    int n1 = (int)(((long long)NN * (b+1)) / POOL_B);
    int g = -1; float acc = 0.f, cl = 0.f;
    for (int n = n0; n < n1; ++n) {
        int bg = batch[n];
        if (bg != g) {
            if (g >= 0) {
                atomicAdd(&sums[g*HD + j], acc);
                if (j == 0) atomicAdd(&cnts[g], cl);
            }
            g = bg; acc = 0.f; cl = 0.f;
        }
        acc += bf2f(h[(size_t)n*HD + j]);
        cl += 1.f;
    }
    if (g >= 0) {
        atomicAdd(&sums[g*HD + j], acc);
        if (j == 0) atomicAdd(&cnts[g], cl);
    }
}

__global__ __launch_bounds__(128)
void graph_feat(const float* __restrict__ sums, const float* __restrict__ cnts,
                const float* __restrict__ w1, const float* __restrict__ b1,
                const float* __restrict__ w2, const float* __restrict__ b2,
                const float* __restrict__ gg, const float* __restrict__ bb,
                u16* __restrict__ gf16)
{
    int gi = blockIdx.x, j = threadIdx.x;
    __shared__ float s0[HD];
    __shared__ float s1[HD];
    __shared__ float part[4];
    __shared__ float stat[2];
    float cnt = fmaxf(cnts[gi], 1.f);
    s0[j] = sums[gi*HD + j] / cnt;
    __syncthreads();
    float a = b1[j];
    for (int i = 0; i < HD; ++i) a = fmaf(s0[i], w1[i*HD + j], a);
    s1[j] = fmaxf(a, 0.f);
    __syncthreads();
    a = b2[j];
    for (int i = 0; i < HD; ++i) a = fmaf(s1[i], w2[i*HD + j], a);
    float s = a, q = a*a;
    for (int o = 32; o > 0; o >>= 1) { s += __shfl_down(s, o); q += __shfl_down(q, o); }
    int wid = j >> 6, lane = j & 63;
    if (lane == 0) { part[wid] = s; part[2 + wid] = q; }
    __syncthreads();
    if (j == 0) {
        float S = part[0] + part[1], Q = part[2] + part[3];
        float mu = S * (1.f/HD);
        stat[0] = mu;
        stat[1] = Q * (1.f/HD) - mu*mu;
    }
    __syncthreads();
    float v = (a - stat[0]) * rsqrtf(stat[1] + LN_EPS) * gg[j] + bb[j];
    gf16[gi*HD + j] = f2bf(v);
}

// ---------------------------------------------------------------------------
// Stage 64 gathered bf16 rows into swizzled LDS chunk (first 256 threads)
// ---------------------------------------------------------------------------
__device__ __forceinline__ void stageRows(u16* dst, const u16* __restrict__ srcBase,
                                          const int* ridx, int t)
{
    int e = t >> 2, part = t & 3;
    const u16* src = srcBase + (size_t)ridx[e]*HD + part*32;
    u16* drow = dst + e*128;
    int re = swzr(e & 15);
#pragma unroll
    for (int w = 0; w < 4; ++w) {
        int ci = (part*4 + w) ^ re;
        *(short8*)(drow + (ci << 3)) = *(const short8*)(src + w*8);
    }
}

// ---------------------------------------------------------------------------
// Fused edge kernel (MFMA bf16). 64 edges/block, 512 threads (8 waves).
// Same work per block as the 256-thread version but the accumulator is split
// across 2x the waves: ep1 acc[4][2]=32 regs/thread (vs 64), enc/ep2 acc[4]=16.
// Targets <=128 VGPR -> 2 blocks/CU = 16 waves/CU (2x round-13 occupancy).
// ---------------------------------------------------------------------------
__global__ __launch_bounds__(512, 3)
void edge_mlp_mfma(const u16* __restrict__ hbf, const u16* __restrict__ gfbf,
                   const int* __restrict__ ei, const int* __restrict__ batch,
                   const float* __restrict__ ea,
                   const float* __restrict__ ew1, const float* __restrict__ eb1,
                   const u16* __restrict__ ew2p, const float* __restrict__ eb2,
                   const u16* __restrict__ ew3p, const float* __restrict__ eb3,
                   const float* __restrict__ egm, const float* __restrict__ ebb,
                   const u16* __restrict__ p1wp, const float* __restrict__ p1b,
                   const u16* __restrict__ p2wp, const float* __restrict__ p2b,
                   const u16* __restrict__ p3wp, const float* __restrict__ p3b,
                   const float* __restrict__ p4w, const float* __restrict__ p4b,
                   float* __restrict__ out)
{
    __shared__ u16 bufChunk[64*HD];    // 16KB swizzled A-chunk
    __shared__ u16 bufWide[64*256];    // 32KB (2 chunks / fp32 scratch)
    __shared__ float sEa[192];
    __shared__ int sGf[64];
    __shared__ float rstat[128];

    const int t = threadIdx.x;
    const int l = t & 63;
    const int wid = t >> 6;            // 0..7
    const int e0 = blockIdx.x * 64;

    // ---- prefetch h[src]/h[dst] into registers (8 threads/row, 16 regs) ----
    const int eRow = t >> 3, part8 = t & 7;
    int srcN = ei[e0 + eRow];
    int dstN = ei[NE + e0 + eRow];
    if (part8 == 0) sGf[eRow] = batch[srcN];
    short8 rs[2], rd[2];
    {
        const short8* ps = (const short8*)(hbf + (size_t)srcN*HD + part8*16);
        const short8* pd = (const short8*)(hbf + (size_t)dstN*HD + part8*16);
#pragma unroll
        for (int w = 0; w < 2; ++w) { rs[w] = ps[w]; rd[w] = pd[w]; }
    }

    if (t < 192) sEa[t] = ea[e0*3 + t];
    __syncthreads();

    // ---- enc1: relu(ea@ew1+b1) -> bufChunk ----
    for (int it = 0; it < 8; ++it) {
        int dw = it*512 + t;
        int e = dw >> 6, cd = dw & 63;
        int c0 = cd*2;
        float x0 = sEa[e*3], x1 = sEa[e*3+1], x2 = sEa[e*3+2];
        float v0 = eb1[c0]   + x0*ew1[c0]   + x1*ew1[HD+c0]   + x2*ew1[2*HD+c0];
        float v1 = eb1[c0+1] + x0*ew1[c0+1] + x1*ew1[HD+c0+1] + x2*ew1[2*HD+c0+1];
        v0 = fmaxf(v0, 0.f); v1 = fmaxf(v1, 0.f);
        int ci = cd >> 2;
        ((u32*)bufChunk)[e*64 + ((ci ^ swzr(e & 15)) << 2) + (cd & 3)] = cvtpk(v0, v1);
    }
    __syncthreads();

    // ---- enc2: relu(A@ew2+b2) -> bufWide chunk0 (wave owns col tile wid) ----
    {
        f32x4 acc[4];
        {
            float b = eb2[wid*16 + (l & 15)];
#pragma unroll
            for (int mi = 0; mi < 4; ++mi) acc[mi] = (f32x4){b,b,b,b};
        }
#pragma unroll
        for (int kk = 0; kk < 4; ++kk) {
            short8 af[4];
#pragma unroll
            for (int mi = 0; mi < 4; ++mi) af[mi] = loadA(bufChunk, mi, kk, l);
            short8 bw = loadB(ew2p, wid, kk, 4, l);
#pragma unroll
            for (int mi = 0; mi < 4; ++mi) acc[mi] = MFMA16(af[mi], bw, acc[mi]);
        }
        int col = wid*16 + (l & 15);
#pragma unroll
        for (int mi = 0; mi < 4; ++mi) {
            int R = mi*16 + ((l >> 4) << 2);
            storeQuad((u32*)bufWide, R, col, l,
                      fmaxf(acc[mi][0], 0.f), fmaxf(acc[mi][1], 0.f),
                      fmaxf(acc[mi][2], 0.f), fmaxf(acc[mi][3], 0.f));
        }
    }
    __syncthreads();

    // ---- enc3: W0@ew3+b3 (pre-LN) -> bufChunk ----
    {
        f32x4 acc[4];
        {
            float b = eb3[wid*16 + (l & 15)];
#pragma unroll
            for (int mi = 0; mi < 4; ++mi) acc[mi] = (f32x4){b,b,b,b};
        }
#pragma unroll
        for (int kk = 0; kk < 4; ++kk) {
            short8 af[4];
#pragma unroll
            for (int mi = 0; mi < 4; ++mi) af[mi] = loadA(bufWide, mi, kk, l);
            short8 bw = loadB(ew3p, wid, kk, 4, l);
#pragma unroll
            for (int mi = 0; mi < 4; ++mi) acc[mi] = MFMA16(af[mi], bw, acc[mi]);
        }
        int col = wid*16 + (l & 15);
#pragma unroll
        for (int mi = 0; mi < 4; ++mi) {
            int R = mi*16 + ((l >> 4) << 2);
            storeQuad((u32*)bufChunk, R, col, l,
                      acc[mi][0], acc[mi][1], acc[mi][2], acc[mi][3]);
        }
    }
    __syncthreads();

    // ---- write prefetched h[src]/h[dst] to bufWide (enc2 data dead) ----
    {
        u16* drow0 = bufWide + eRow*128;
        u16* drow1 = bufWide + 8192 + eRow*128;
        int re = swzr(eRow & 15);
#pragma unroll
        for (int w = 0; w < 2; ++w) {
            int ci = (part8*2 + w) ^ re;
            *(short8*)(drow0 + (ci << 3)) = rs[w];
            *(short8*)(drow1 + (ci << 3)) = rd[w];
        }
    }

    // ---- LN stats: 8 lanes per edge (all 512 threads), rotated read ----
    {
        int e = wid*8 + (l >> 3);
        int q = l & 7;
        const u32* rowp = (const u32*)bufChunk + e*64;
        float s = 0.f, sq = 0.f;
#pragma unroll
        for (int i = 0; i < 8; ++i) {
            u32 pk = rowp[q*8 + ((i + e) & 7)];
            float a = bf2f(pk & 0xffffu), b = bf2f(pk >> 16);
            s += a + b;
            sq = fmaf(a, a, fmaf(b, b, sq));
        }
        s  += __shfl_xor(s, 1);  sq += __shfl_xor(sq, 1);
        s  += __shfl_xor(s, 2);  sq += __shfl_xor(sq, 2);
        s  += __shfl_xor(s, 4);  sq += __shfl_xor(sq, 4);
        if (q == 0) {
            float mu = s * (1.f/HD);
            rstat[e] = mu;
            rstat[64 + e] = rsqrtf(sq*(1.f/HD) - mu*mu + LN_EPS);
        }
    }
    __syncthreads();

    // ---- normalize in place: bufChunk = ef ----
    for (int it = 0; it < 8; ++it) {
        int pd = it*512 + t;
        int row = pd >> 6, cwd = pd & 63;
        int ci = (cwd >> 2) ^ swzr(row & 15);
        int col = ci*8 + (cwd & 3)*2;
        u32 pk = ((u32*)bufChunk)[pd];
        float mu = rstat[row], ri = rstat[64 + row];
        float v0 = (bf2f(pk & 0xffffu) - mu)*ri*egm[col]     + ebb[col];
        float v1 = (bf2f(pk >> 16)     - mu)*ri*egm[col + 1] + ebb[col + 1];
        ((u32*)bufChunk)[pd] = cvtpk(v0, v1);
    }
    __syncthreads();

    // ---- ep1 MFMA: wave owns 2 col tiles (ni 0..1 -> global wid*2+ni).
    //      K-slices: ef (ks 12..15), hsrc (ks 0..3), hdst (ks 4..7) ----
    f32x4 acc1[4][2];
#pragma unroll
    for (int ni = 0; ni < 2; ++ni) {
        float b = p1b[(wid*2 + ni)*16 + (l & 15)];
#pragma unroll
        for (int mi = 0; mi < 4; ++mi) acc1[mi][ni] = (f32x4){b,b,b,b};
    }
#pragma unroll
    for (int kk = 0; kk < 4; ++kk) {
        short8 af[4];
#pragma unroll
        for (int mi = 0; mi < 4; ++mi) af[mi] = loadA(bufChunk, mi, kk, l);
#pragma unroll
        for (int ni = 0; ni < 2; ++ni) {
            short8 bw = loadB(p1wp, wid*2 + ni, 12 + kk, 16, l);
#pragma unroll
            for (int mi = 0; mi < 4; ++mi) acc1[mi][ni] = MFMA16(af[mi], bw, acc1[mi][ni]);
        }
    }
#pragma unroll
    for (int kk = 0; kk < 4; ++kk) {
        short8 af[4];
#pragma unroll
        for (int mi = 0; mi < 4; ++mi) af[mi] = loadA(bufWide, mi, kk, l);
#pragma unroll
        for (int ni = 0; ni < 2; ++ni) {
            short8 bw = loadB(p1wp, wid*2 + ni, kk, 16, l);
#pragma unroll
            for (int mi = 0; mi < 4; ++mi) acc1[mi][ni] = MFMA16(af[mi], bw, acc1[mi][ni]);
        }
    }
#pragma unroll
    for (int kk = 0; kk < 4; ++kk) {
        short8 af[4];
#pragma unroll
        for (int mi = 0; mi < 4; ++mi) af[mi] = loadA(bufWide + 8192, mi, kk, l);
#pragma unroll
        for (int ni = 0; ni < 2; ++ni) {
            short8 bw = loadB(p1wp, wid*2 + ni, 4 + kk, 16, l);
#pragma unroll
            for (int mi = 0; mi < 4; ++mi) acc1[mi][ni] = MFMA16(af[mi], bw, acc1[mi][ni]);
        }
    }
    __syncthreads();

    // ---- stage gf -> bufChunk (ef dead), MFMA (ks 8..11), tanh -> bufWide ----
    if (t < 256) stageRows(bufChunk, gfbf, sGf, t);
    __syncthreads();
#pragma unroll
    for (int kk = 0; kk < 4; ++kk) {
        short8 af[4];
#pragma unroll
        for (int mi = 0; mi < 4; ++mi) af[mi] = loadA(bufChunk, mi, kk, l);
#pragma unroll
        for (int ni = 0; ni < 2; ++ni) {
            short8 bw = loadB(p1wp, wid*2 + ni, 8 + kk, 16, l);
#pragma unroll
            for (int mi = 0; mi < 4; ++mi) acc1[mi][ni] = MFMA16(af[mi], bw, acc1[mi][ni]);
        }
    }
    __syncthreads();
#pragma unroll
    for (int ni = 0; ni < 2; ++ni) {
        int col = (wid*2 + ni)*16 + (l & 15);
        u32* dst = (u32*)bufWide + ((col >> 7) << 12);
        int cc = col & 127;
#pragma unroll
        for (int mi = 0; mi < 4; ++mi) {
            int R = mi*16 + ((l >> 4) << 2);
            storeQuad(dst, R, cc, l,
                      fast_tanh(acc1[mi][ni][0]), fast_tanh(acc1[mi][ni][1]),
                      fast_tanh(acc1[mi][ni][2]), fast_tanh(acc1[mi][ni][3]));
        }
    }
    __syncthreads();

    // ---- ep2: [64,256]@p2w[256,128], tanh -> bufChunk (wave owns tile wid) ----
    {
        f32x4 acc[4];
        {
            float b = p2b[wid*16 + (l & 15)];
#pragma unroll
            for (int mi = 0; mi < 4; ++mi) acc[mi] = (f32x4){b,b,b,b};
        }
        for (int kc = 0; kc < 2; ++kc) {
            const u16* abuf = bufWide + (kc << 13);
#pragma unroll
            for (int kk = 0; kk < 4; ++kk) {
                short8 af[4];
#pragma unroll
                for (int mi = 0; mi < 4; ++mi) af[mi] = loadA(abuf, mi, kk, l);
                short8 bw = loadB(p2wp, wid, kc*4 + kk, 8, l);
#pragma unroll
                for (int mi = 0; mi < 4; ++mi) acc[mi] = MFMA16(af[mi], bw, acc[mi]);
            }
        }
        int col = wid*16 + (l & 15);
#pragma unroll
        for (int mi = 0; mi < 4; ++mi) {
            int R = mi*16 + ((l >> 4) << 2);
            storeQuad((u32*)bufChunk, R, col, l,
                      fast_tanh(acc[mi][0]), fast_tanh(acc[mi][1]),
                      fast_tanh(acc[mi][2]), fast_tanh(acc[mi][3]));
        }
    }
    __syncthreads();

    // ---- ep3: [64,128]@p3w[128,64], relu -> bufWide fp32 stride-65.
    //      All waves compute tile (wid&3); only wid<4 store. ----
    {
        int wt = wid & 3;
        f32x4 acc[4];
        {
            float b = p3b[wt*16 + (l & 15)];
#pragma unroll
            for (int mi = 0; mi < 4; ++mi) acc[mi] = (f32x4){b,b,b,b};
        }
#pragma unroll
        for (int kk = 0; kk < 4; ++kk) {
            short8 af[4];
#pragma unroll
            for (int mi = 0; mi < 4; ++mi) af[mi] = loadA(bufChunk, mi, kk, l);
            short8 bw = loadB(p3wp, wt, kk, 4, l);
#pragma unroll
            for (int mi = 0; mi < 4; ++mi) acc[mi] = MFMA16(af[mi], bw, acc[mi]);
        }
        if (wid < 4) {
            float* fb = (float*)bufWide;
            int col = wt*16 + (l & 15);
#pragma unroll
            for (int mi = 0; mi < 4; ++mi)
#pragma unroll
                for (int rr = 0; rr < 4; ++rr) {
                    int row = mi*16 + ((l >> 4) << 2) + rr;
                    fb[row*65 + col] = fmaxf(acc[mi][rr], 0.f);
                }
        }
    }
    __syncthreads();

    // ---- ep4: 4 lanes/edge dot-64 + sigmoid (waves 0..3 cover 64 edges) ----
    {
        const float* fb = (const float*)bufWide;
        int e = (wid & 3)*16 + (l >> 2), q = l & 3;
        float v = 0.f;
#pragma unroll
        for (int k = 0; k < 16; ++k) {
            int i = q*16 + k;
            v = fmaf(fb[e*65 + i], p4w[i], v);
        }
        v += __shfl_xor(v, 1);
        v += __shfl_xor(v, 2);
        if (q == 0 && wid < 4) out[e0 + e] = fast_sigmoid(v + p4b[0]);
    }
}

// ---------------------------------------------------------------------------
extern "C" void kernel_launch(void* const* d_in, const int* in_sizes, int n_in,
                              void* d_out, int out_size, void* d_ws, size_t ws_size,
                              hipStream_t stream)
{
    const float* x     = (const float*)d_in[0];
    const int*   ei    = (const int*)  d_in[1];
    const float* ea    = (const float*)d_in[2];
    const int*   batch = (const int*)  d_in[3];
    const float* ne1w = (const float*)d_in[4];  const float* ne1b = (const float*)d_in[5];
    const float* ne2w = (const float*)d_in[6];  const float* ne2b = (const float*)d_in[7];
    const float* ne3w = (const float*)d_in[8];  const float* ne3b = (const float*)d_in[9];
    const float* neg  = (const float*)d_in[10]; const float* nebb = (const float*)d_in[11];
    const float* ee1w = (const float*)d_in[12]; const float* ee1b = (const float*)d_in[13];
    const float* ee2w = (const float*)d_in[14]; const float* ee2b = (const float*)d_in[15];
    const float* ee3w = (const float*)d_in[16]; const float* ee3b = (const float*)d_in[17];
    const float* eeg  = (const float*)d_in[18]; const float* eebb = (const float*)d_in[19];
    const float* g1w  = (const float*)d_in[20]; const float* g1b  = (const float*)d_in[21];
    const float* g2w  = (const float*)d_in[22]; const float* g2b  = (const float*)d_in[23];
    const float* gp1w = (const float*)d_in[24]; const float* gp1b = (const float*)d_in[25];
    const float* gp2w = (const float*)d_in[26]; const float* gp2b = (const float*)d_in[27];
    const float* gpg  = (const float*)d_in[28]; const float* gpbb = (const float*)d_in[29];
    const float* p1w  = (const float*)d_in[30]; const float* p1b  = (const float*)d_in[31];
    const float* p2w  = (const float*)d_in[32]; const float* p2b  = (const float*)d_in[33];
    const float* p3w  = (const float*)d_in[34]; const float* p3b  = (const float*)d_in[35];
    const float* p4w  = (const float*)d_in[36]; const float* p4b  = (const float*)d_in[37];

    float* dinv = (float*)d_ws;                // NN
    float* sums = dinv + NN;                   // NG*HD
    float* cnts = sums + NG*HD;                // NG
    int* degi   = (int*)(cnts + NG);           // NN
    int* cursor = degi + NN;                   // NN+2
    int* rowptr = cursor + NN + 2;             // NN+2
    int* sadj   = rowptr + NN + 2;             // NE
    u16* xw1p   = (u16*)(sadj + NE);           // NN*HD
    u16* xw2p   = xw1p + (size_t)NN*HD;        // NN*HD
    u16* hbf    = xw2p + (size_t)NN*HD;        // NN*HD
    u16* gf16   = hbf + (size_t)NN*HD;         // NG*HD
    u16* wpk    = gf16 + NG*HD;                // 270336
    u16* ee2p = wpk;
    u16* ee3p = wpk + 16384;
    u16* p1p  = wpk + 32768;
    u16* p2p  = wpk + 163840;
    u16* p3p  = wpk + 196608;
    u16* ne2p = wpk + 204800;
    u16* ne3p = wpk + 221184;
    u16* g1p  = wpk + 237568;
    u16* g2p  = wpk + 253952;

    float* out = (float*)d_out;

    hipMemsetAsync(degi, 0, (size_t)(2*NN + 2)*sizeof(int), stream);
    hipMemsetAsync(sums, 0, (size_t)(NG*HD + NG)*sizeof(float), stream);

    pack_all<<<(270336 + 255)/256, 256, 0, stream>>>(ee2w, ee3w, p1w, p2w, p3w,
                                                     ne2w, ne3w, g1w, g2w, wpk);

    // CSR build (+dinv fused into scan)
    deg_count_int<<<(NE + 255)/256, 256, 0, stream>>>(ei, degi);
    scan_excl<<<1, 1024, 0, stream>>>(degi, rowptr, dinv);
    fill_csr<<<(NE + 255)/256, 256, 0, stream>>>(ei, rowptr, cursor, sadj);

    // node encoder + g1 GEMM (bf16 out, prescaled by dinv)
    enc_mfma<<<(NN + 63)/64, 256, 0, stream>>>(x, ne1w, ne1b, ne2p, ne2b, ne3p, ne3b,
                                               neg, nebb, g1p, dinv, (u32*)xw1p);
    // GCN1 gather + relu + g2 GEMM
    gcn_agg1_mfma<<<(NN + 63)/64, 256, 0, stream>>>(xw1p, rowptr, sadj, dinv,
                                                    g1b, g2p, (u32*)xw2p);
    // GCN2 gather -> hbf bf16
    gcn_agg2_gather<<<(NN + 63)/64, 256, 0, stream>>>(xw2p, rowptr, sadj, dinv,
                                                      g2b, (u32*)hbf);

    // pool (+counts fused) + graph MLP
    pool_sorted<<<POOL_B, 128, 0, stream>>>(hbf, batch, sums, cnts);
    graph_feat<<<NG, 128, 0, stream>>>(sums, cnts, gp1w, gp1b, gp2w, gp2b,
                                       gpg, gpbb, gf16);

    // fused edge encoder + edge-score MLP (512-thread blocks)
    edge_mlp_mfma<<<NE/64, 512, 0, stream>>>(hbf, gf16, ei, batch, ea,
                                             ee1w, ee1b, ee2p, ee2b, ee3p, ee3b,
                                             eeg, eebb,
                                             p1p, p1b, p2p, p2b, p3p, p3b,
                                             p4w, p4b, out);
}

// Round 15
// 451.297 us; speedup vs baseline: 1.9286x; 1.0004x over previous
//
#include <hip/hip_runtime.h>
#include <math.h>

#define NN 50000
#define NE 400000
#define NG 64
#define HD 128
#define LN_EPS 1e-5f

typedef unsigned short u16;
typedef unsigned int u32;
typedef __attribute__((ext_vector_type(8))) short short8;
typedef __attribute__((ext_vector_type(4))) float f32x4;

#define MFMA16(a,b,c) __builtin_amdgcn_mfma_f32_16x16x32_bf16((a),(b),(c),0,0,0)

__device__ __forceinline__ u16 f2bf(float f) {
    union { float f; u32 u; } v; v.f = f;
    u32 r = v.u + 0x7FFFu + ((v.u >> 16) & 1u);
    return (u16)(r >> 16);
}
__device__ __forceinline__ float bf2f(u32 hs) {
    union { u32 u; float f; } v; v.u = hs << 16;
    return v.f;
}
__device__ __forceinline__ float fast_rcp(float x) {
    float r; asm("v_rcp_f32 %0, %1" : "=v"(r) : "v"(x)); return r;
}
__device__ __forceinline__ float fast_exp2(float x) {
    float r; asm("v_exp_f32 %0, %1" : "=v"(r) : "v"(x)); return r;
}
__device__ __forceinline__ u32 cvtpk(float lo, float hi) {
    u32 r; asm("v_cvt_pk_bf16_f32 %0, %1, %2" : "=v"(r) : "v"(lo), "v"(hi)); return r;
}
// tanh(x) = 1 - 2/(1+2^(2*log2e*x)); exp2 saturates correctly at +-inf
__device__ __forceinline__ float fast_tanh(float x) {
    return fmaf(-2.f, fast_rcp(1.f + fast_exp2(2.885390082f * x)), 1.f);
}
__device__ __forceinline__ float fast_sigmoid(float x) {
    return fast_rcp(1.f + fast_exp2(-1.442695041f * x));
}

// swizzle term for row within 16-row group
__device__ __forceinline__ int swzr(int row) {
    return (row & 7) ^ ((row & 8) >> 2);
}

// A-fragment load from swizzled [64][128] bf16 chunk buffer.
__device__ __forceinline__ short8 loadA(const u16* buf, int mi, int kk, int l) {
    int row = mi*16 + (l & 15);
    int ci  = (kk*4 + (l >> 4)) ^ swzr(l & 15);
    return *(const short8*)(buf + row*128 + (ci << 3));
}
__device__ __forceinline__ short8 loadB(const u16* wp, int nt, int ks, int nk, int l) {
    return *(const short8*)(wp + (((nt*nk + ks)*64 + l) << 3));
}

// Store 4 accumulator values (rows R..R+3, col c) into swizzled bf16 chunk as
// packed u32 via lane-pair exchange + v_cvt_pk_bf16_f32.
__device__ __forceinline__ void storeQuad(u32* buf, int R, int c, int l,
                                          float v0, float v1, float v2, float v3)
{
    int cw = c >> 1;
    int par = l & 1;
    float send = par ? v0 : v1;
    float recv = __shfl_xor(send, 1);
    int row = R + par;
    u32 word = par ? cvtpk(recv, v1) : cvtpk(v0, recv);
    buf[row*64 + (((cw >> 2) ^ swzr(row & 15)) << 2) + (cw & 3)] = word;
    send = par ? v2 : v3;
    recv = __shfl_xor(send, 1);
    row = R + 2 + par;
    word = par ? cvtpk(recv, v3) : cvtpk(v2, recv);
    buf[row*64 + (((cw >> 2) ^ swzr(row & 15)) << 2) + (cw & 3)] = word;
}

// Unswizzle copy: LDS chunk -> global bf16 [64][128] rows n0..n0+63 (u32 words)
__device__ __forceinline__ void copyChunkOut(const u32* chunk, u32* gout, int n0, int t)
{
    for (int it = 0; it < 16; ++it) {
        int dw = it*256 + t;
        int row = dw >> 6, cw = dw & 63;
        if (n0 + row < NN)
            gout[(size_t)(n0 + row)*64 + cw] =
                chunk[row*64 + (((cw >> 2) ^ swzr(row & 15)) << 2) + (cw & 3)];
    }
}

// ---------------------------------------------------------------------------
// One-shot weight packing of all 9 GEMM weights -> bf16 MFMA B-fragment order.
// ---------------------------------------------------------------------------
__global__ __launch_bounds__(256)
void pack_all(const float* __restrict__ ee2w, const float* __restrict__ ee3w,
              const float* __restrict__ p1w,  const float* __restrict__ p2w,
              const float* __restrict__ p3w,  const float* __restrict__ ne2w,
              const float* __restrict__ ne3w, const float* __restrict__ g1w,
              const float* __restrict__ g2w,  u16* __restrict__ wpk)
{
    int idx = blockIdx.x*256 + threadIdx.x;
    if (idx >= 270336) return;
    const float* w; int K, N, local;
    if      (idx < 16384)  { w = ee2w; K = 128; N = 128; local = idx; }
    else if (idx < 32768)  { w = ee3w; K = 128; N = 128; local = idx - 16384; }
    else if (idx < 163840) { w = p1w;  K = 512; N = 256; local = idx - 32768; }
    else if (idx < 196608) { w = p2w;  K = 256; N = 128; local = idx - 163840; }
    else if (idx < 204800) { w = p3w;  K = 128; N = 64;  local = idx - 196608; }
    else if (idx < 221184) { w = ne2w; K = 128; N = 128; local = idx - 204800; }
    else if (idx < 237568) { w = ne3w; K = 128; N = 128; local = idx - 221184; }
    else if (idx < 253952) { w = g1w;  K = 128; N = 128; local = idx - 237568; }
    else                   { w = g2w;  K = 128; N = 128; local = idx - 253952; }
    int e = local & 7, l = (local >> 3) & 63, r = local >> 9;
    int nk = K >> 5;
    int nt = r / nk, kk = r % nk;
    int k = kk*32 + ((l >> 4) << 3) + e;
    int n = nt*16 + (l & 15);
    wpk[idx] = f2bf(w[k*N + n]);
}

// ---------------------------------------------------------------------------
// CSR build
// ---------------------------------------------------------------------------
__global__ __launch_bounds__(256)
void deg_count_int(const int* __restrict__ ei, int* __restrict__ degi)
{
    int e = blockIdx.x*256 + threadIdx.x;
    if (e < NE) atomicAdd(&degi[ei[NE + e]], 1);
}

__global__ __launch_bounds__(1024)
void scan_excl(const int* __restrict__ cnt, int* __restrict__ rp,
               float* __restrict__ dinv)
{
    __shared__ int wsum[16];
    __shared__ int carry;
    int t = threadIdx.x, lane = t & 63, w = t >> 6;
    int base = 0;
    for (int off = 0; off < NN; off += 4096) {
        int i0 = off + t*4;
        int v0 = (i0   < NN) ? cnt[i0]   : 0;
        int v1 = (i0+1 < NN) ? cnt[i0+1] : 0;
        int v2 = (i0+2 < NN) ? cnt[i0+2] : 0;
        int v3 = (i0+3 < NN) ? cnt[i0+3] : 0;
        int tot = v0 + v1 + v2 + v3;
        int s = tot;
#pragma unroll
        for (int d = 1; d < 64; d <<= 1) { int u = __shfl_up(s, d); if (lane >= d) s += u; }
        if (lane == 63) wsum[w] = s;
        __syncthreads();
        if (w == 0) {
            int wv = (lane < 16) ? wsum[lane] : 0;
            int ss = wv;
#pragma unroll
            for (int d = 1; d < 16; d <<= 1) { int u = __shfl_up(ss, d); if (lane >= d) ss += u; }
            if (lane < 16) wsum[lane] = ss - wv;
            if (lane == 15) carry = ss;
        }
        __syncthreads();
        int excl = base + wsum[w] + s - tot;
        if (i0   < NN) { rp[i0]   = excl;              dinv[i0]   = rsqrtf((float)v0 + 1.f); }
        if (i0+1 < NN) { rp[i0+1] = excl + v0;         dinv[i0+1] = rsqrtf((float)v1 + 1.f); }
        if (i0+2 < NN) { rp[i0+2] = excl + v0 + v1;    dinv[i0+2] = rsqrtf((float)v2 + 1.f); }
        if (i0+3 < NN) { rp[i0+3] = excl + v0 + v1 + v2; dinv[i0+3] = rsqrtf((float)v3 + 1.f); }
        base += carry;
        __syncthreads();
    }
    if (t == 0) rp[NN] = base;
}

__global__ __launch_bounds__(256)
void fill_csr(const int* __restrict__ ei, const int* __restrict__ rp,
              int* __restrict__ cursor, int* __restrict__ sadj)
{
    int e = blockIdx.x*256 + threadIdx.x;
    if (e >= NE) return;
    int d = ei[NE + e];
    int slot = atomicAdd(&cursor[d], 1);
    sadj[rp[d] + slot] = ei[e];
}

// ---------------------------------------------------------------------------
// Node encoder + g1w GEMM, MFMA. 64 nodes/block, 256 threads.
// ---------------------------------------------------------------------------
__global__ __launch_bounds__(256, 4)
void enc_mfma(const float* __restrict__ x,
              const float* __restrict__ w1, const float* __restrict__ b1,
              const u16* __restrict__ w2p, const float* __restrict__ b2,
              const u16* __restrict__ w3p, const float* __restrict__ b3,
              const float* __restrict__ gg, const float* __restrict__ bb,
              const u16* __restrict__ g1p, const float* __restrict__ dinv,
              u32* __restrict__ xw1p)
{
    __shared__ u16 chunkA[64*HD];
    __shared__ u16 chunkB[64*HD];
    __shared__ float sX[192];
    __shared__ float sDi[64];
    __shared__ float rstat[128];

    const int t = threadIdx.x;
    const int l = t & 63;
    const int wid = t >> 6;
    const int n0 = blockIdx.x * 64;

    if (t < 192) sX[t] = (n0*3 + t < NN*3) ? x[n0*3 + t] : 0.f;
    if (t < 64)  sDi[t] = (n0 + t < NN) ? dinv[n0 + t] : 0.f;
    __syncthreads();

    // L1: 3->128 relu (VALU) -> chunkA
    for (int it = 0; it < 16; ++it) {
        int dw = it*256 + t;
        int e = dw >> 6, cd = dw & 63;
        int c0 = cd*2;
        float x0 = sX[e*3], x1 = sX[e*3+1], x2 = sX[e*3+2];
        float v0 = b1[c0]   + x0*w1[c0]   + x1*w1[HD+c0]   + x2*w1[2*HD+c0];
        float v1 = b1[c0+1] + x0*w1[c0+1] + x1*w1[HD+c0+1] + x2*w1[2*HD+c0+1];
        v0 = fmaxf(v0, 0.f); v1 = fmaxf(v1, 0.f);
        int ci = cd >> 2;
        ((u32*)chunkA)[e*64 + ((ci ^ swzr(e & 15)) << 2) + (cd & 3)] = cvtpk(v0, v1);
    }
    __syncthreads();

    // L2 MFMA: relu(A@w2+b2) -> chunkB
    {
        f32x4 acc[4][2];
#pragma unroll
        for (int ni = 0; ni < 2; ++ni) {
            float b = b2[(2*wid + ni)*16 + (l & 15)];
#pragma unroll
            for (int mi = 0; mi < 4; ++mi) acc[mi][ni] = (f32x4){b,b,b,b};
        }
#pragma unroll
        for (int kk = 0; kk < 4; ++kk) {
            short8 af[4];
#pragma unroll
            for (int mi = 0; mi < 4; ++mi) af[mi] = loadA(chunkA, mi, kk, l);
#pragma unroll
            for (int ni = 0; ni < 2; ++ni) {
                short8 bw = loadB(w2p, 2*wid + ni, kk, 4, l);
#pragma unroll
                for (int mi = 0; mi < 4; ++mi) acc[mi][ni] = MFMA16(af[mi], bw, acc[mi][ni]);
            }
        }
#pragma unroll
        for (int ni = 0; ni < 2; ++ni) {
            int col = (2*wid + ni)*16 + (l & 15);
#pragma unroll
            for (int mi = 0; mi < 4; ++mi) {
                int R = mi*16 + ((l >> 4) << 2);
                storeQuad((u32*)chunkB, R, col, l,
                          fmaxf(acc[mi][ni][0], 0.f), fmaxf(acc[mi][ni][1], 0.f),
                          fmaxf(acc[mi][ni][2], 0.f), fmaxf(acc[mi][ni][3], 0.f));
            }
        }
    }
    __syncthreads();

    // L3 MFMA: B@w3+b3 (pre-LN) -> chunkA
    {
        f32x4 acc[4][2];
#pragma unroll
        for (int ni = 0; ni < 2; ++ni) {
            float b = b3[(2*wid + ni)*16 + (l & 15)];
#pragma unroll
            for (int mi = 0; mi < 4; ++mi) acc[mi][ni] = (f32x4){b,b,b,b};
        }
#pragma unroll
        for (int kk = 0; kk < 4; ++kk) {
            short8 af[4];
#pragma unroll
            for (int mi = 0; mi < 4; ++mi) af[mi] = loadA(chunkB, mi, kk, l);
#pragma unroll
            for (int ni = 0; ni < 2; ++ni) {
                short8 bw = loadB(w3p, 2*wid + ni, kk, 4, l);
#pragma unroll
                for (int mi = 0; mi < 4; ++mi) acc[mi][ni] = MFMA16(af[mi], bw, acc[mi][ni]);
            }
        }
#pragma unroll
        for (int ni = 0; ni < 2; ++ni) {
            int col = (2*wid + ni)*16 + (l & 15);
#pragma unroll
            for (int mi = 0; mi < 4; ++mi) {
                int R = mi*16 + ((l >> 4) << 2);
                storeQuad((u32*)chunkA, R, col, l,
                          acc[mi][ni][0], acc[mi][ni][1], acc[mi][ni][2], acc[mi][ni][3]);
            }
        }
    }
    __syncthreads();

    // LN stats: 4 lanes per row, rotated read
    {
        int e = wid*16 + (l >> 2);
        int q = l & 3;
        const u32* rowp = (const u32*)chunkA + e*64;
        float s = 0.f, sq = 0.f;
#pragma unroll
        for (int i = 0; i < 16; ++i) {
            u32 pk = rowp[q*16 + ((i + e) & 15)];
            float a = bf2f(pk & 0xffffu), b = bf2f(pk >> 16);
            s += a + b;
            sq = fmaf(a, a, fmaf(b, b, sq));
        }
        s  += __shfl_xor(s, 1);  sq += __shfl_xor(sq, 1);
        s  += __shfl_xor(s, 2);  sq += __shfl_xor(sq, 2);
        if (q == 0) {
            float mu = s * (1.f/HD);
            rstat[e] = mu;
            rstat[64 + e] = rsqrtf(sq*(1.f/HD) - mu*mu + LN_EPS);
        }
    }
    __syncthreads();

    // normalize in place
    for (int it = 0; it < 16; ++it) {
        int pd = it*256 + t;
        int row = pd >> 6, cwd = pd & 63;
        int ci = (cwd >> 2) ^ swzr(row & 15);
        int col = ci*8 + (cwd & 3)*2;
        u32 pk = ((u32*)chunkA)[pd];
        float mu = rstat[row], ri = rstat[64 + row];
        float v0 = (bf2f(pk & 0xffffu) - mu)*ri*gg[col]     + bb[col];
        float v1 = (bf2f(pk >> 16)     - mu)*ri*gg[col + 1] + bb[col + 1];
        ((u32*)chunkA)[pd] = cvtpk(v0, v1);
    }
    __syncthreads();

    // GEMM @g1w, scale by dinv -> chunkB -> global
    {
        f32x4 acc[4][2];
#pragma unroll
        for (int mi = 0; mi < 4; ++mi)
#pragma unroll
            for (int ni = 0; ni < 2; ++ni) acc[mi][ni] = (f32x4){0.f,0.f,0.f,0.f};
#pragma unroll
        for (int kk = 0; kk < 4; ++kk) {
            short8 af[4];
#pragma unroll
            for (int mi = 0; mi < 4; ++mi) af[mi] = loadA(chunkA, mi, kk, l);
#pragma unroll
            for (int ni = 0; ni < 2; ++ni) {
                short8 bw = loadB(g1p, 2*wid + ni, kk, 4, l);
#pragma unroll
                for (int mi = 0; mi < 4; ++mi) acc[mi][ni] = MFMA16(af[mi], bw, acc[mi][ni]);
            }
        }
#pragma unroll
        for (int ni = 0; ni < 2; ++ni) {
            int col = (2*wid + ni)*16 + (l & 15);
#pragma unroll
            for (int mi = 0; mi < 4; ++mi) {
                int R = mi*16 + ((l >> 4) << 2);
                storeQuad((u32*)chunkB, R, col, l,
                          acc[mi][ni][0]*sDi[R], acc[mi][ni][1]*sDi[R+1],
                          acc[mi][ni][2]*sDi[R+2], acc[mi][ni][3]*sDi[R+3]);
            }
        }
    }
    __syncthreads();
    copyChunkOut((const u32*)chunkB, xw1p, n0, t);
}

// ---------------------------------------------------------------------------
// GCN layer 1: gather bf16 xw1p (prescaled, 2-deep neighbor prefetch),
// relu(+g1b), MFMA @g2w, *dinv -> xw2p
// ---------------------------------------------------------------------------
__global__ __launch_bounds__(256, 4)
void gcn_agg1_mfma(const u16* __restrict__ xw1p, const int* __restrict__ rp,
                   const int* __restrict__ sadj, const float* __restrict__ dinv,
                   const float* __restrict__ g1b, const u16* __restrict__ g2p,
                   u32* __restrict__ xw2p)
{
    __shared__ u16 chunkA[64*HD];
    __shared__ u16 chunkB[64*HD];
    __shared__ float sDi[64];
    __shared__ float sB[HD];

    const int t = threadIdx.x;
    const int l = t & 63;
    const int wid = t >> 6;
    const int n0 = blockIdx.x * 64;

    if (t < 64)  sDi[t] = (n0 + t < NN) ? dinv[n0 + t] : 0.f;
    if (t < HD)  sB[t] = g1b[t];
    __syncthreads();

    {
        int s = t >> 2, part = t & 3, n = n0 + s;
        float acc[32];
#pragma unroll
        for (int j = 0; j < 32; ++j) acc[j] = 0.f;
        float di = 0.f;
        if (n < NN) {
            di = sDi[s];
            const short8* selfp = (const short8*)(xw1p + (size_t)n*HD + part*32);
#pragma unroll
            for (int w = 0; w < 4; ++w) {
                short8 v = selfp[w];
#pragma unroll
                for (int j = 0; j < 8; ++j) acc[w*8+j] += bf2f((u16)v[j]);
            }
            int k = rp[n], k1 = rp[n+1];
            if (k < k1) {
                const short8* cp = (const short8*)(xw1p + (size_t)sadj[k]*HD + part*32);
                short8 c0 = cp[0], c1 = cp[1], c2 = cp[2], c3 = cp[3];
                for (++k; k < k1; ++k) {
                    const short8* np = (const short8*)(xw1p + (size_t)sadj[k]*HD + part*32);
                    short8 m0 = np[0], m1 = np[1], m2 = np[2], m3 = np[3];
#pragma unroll
                    for (int j = 0; j < 8; ++j) {
                        acc[j]      += bf2f((u16)c0[j]);
                        acc[8 + j]  += bf2f((u16)c1[j]);
                        acc[16 + j] += bf2f((u16)c2[j]);
                        acc[24 + j] += bf2f((u16)c3[j]);
                    }
                    c0 = m0; c1 = m1; c2 = m2; c3 = m3;
                }
#pragma unroll
                for (int j = 0; j < 8; ++j) {
                    acc[j]      += bf2f((u16)c0[j]);
                    acc[8 + j]  += bf2f((u16)c1[j]);
                    acc[16 + j] += bf2f((u16)c2[j]);
                    acc[24 + j] += bf2f((u16)c3[j]);
                }
            }
        }
#pragma unroll
        for (int p = 0; p < 16; ++p) {
            float v0 = fmaxf(fmaf(acc[2*p],   di, sB[part*32 + 2*p]),   0.f);
            float v1 = fmaxf(fmaf(acc[2*p+1], di, sB[part*32 + 2*p+1]), 0.f);
            int cw = part*16 + p;
            ((u32*)chunkA)[s*64 + (((cw >> 2) ^ swzr(s & 15)) << 2) + (cw & 3)] = cvtpk(v0, v1);
        }
    }
    __syncthreads();

    {
        f32x4 acc[4][2];
#pragma unroll
        for (int mi = 0; mi < 4; ++mi)
#pragma unroll
            for (int ni = 0; ni < 2; ++ni) acc[mi][ni] = (f32x4){0.f,0.f,0.f,0.f};
#pragma unroll
        for (int kk = 0; kk < 4; ++kk) {
            short8 af[4];
#pragma unroll
            for (int mi = 0; mi < 4; ++mi) af[mi] = loadA(chunkA, mi, kk, l);
#pragma unroll
            for (int ni = 0; ni < 2; ++ni) {
                short8 bw = loadB(g2p, 2*wid + ni, kk, 4, l);
#pragma unroll
                for (int mi = 0; mi < 4; ++mi) acc[mi][ni] = MFMA16(af[mi], bw, acc[mi][ni]);
            }
        }
#pragma unroll
        for (int ni = 0; ni < 2; ++ni) {
            int col = (2*wid + ni)*16 + (l & 15);
#pragma unroll
            for (int mi = 0; mi < 4; ++mi) {
                int R = mi*16 + ((l >> 4) << 2);
                storeQuad((u32*)chunkB, R, col, l,
                          acc[mi][ni][0]*sDi[R], acc[mi][ni][1]*sDi[R+1],
                          acc[mi][ni][2]*sDi[R+2], acc[mi][ni][3]*sDi[R+3]);
            }
        }
    }
    __syncthreads();
    copyChunkOut((const u32*)chunkB, xw2p, n0, t);
}

// ---------------------------------------------------------------------------
// GCN layer 2: gather bf16 xw2p (2-deep neighbor prefetch), +g2b -> hbf
// ---------------------------------------------------------------------------
__global__ __launch_bounds__(256)
void gcn_agg2_gather(const u16* __restrict__ xw2p, const int* __restrict__ rp,
                     const int* __restrict__ sadj, const float* __restrict__ dinv,
                     const float* __restrict__ g2b, u32* __restrict__ hbw)
{
    int t = threadIdx.x;
    int s = t >> 2, part = t & 3;
    int n = blockIdx.x * 64 + s;
    if (n >= NN) return;
    float acc[32];
#pragma unroll
    for (int j = 0; j < 32; ++j) acc[j] = 0.f;
    const short8* selfp = (const short8*)(xw2p + (size_t)n*HD + part*32);
#pragma unroll
    for (int w = 0; w < 4; ++w) {
        short8 v = selfp[w];
#pragma unroll
        for (int j = 0; j < 8; ++j) acc[w*8+j] += bf2f((u16)v[j]);
    }
    int k = rp[n], k1 = rp[n+1];
    if (k < k1) {
        const short8* cp = (const short8*)(xw2p + (size_t)sadj[k]*HD + part*32);
        short8 c0 = cp[0], c1 = cp[1], c2 = cp[2], c3 = cp[3];
        for (++k; k < k1; ++k) {
            const short8* np = (const short8*)(xw2p + (size_t)sadj[k]*HD + part*32);
            short8 m0 = np[0], m1 = np[1], m2 = np[2], m3 = np[3];
#pragma unroll
            for (int j = 0; j < 8; ++j) {
                acc[j]      += bf2f((u16)c0[j]);
                acc[8 + j]  += bf2f((u16)c1[j]);
                acc[16 + j] += bf2f((u16)c2[j]);
                acc[24 + j] += bf2f((u16)c3[j]);
            }
            c0 = m0; c1 = m1; c2 = m2; c3 = m3;
        }
#pragma unroll
        for (int j = 0; j < 8; ++j) {
            acc[j]      += bf2f((u16)c0[j]);
            acc[8 + j]  += bf2f((u16)c1[j]);
            acc[16 + j] += bf2f((u16)c2[j]);
            acc[24 + j] += bf2f((u16)c3[j]);
        }
    }
    float di = dinv[n];
    u32* hb = hbw + (size_t)n*64 + part*16;
#pragma unroll
    for (int p = 0; p < 16; ++p) {
        float v0 = fmaf(acc[2*p],   di, g2b[part*32 + 2*p]);
        float v1 = fmaf(acc[2*p+1], di, g2b[part*32 + 2*p+1]);
        hb[p] = cvtpk(v0, v1);
    }
}

// ---------------------------------------------------------------------------
// Pool (batch sorted, bf16 input) + fused counts + graph MLP
// ---------------------------------------------------------------------------
#define POOL_B 512
__global__ __launch_bounds__(128)
void pool_sorted(const u16* __restrict__ h, const int* __restrict__ batch,
                 float* __restrict__ sums, float* __restrict__ cnts)
{
    int b = blockIdx.x, j = threadIdx.x;
    int n0 = (int)(((long long)NN * b) / POOL_B);
    int n1 = (int)(((long long)NN * (b+1)) / POOL_B);
    int g = -1; float acc = 0.f, cl = 0.f;
    for (int n = n0; n < n1; ++n) {
        int bg = batch[n];
        if (bg != g) {
            if (g >= 0) {
                atomicAdd(&sums[g*HD + j], acc);
                if (j == 0) atomicAdd(&cnts[g], cl);
            }
            g = bg; acc = 0.f; cl = 0.f;
        }
        acc += bf2f(h[(size_t)n*HD + j]);
        cl += 1.f;
    }
    if (g >= 0) {
        atomicAdd(&sums[g*HD + j], acc);
        if (j == 0) atomicAdd(&cnts[g], cl);
    }
}

__global__ __launch_bounds__(128)
void graph_feat(const float* __restrict__ sums, const float* __restrict__ cnts,
                const float* __restrict__ w1, const float* __restrict__ b1,
                const float* __restrict__ w2, const float* __restrict__ b2,
                const float* __restrict__ gg, const float* __restrict__ bb,
                u16* __restrict__ gf16)
{
    int gi = blockIdx.x, j = threadIdx.x;
    __shared__ float s0[HD];
    __shared__ float s1[HD];
    __shared__ float part[4];
    __shared__ float stat[2];
    float cnt = fmaxf(cnts[gi], 1.f);
    s0[j] = sums[gi*HD + j] / cnt;
    __syncthreads();
    float a = b1[j];
    for (int i = 0; i < HD; ++i) a = fmaf(s0[i], w1[i*HD + j], a);
    s1[j] = fmaxf(a, 0.f);
    __syncthreads();
    a = b2[j];
    for (int i = 0; i < HD; ++i) a = fmaf(s1[i], w2[i*HD + j], a);
    float s = a, q = a*a;
    for (int o = 32; o > 0; o >>= 1) { s += __shfl_down(s, o); q += __shfl_down(q, o); }
    int wid = j >> 6, lane = j & 63;
    if (lane == 0) { part[wid] = s; part[2 + wid] = q; }
    __syncthreads();
    if (j == 0) {
        float S = part[0] + part[1], Q = part[2] + part[3];
        float mu = S * (1.f/HD);
        stat[0] = mu;
        stat[1] = Q * (1.f/HD) - mu*mu;
    }
    __syncthreads();
    float v = (a - stat[0]) * rsqrtf(stat[1] + LN_EPS) * gg[j] + bb[j];
    gf16[gi*HD + j] = f2bf(v);
}

// ---------------------------------------------------------------------------
// Stage 64 gathered bf16 rows into swizzled LDS chunk (first 256 threads)
// ---------------------------------------------------------------------------
__device__ __forceinline__ void stageRows(u16* dst, const u16* __restrict__ srcBase,
                                          const int* ridx, int t)
{
    int e = t >> 2, part = t & 3;
    const u16* src = srcBase + (size_t)ridx[e]*HD + part*32;
    u16* drow = dst + e*128;
    int re = swzr(e & 15);
#pragma unroll
    for (int w = 0; w < 4; ++w) {
        int ci = (part*4 + w) ^ re;
        *(short8*)(drow + (ci << 3)) = *(const short8*)(src + w*8);
    }
}

// ---------------------------------------------------------------------------
// Fused edge kernel (MFMA bf16). 64 edges/block, 512 threads (8 waves).
// Accumulator split across 8 waves: ep1 acc[4][2]=32 regs, enc/ep2 acc[4]=16.
// sEa aliased into bufWide (dead until enc2 epilogue) to shave LDS below 50KB
// and give the 3rd block/CU its best shot.
// ---------------------------------------------------------------------------
__global__ __launch_bounds__(512, 3)
void edge_mlp_mfma(const u16* __restrict__ hbf, const u16* __restrict__ gfbf,
                   const int* __restrict__ ei, const int* __restrict__ batch,
                   const float* __restrict__ ea,
                   const float* __restrict__ ew1, const float* __restrict__ eb1,
                   const u16* __restrict__ ew2p, const float* __restrict__ eb2,
                   const u16* __restrict__ ew3p, const float* __restrict__ eb3,
                   const float* __restrict__ egm, const float* __restrict__ ebb,
                   const u16* __restrict__ p1wp, const float* __restrict__ p1b,
                   const u16* __restrict__ p2wp, const float* __restrict__ p2b,
                   const u16* __restrict__ p3wp, const float* __restrict__ p3b,
                   const float* __restrict__ p4w, const float* __restrict__ p4b,
                   float* __restrict__ out)
{
    __shared__ u16 bufChunk[64*HD];    // 16KB swizzled A-chunk
    __shared__ u16 bufWide[64*256];    // 32KB (2 chunks / fp32 scratch)
    __shared__ int sGf[64];
    __shared__ float rstat[128];
    float* sEa = (float*)bufWide;      // alias: bufWide dead until enc2 epilogue

    const int t = threadIdx.x;
    const int l = t & 63;
    const int wid = t >> 6;            // 0..7
    const int e0 = blockIdx.x * 64;

    // ---- prefetch h[src]/h[dst] into registers (8 threads/row, 16 regs) ----
    const int eRow = t >> 3, part8 = t & 7;
    int srcN = ei[e0 + eRow];
    int dstN = ei[NE + e0 + eRow];
    if (part8 == 0) sGf[eRow] = batch[srcN];
    short8 rs[2], rd[2];
    {
        const short8* ps = (const short8*)(hbf + (size_t)srcN*HD + part8*16);
        const short8* pd = (const short8*)(hbf + (size_t)dstN*HD + part8*16);
#pragma unroll
        for (int w = 0; w < 2; ++w) { rs[w] = ps[w]; rd[w] = pd[w]; }
    }

    if (t < 192) sEa[t] = ea[e0*3 + t];
    __syncthreads();

    // ---- enc1: relu(ea@ew1+b1) -> bufChunk ----
    for (int it = 0; it < 8; ++it) {
        int dw = it*512 + t;
        int e = dw >> 6, cd = dw & 63;
        int c0 = cd*2;
        float x0 = sEa[e*3], x1 = sEa[e*3+1], x2 = sEa[e*3+2];
        float v0 = eb1[c0]   + x0*ew1[c0]   + x1*ew1[HD+c0]   + x2*ew1[2*HD+c0];
        float v1 = eb1[c0+1] + x0*ew1[c0+1] + x1*ew1[HD+c0+1] + x2*ew1[2*HD+c0+1];
        v0 = fmaxf(v0, 0.f); v1 = fmaxf(v1, 0.f);
        int ci = cd >> 2;
        ((u32*)bufChunk)[e*64 + ((ci ^ swzr(e & 15)) << 2) + (cd & 3)] = cvtpk(v0, v1);
    }
    __syncthreads();

    // ---- enc2: relu(A@ew2+b2) -> bufWide chunk0 (wave owns col tile wid) ----
    {
        f32x4 acc[4];
        {
            float b = eb2[wid*16 + (l & 15)];
#pragma unroll
            for (int mi = 0; mi < 4; ++mi) acc[mi] = (f32x4){b,b,b,b};
        }
#pragma unroll
        for (int kk = 0; kk < 4; ++kk) {
            short8 af[4];
#pragma unroll
            for (int mi = 0; mi < 4; ++mi) af[mi] = loadA(bufChunk, mi, kk, l);
            short8 bw = loadB(ew2p, wid, kk, 4, l);
#pragma unroll
            for (int mi = 0; mi < 4; ++mi) acc[mi] = MFMA16(af[mi], bw, acc[mi]);
        }
        __syncthreads();   // sEa reads fully done before bufWide writes
        int col = wid*16 + (l & 15);
#pragma unroll
        for (int mi = 0; mi < 4; ++mi) {
            int R = mi*16 + ((l >> 4) << 2);
            storeQuad((u32*)bufWide, R, col, l,
                      fmaxf(acc[mi][0], 0.f), fmaxf(acc[mi][1], 0.f),
                      fmaxf(acc[mi][2], 0.f), fmaxf(acc[mi][3], 0.f));
        }
    }
    __syncthreads();

    // ---- enc3: W0@ew3+b3 (pre-LN) -> bufChunk ----
    {
        f32x4 acc[4];
        {
            float b = eb3[wid*16 + (l & 15)];
#pragma unroll
            for (int mi = 0; mi < 4; ++mi) acc[mi] = (f32x4){b,b,b,b};
        }
#pragma unroll
        for (int kk = 0; kk < 4; ++kk) {
            short8 af[4];
#pragma unroll
            for (int mi = 0; mi < 4; ++mi) af[mi] = loadA(bufWide, mi, kk, l);
            short8 bw = loadB(ew3p, wid, kk, 4, l);
#pragma unroll
            for (int mi = 0; mi < 4; ++mi) acc[mi] = MFMA16(af[mi], bw, acc[mi]);
        }
        int col = wid*16 + (l & 15);
#pragma unroll
        for (int mi = 0; mi < 4; ++mi) {
            int R = mi*16 + ((l >> 4) << 2);
            storeQuad((u32*)bufChunk, R, col, l,
                      acc[mi][0], acc[mi][1], acc[mi][2], acc[mi][3]);
        }
    }
    __syncthreads();

    // ---- write prefetched h[src]/h[dst] to bufWide (enc2 data dead) ----
    {
        u16* drow0 = bufWide + eRow*128;
        u16* drow1 = bufWide + 8192 + eRow*128;
        int re = swzr(eRow & 15);
#pragma unroll
        for (int w = 0; w < 2; ++w) {
            int ci = (part8*2 + w) ^ re;
            *(short8*)(drow0 + (ci << 3)) = rs[w];
            *(short8*)(drow1 + (ci << 3)) = rd[w];
        }
    }

    // ---- LN stats: 8 lanes per edge (all 512 threads), rotated read ----
    {
        int e = wid*8 + (l >> 3);
        int q = l & 7;
        const u32* rowp = (const u32*)bufChunk + e*64;
        float s = 0.f, sq = 0.f;
#pragma unroll
        for (int i = 0; i < 8; ++i) {
            u32 pk = rowp[q*8 + ((i + e) & 7)];
            float a = bf2f(pk & 0xffffu), b = bf2f(pk >> 16);
            s += a + b;
            sq = fmaf(a, a, fmaf(b, b, sq));
        }
        s  += __shfl_xor(s, 1);  sq += __shfl_xor(sq, 1);
        s  += __shfl_xor(s, 2);  sq += __shfl_xor(sq, 2);
        s  += __shfl_xor(s, 4);  sq += __shfl_xor(sq, 4);
        if (q == 0) {
            float mu = s * (1.f/HD);
            rstat[e] = mu;
            rstat[64 + e] = rsqrtf(sq*(1.f/HD) - mu*mu + LN_EPS);
        }
    }
    __syncthreads();

    // ---- normalize in place: bufChunk = ef ----
    for (int it = 0; it < 8; ++it) {
        int pd = it*512 + t;
        int row = pd >> 6, cwd = pd & 63;
        int ci = (cwd >> 2) ^ swzr(row & 15);
        int col = ci*8 + (cwd & 3)*2;
        u32 pk = ((u32*)bufChunk)[pd];
        float mu = rstat[row], ri = rstat[64 + row];
        float v0 = (bf2f(pk & 0xffffu) - mu)*ri*egm[col]     + ebb[col];
        float v1 = (bf2f(pk >> 16)     - mu)*ri*egm[col + 1] + ebb[col + 1];
        ((u32*)bufChunk)[pd] = cvtpk(v0, v1);
    }
    __syncthreads();

    // ---- ep1 MFMA: wave owns 2 col tiles (ni 0..1 -> global wid*2+ni).
    //      K-slices: ef (ks 12..15), hsrc (ks 0..3), hdst (ks 4..7) ----
    f32x4 acc1[4][2];
#pragma unroll
    for (int ni = 0; ni < 2; ++ni) {
        float b = p1b[(wid*2 + ni)*16 + (l & 15)];
#pragma unroll
        for (int mi = 0; mi < 4; ++mi) acc1[mi][ni] = (f32x4){b,b,b,b};
    }
#pragma unroll
    for (int kk = 0; kk < 4; ++kk) {
        short8 af[4];
#pragma unroll
        for (int mi = 0; mi < 4; ++mi) af[mi] = loadA(bufChunk, mi, kk, l);
#pragma unroll
        for (int ni = 0; ni < 2; ++ni) {
            short8 bw = loadB(p1wp, wid*2 + ni, 12 + kk, 16, l);
#pragma unroll
            for (int mi = 0; mi < 4; ++mi) acc1[mi][ni] = MFMA16(af[mi], bw, acc1[mi][ni]);
        }
    }
#pragma unroll
    for (int kk = 0; kk < 4; ++kk) {
        short8 af[4];
#pragma unroll
        for (int mi = 0; mi < 4; ++mi) af[mi] = loadA(bufWide, mi, kk, l);
#pragma unroll
        for (int ni = 0; ni < 2; ++ni) {
            short8 bw = loadB(p1wp, wid*2 + ni, kk, 16, l);
#pragma unroll
            for (int mi = 0; mi < 4; ++mi) acc1[mi][ni] = MFMA16(af[mi], bw, acc1[mi][ni]);
        }
    }
#pragma unroll
    for (int kk = 0; kk < 4; ++kk) {
        short8 af[4];
#pragma unroll
        for (int mi = 0; mi < 4; ++mi) af[mi] = loadA(bufWide + 8192, mi, kk, l);
#pragma unroll
        for (int ni = 0; ni < 2; ++ni) {
            short8 bw = loadB(p1wp, wid*2 + ni, 4 + kk, 16, l);
#pragma unroll
            for (int mi = 0; mi < 4; ++mi) acc1[mi][ni] = MFMA16(af[mi], bw, acc1[mi][ni]);
        }
    }
    __syncthreads();

    // ---- stage gf -> bufChunk (ef dead), MFMA (ks 8..11), tanh -> bufWide ----
    if (t < 256) stageRows(bufChunk, gfbf, sGf, t);
    __syncthreads();
#pragma unroll
    for (int kk = 0; kk < 4; ++kk) {
        short8 af[4];
#pragma unroll
        for (int mi = 0; mi < 4; ++mi) af[mi] = loadA(bufChunk, mi, kk, l);
#pragma unroll
        for (int ni = 0; ni < 2; ++ni) {
            short8 bw = loadB(p1wp, wid*2 + ni, 8 + kk, 16, l);
#pragma unroll
            for (int mi = 0; mi < 4; ++mi) acc1[mi][ni] = MFMA16(af[mi], bw, acc1[mi][ni]);
        }
    }
    __syncthreads();
#pragma unroll
    for (int ni = 0; ni < 2; ++ni) {
        int col = (wid*2 + ni)*16 + (l & 15);
        u32* dst = (u32*)bufWide + ((col >> 7) << 12);
        int cc = col & 127;
#pragma unroll
        for (int mi = 0; mi < 4; ++mi) {
            int R = mi*16 + ((l >> 4) << 2);
            storeQuad(dst, R, cc, l,
                      fast_tanh(acc1[mi][ni][0]), fast_tanh(acc1[mi][ni][1]),
                      fast_tanh(acc1[mi][ni][2]), fast_tanh(acc1[mi][ni][3]));
        }
    }
    __syncthreads();

    // ---- ep2: [64,256]@p2w[256,128], tanh -> bufChunk (wave owns tile wid) ----
    {
        f32x4 acc[4];
        {
            float b = p2b[wid*16 + (l & 15)];
#pragma unroll
            for (int mi = 0; mi < 4; ++mi) acc[mi] = (f32x4){b,b,b,b};
        }
        for (int kc = 0; kc < 2; ++kc) {
            const u16* abuf = bufWide + (kc << 13);
#pragma unroll
            for (int kk = 0; kk < 4; ++kk) {
                short8 af[4];
#pragma unroll
                for (int mi = 0; mi < 4; ++mi) af[mi] = loadA(abuf, mi, kk, l);
                short8 bw = loadB(p2wp, wid, kc*4 + kk, 8, l);
#pragma unroll
                for (int mi = 0; mi < 4; ++mi) acc[mi] = MFMA16(af[mi], bw, acc[mi]);
            }
        }
        int col = wid*16 + (l & 15);
#pragma unroll
        for (int mi = 0; mi < 4; ++mi) {
            int R = mi*16 + ((l >> 4) << 2);
            storeQuad((u32*)bufChunk, R, col, l,
                      fast_tanh(acc[mi][0]), fast_tanh(acc[mi][1]),
                      fast_tanh(acc[mi][2]), fast_tanh(acc[mi][3]));
        }
    }
    __syncthreads();

    // ---- ep3: [64,128]@p3w[128,64], relu -> bufWide fp32 stride-65.
    //      All waves compute tile (wid&3); only wid<4 store. ----
    {
        int wt = wid & 3;
        f32x4 acc[4];
        {
            float b = p3b[wt*16 + (l & 15)];
#pragma unroll
            for (int mi = 0; mi < 4; ++mi) acc[mi] = (f32x4){b,b,b,b};
        }
#pragma unroll
        for (int kk = 0; kk < 4; ++kk) {
            short8 af[4];
#pragma unroll
            for (int mi = 0; mi < 4; ++mi) af[mi] = loadA(bufChunk, mi, kk, l);
            short8 bw = loadB(p3wp, wt, kk, 4, l);
#pragma unroll
            for (int mi = 0; mi < 4; ++mi) acc[mi] = MFMA16(af[mi], bw, acc[mi]);
        }
        if (wid < 4) {
            float* fb = (float*)bufWide;
            int col = wt*16 + (l & 15);
#pragma unroll
            for (int mi = 0; mi < 4; ++mi)
#pragma unroll
                for (int rr = 0; rr < 4; ++rr) {
                    int row = mi*16 + ((l >> 4) << 2) + rr;
                    fb[row*65 + col] = fmaxf(acc[mi][rr], 0.f);
                }
        }
    }
    __syncthreads();

    // ---- ep4: 4 lanes/edge dot-64 + sigmoid (waves 0..3 cover 64 edges) ----
    {
        const float* fb = (const float*)bufWide;
        int e = (wid & 3)*16 + (l >> 2), q = l & 3;
        float v = 0.f;
#pragma unroll
        for (int k = 0; k < 16; ++k) {
            int i = q*16 + k;
            v = fmaf(fb[e*65 + i], p4w[i], v);
        }
        v += __shfl_xor(v, 1);
        v += __shfl_xor(v, 2);
        if (q == 0 && wid < 4) out[e0 + e] = fast_sigmoid(v + p4b[0]);
    }
}

// ---------------------------------------------------------------------------
extern "C" void kernel_launch(void* const* d_in, const int* in_sizes, int n_in,
                              void* d_out, int out_size, void* d_ws, size_t ws_size,
                              hipStream_t stream)
{
    const float* x     = (const float*)d_in[0];
    const int*   ei    = (const int*)  d_in[1];
    const float* ea    = (const float*)d_in[2];
    const int*   batch = (const int*)  d_in[3];
    const float* ne1w = (const float*)d_in[4];  const float* ne1b = (const float*)d_in[5];
    const float* ne2w = (const float*)d_in[6];  const float* ne2b = (const float*)d_in[7];
    const float* ne3w = (const float*)d_in[8];  const float* ne3b = (const float*)d_in[9];
    const float* neg  = (const float*)d_in[10]; const float* nebb = (const float*)d_in[11];
    const float* ee1w = (const float*)d_in[12]; const float* ee1b = (const float*)d_in[13];
    const float* ee2w = (const float*)d_in[14]; const float* ee2b = (const float*)d_in[15];
    const float* ee3w = (const float*)d_in[16]; const float* ee3b = (const float*)d_in[17];
    const float* eeg  = (const float*)d_in[18]; const float* eebb = (const float*)d_in[19];
    const float* g1w  = (const float*)d_in[20]; const float* g1b  = (const float*)d_in[21];
    const float* g2w  = (const float*)d_in[22]; const float* g2b  = (const float*)d_in[23];
    const float* gp1w = (const float*)d_in[24]; const float* gp1b = (const float*)d_in[25];
    const float* gp2w = (const float*)d_in[26]; const float* gp2b = (const float*)d_in[27];
    const float* gpg  = (const float*)d_in[28]; const float* gpbb = (const float*)d_in[29];
    const float* p1w  = (const float*)d_in[30]; const float* p1b  = (const float*)d_in[31];
    const float* p2w  = (const float*)d_in[32]; const float* p2b  = (const float*)d_in[33];
    const float* p3w  = (const float*)d_in[34]; const float* p3b  = (const float*)d_in[35];
    const float* p4w  = (const float*)d_in[36]; const float* p4b  = (const float*)d_in[37];

    float* dinv = (float*)d_ws;                // NN
    float* sums = dinv + NN;                   // NG*HD
    float* cnts = sums + NG*HD;                // NG
    int* degi   = (int*)(cnts + NG);           // NN
    int* cursor = degi + NN;                   // NN+2
    int* rowptr = cursor + NN + 2;             // NN+2
    int* sadj   = rowptr + NN + 2;             // NE
    u16* xw1p   = (u16*)(sadj + NE);           // NN*HD
    u16* xw2p   = xw1p + (size_t)NN*HD;        // NN*HD
    u16* hbf    = xw2p + (size_t)NN*HD;        // NN*HD
    u16* gf16   = hbf + (size_t)NN*HD;         // NG*HD
    u16* wpk    = gf16 + NG*HD;                // 270336
    u16* ee2p = wpk;
    u16* ee3p = wpk + 16384;
    u16* p1p  = wpk + 32768;
    u16* p2p  = wpk + 163840;
    u16* p3p  = wpk + 196608;
    u16* ne2p = wpk + 204800;
    u16* ne3p = wpk + 221184;
    u16* g1p  = wpk + 237568;
    u16* g2p  = wpk + 253952;

    float* out = (float*)d_out;

    hipMemsetAsync(degi, 0, (size_t)(2*NN + 2)*sizeof(int), stream);
    hipMemsetAsync(sums, 0, (size_t)(NG*HD + NG)*sizeof(float), stream);

    pack_all<<<(270336 + 255)/256, 256, 0, stream>>>(ee2w, ee3w, p1w, p2w, p3w,
                                                     ne2w, ne3w, g1w, g2w, wpk);

    // CSR build (+dinv fused into scan)
    deg_count_int<<<(NE + 255)/256, 256, 0, stream>>>(ei, degi);
    scan_excl<<<1, 1024, 0, stream>>>(degi, rowptr, dinv);
    fill_csr<<<(NE + 255)/256, 256, 0, stream>>>(ei, rowptr, cursor, sadj);

    // node encoder + g1 GEMM (bf16 out, prescaled by dinv)
    enc_mfma<<<(NN + 63)/64, 256, 0, stream>>>(x, ne1w, ne1b, ne2p, ne2b, ne3p, ne3b,
                                               neg, nebb, g1p, dinv, (u32*)xw1p);
    // GCN1 gather + relu + g2 GEMM
    gcn_agg1_mfma<<<(NN + 63)/64, 256, 0, stream>>>(xw1p, rowptr, sadj, dinv,
                                                    g1b, g2p, (u32*)xw2p);
    // GCN2 gather -> hbf bf16
    gcn_agg2_gather<<<(NN + 63)/64, 256, 0, stream>>>(xw2p, rowptr, sadj, dinv,
                                                      g2b, (u32*)hbf);

    // pool (+counts fused) + graph MLP
    pool_sorted<<<POOL_B, 128, 0, stream>>>(hbf, batch, sums, cnts);
    graph_feat<<<NG, 128, 0, stream>>>(sums, cnts, gp1w, gp1b, gp2w, gp2b,
                                       gpg, gpbb, gf16);

    // fused edge encoder + edge-score MLP (512-thread blocks)
    edge_mlp_mfma<<<NE/64, 512, 0, stream>>>(hbf, gf16, ei, batch, ea,
                                             ee1w, ee1b, ee2p, ee2b, ee3p, ee3b,
                                             eeg, eebb,
                                             p1p, p1b, p2p, p2b, p3p, p3b,
                                             p4w, p4b, out);
}